// Round 1
// baseline (260.935 us; speedup 1.0000x reference)
//
#include <hip/hip_runtime.h>
#include <hip/hip_bf16.h>

#define BB 2
#define NN 2048
#define DD 768
#define EE 8
#define FF 3072
#define TOK (BB*NN)       // 4096
#define ROWS_CAP 9216     // 8192 slots + 8*128 alignment pad
#define TILES 72          // ROWS_CAP / 128

typedef __attribute__((ext_vector_type(8))) __bf16 bf16x8;
typedef __attribute__((ext_vector_type(4))) float floatx4;

// ---------- ws layout (bytes) ----------
#define OFF_CTRL    0ull                    // int[96]: base@16, tile_expert@24
#define OFF_V       1024ull                 // float[4096]
#define OFF_TOKE    17408ull                // int[8192]
#define OFF_TOKW    50176ull                // float[8192]
#define OFF_ROWTOK  82944ull                // int[9216]
#define OFF_ROWW    119808ull               // float[9216]
#define OFF_SLOT    156672ull               // int[8192]
#define OFF_FEATS   189440ull               // float[8192]
// big buffers
#define OFF_W2T     222208ull               // ushort[8*768*3072] = 37,748,736 B   (w2^T: [e][d][f])
#define OFF_XBF     37970944ull             // ushort[4096*768]   = 6,291,456 B
#define OFF_W1T     44262400ull             // ushort[8*3072*768] = 37,748,736 B   (w1^T: [e][f][d])
#define OFF_H       82011136ull             // ushort[9216*3072]  = 56,623,104 B -> end 138,634,240
#define OFF_Y       OFF_XBF                 // float[9216*768] = 28,311,552 B, aliases dead XBF+W1T

__device__ __forceinline__ ushort f2b(float f) {
    union { float f; unsigned int i; } v; v.f = f;
    unsigned int u = v.i;
    unsigned int r = (u + 0x7FFFu + ((u >> 16) & 1u)) >> 16;
    return (ushort)r;
}
__device__ __forceinline__ unsigned int pk2(float lo, float hi) {
    union { float f; unsigned int u; } a, b;
    a.f = lo; b.f = hi;
    unsigned int ra = ((a.u + 0x7FFFu + ((a.u >> 16) & 1u)) >> 16) & 0xFFFFu;
    unsigned int rb = (b.u + 0x7FFFu + ((b.u >> 16) & 1u)) & 0xFFFF0000u;
    return ra | rb;
}
__device__ __forceinline__ float gelu_f(float x) {
    float z = 0.7978845608028654f * x * (1.f + 0.044715f * x * x);
    z = fminf(fmaxf(z, -12.f), 12.f);
    float e = __expf(2.f * z);
    return 0.5f * x * (1.f + (e - 1.f) / (e + 1.f));
}
// async global(16B/lane) -> LDS (wave-uniform base + lane*16)
__device__ __forceinline__ void gload16(const ushort* g, ushort* l) {
    __builtin_amdgcn_global_load_lds((const __attribute__((address_space(1))) void*)g,
                                     (__attribute__((address_space(3))) void*)l,
                                     16, 0, 0);
}

// ---------- complex / Mobius helpers ----------
struct cplx { float x, y; };
__device__ __forceinline__ cplx cmulc(cplx a, cplx b) { return {a.x*b.x - a.y*b.y, a.x*b.y + a.y*b.x}; }
__device__ __forceinline__ cplx caddc(cplx a, cplx b) { return {a.x + b.x, a.y + b.y}; }
__device__ __forceinline__ cplx cdivc(cplx a, cplx b) {
    float s = 1.f / (b.x*b.x + b.y*b.y);
    return {(a.x*b.x + a.y*b.y)*s, (a.y*b.x - a.x*b.y)*s};
}
struct mob { cplx m00, m01, m10, m11; };
__device__ __forceinline__ mob mmul(const mob& A, const mob& B) {
    mob C;
    C.m00 = caddc(cmulc(A.m00, B.m00), cmulc(A.m01, B.m10));
    C.m01 = caddc(cmulc(A.m00, B.m01), cmulc(A.m01, B.m11));
    C.m10 = caddc(cmulc(A.m10, B.m00), cmulc(A.m11, B.m10));
    C.m11 = caddc(cmulc(A.m10, B.m01), cmulc(A.m11, B.m11));
    return C;
}
__device__ __forceinline__ void mnorm(mob& A) {
    float s = fabsf(A.m00.x);
    s = fmaxf(s, fabsf(A.m00.y)); s = fmaxf(s, fabsf(A.m01.x)); s = fmaxf(s, fabsf(A.m01.y));
    s = fmaxf(s, fabsf(A.m10.x)); s = fmaxf(s, fabsf(A.m10.y)); s = fmaxf(s, fabsf(A.m11.x));
    s = fmaxf(s, fabsf(A.m11.y));
    float r = 1.f / fmaxf(s, 1e-30f);
    A.m00.x *= r; A.m00.y *= r; A.m01.x *= r; A.m01.y *= r;
    A.m10.x *= r; A.m10.y *= r; A.m11.x *= r; A.m11.y *= r;
}
__device__ __forceinline__ mob mstep(cplx a, const mob& P) {
    mob C;
    C.m00 = {a.x*P.m00.x - a.y*P.m00.y - P.m10.x, a.x*P.m00.y + a.y*P.m00.x - P.m10.y};
    C.m01 = {a.x*P.m01.x - a.y*P.m01.y - P.m11.x, a.x*P.m01.y + a.y*P.m01.x - P.m11.y};
    C.m10 = P.m00; C.m11 = P.m01;
    return C;
}
__device__ __forceinline__ void mstore(float* s, const mob& A) {
    s[0]=A.m00.x; s[1]=A.m00.y; s[2]=A.m01.x; s[3]=A.m01.y;
    s[4]=A.m10.x; s[5]=A.m10.y; s[6]=A.m11.x; s[7]=A.m11.y;
}
__device__ __forceinline__ mob mload(const float* s) {
    mob A;
    A.m00 = {s[0], s[1]}; A.m01 = {s[2], s[3]};
    A.m10 = {s[4], s[5]}; A.m11 = {s[6], s[7]};
    return A;
}

// ---------- K0b: fp32 -> bf16 bulk convert (8 elems/thread) ----------
__global__ __launch_bounds__(256) void cvt_kernel(
    const float* __restrict__ src, ushort* __restrict__ dst, int n8)
{
    int i = blockIdx.x * 256 + threadIdx.x;
    if (i >= n8) return;
    const float4* s = ((const float4*)src) + (size_t)i * 2;
    float4 a = s[0], b = s[1];
    uint4 o;
    o.x = pk2(a.x, a.y); o.y = pk2(a.z, a.w);
    o.z = pk2(b.x, b.y); o.w = pk2(b.z, b.w);
    *(((uint4*)dst) + i) = o;
}

// ---------- K0c: fp32 [R][C] -> bf16 transposed [C][R], per-expert (blockIdx.z) ----------
__global__ __launch_bounds__(256) void tcvt_kernel(
    const float* __restrict__ src, ushort* __restrict__ dst, int R, int C)
{
    size_t eoff = (size_t)blockIdx.z * R * C;
    const float* s = src + eoff;
    ushort* d = dst + eoff;
    __shared__ float t[32][33];
    int c0 = blockIdx.x * 32, r0 = blockIdx.y * 32;
    int tid = threadIdx.x;
    int tr = tid >> 3, tc = (tid & 7) * 4;
    float4 vsrc = *(const float4*)(s + (size_t)(r0 + tr) * C + c0 + tc);
    t[tr][tc] = vsrc.x; t[tr][tc+1] = vsrc.y; t[tr][tc+2] = vsrc.z; t[tr][tc+3] = vsrc.w;
    __syncthreads();
    ushort4 o;
    o.x = f2b(t[tc  ][tr]);
    o.y = f2b(t[tc+1][tr]);
    o.z = f2b(t[tc+2][tr]);
    o.w = f2b(t[tc+3][tr]);
    *(ushort4*)(d + (size_t)(c0 + tr) * R + r0 + tc) = o;
}

// ---------- K1: routing (one wave per token), fp32 inputs, NO atomics ----------
__global__ __launch_bounds__(256) void routing_kernel(
    const float* __restrict__ x, const float* __restrict__ v_w, const float* __restrict__ v_b,
    const float* __restrict__ gate_w, const float* __restrict__ gate_b,
    float* __restrict__ v_out, int* __restrict__ tok_e, float* __restrict__ tok_w)
{
    int wave = threadIdx.x >> 6, lane = threadIdx.x & 63;
    int t = blockIdx.x * 4 + wave;
    const float* xr = x + (size_t)t * DD;
    float av = 0.f;
    float ag[8] = {0.f, 0.f, 0.f, 0.f, 0.f, 0.f, 0.f, 0.f};
    #pragma unroll
    for (int i = 0; i < 12; i++) {
        int d = lane + 64 * i;
        float xv = xr[d];
        av += xv * v_w[d];
        const float4* g = (const float4*)(gate_w + d * 8);
        float4 g0 = g[0], g1 = g[1];
        ag[0] += xv * g0.x; ag[1] += xv * g0.y; ag[2] += xv * g0.z; ag[3] += xv * g0.w;
        ag[4] += xv * g1.x; ag[5] += xv * g1.y; ag[6] += xv * g1.z; ag[7] += xv * g1.w;
    }
    #pragma unroll
    for (int off = 32; off >= 1; off >>= 1) {
        av += __shfl_xor(av, off);
        #pragma unroll
        for (int e = 0; e < 8; e++) ag[e] += __shfl_xor(ag[e], off);
    }
    if (lane == 0) {
        float vv = av + v_b[0];
        vv = fminf(fmaxf(vv, -3.f), 3.f);
        v_out[t] = vv;
        float lg[8];
        #pragma unroll
        for (int e = 0; e < 8; e++) lg[e] = ag[e] + gate_b[e];
        int e0 = 0;
        #pragma unroll
        for (int e = 1; e < 8; e++) if (lg[e] > lg[e0]) e0 = e;
        int e1 = -1;
        #pragma unroll
        for (int e = 0; e < 8; e++) if (e != e0 && (e1 < 0 || lg[e] > lg[e1])) e1 = e;
        float w0 = 1.f / (1.f + __expf(lg[e1] - lg[e0]));
        tok_e[2*t] = e0; tok_e[2*t+1] = e1;
        tok_w[2*t] = w0; tok_w[2*t+1] = 1.f - w0;
    }
}

// ---------- K2: fused histogram + bases + tile map + scatter (1 block, LDS atomics only) ----------
__global__ __launch_bounds__(1024) void setup_scatter_kernel(
    const int* __restrict__ tok_e, const float* __restrict__ tok_w,
    int* __restrict__ ctrl, int* __restrict__ row_token, float* __restrict__ row_w,
    int* __restrict__ slot)
{
    __shared__ int cnt[8], base[8], cursor[8];
    int tid = threadIdx.x;
    int lane = tid & 63;
    if (tid < 8) { cnt[tid] = 0; cursor[tid] = 0; }
    __syncthreads();

    int mye[8];
    #pragma unroll
    for (int it = 0; it < 8; it++) {
        int idx = it * 1024 + tid;
        int e = tok_e[idx];
        mye[it] = e;
        #pragma unroll
        for (int ex = 0; ex < 8; ex++) {
            unsigned long long m = __ballot(e == ex);
            if (e == ex && lane == (__ffsll((long long)m) - 1))
                atomicAdd(&cnt[ex], (int)__popcll(m));
        }
    }
    __syncthreads();
    if (tid == 0) {
        int b = 0;
        int* te = ctrl + 24;
        for (int i = 0; i < TILES; i++) te[i] = -1;
        #pragma unroll
        for (int e = 0; e < EE; e++) {
            base[e] = b;
            ctrl[16 + e] = b;
            int tiles = (cnt[e] + 127) >> 7;
            int t0 = b >> 7;
            for (int i = 0; i < tiles; i++) te[t0 + i] = e;
            b += tiles << 7;
        }
    }
    // pad rows default: token -1
    for (int p = tid; p < ROWS_CAP; p += 1024) row_token[p] = -1;
    __syncthreads();

    #pragma unroll
    for (int it = 0; it < 8; it++) {
        int idx = it * 1024 + tid;
        int e = mye[it];
        unsigned long long lt = (1ull << lane) - 1ull;
        int p = 0;
        #pragma unroll
        for (int ex = 0; ex < 8; ex++) {
            unsigned long long m = __ballot(e == ex);
            if (e == ex) {
                int leader = __ffsll((long long)m) - 1;
                int pos = (int)__popcll(m & lt);
                int bp = 0;
                if (lane == leader) bp = atomicAdd(&cursor[ex], (int)__popcll(m));
                bp = __shfl(bp, leader);
                p = base[ex] + bp + pos;
            }
        }
        row_token[p] = idx >> 1;
        row_w[p] = tok_w[idx];
        slot[idx] = p;
    }
}

// ---------- K4: BK Green diag via Mobius prefix scan ----------
__global__ __launch_bounds__(256) void bk_scan_kernel(const float* __restrict__ v, float* __restrict__ feats) {
    int b = blockIdx.x;
    int t = threadIdx.x;
    __shared__ float sm[256][8];
    const mob I = {{1.f,0.f},{0.f,0.f},{0.f,0.f},{1.f,0.f}};
    cplx a[8];
    const float* vb = v + (size_t)b * NN;
    #pragma unroll
    for (int j = 0; j < 8; j++) { a[j].x = -2.f + vb[t*8 + j]; a[j].y = -1.f; }

    mob cur = I;
    #pragma unroll
    for (int j = 0; j < 8; j++) cur = mstep(a[j], cur);
    mnorm(cur);
    mstore(sm[t], cur);
    for (int s = 1; s < 256; s <<= 1) {
        __syncthreads();
        mob prev; bool has = (t >= s);
        if (has) prev = mload(sm[t - s]);
        __syncthreads();
        if (has) { cur = mmul(cur, prev); mnorm(cur); mstore(sm[t], cur); }
    }
    __syncthreads();
    mob P = (t > 0) ? mload(sm[t - 1]) : I;
    cplx dreg[8];
    #pragma unroll
    for (int j = 0; j < 8; j++) {
        P = mstep(a[j], P); mnorm(P);
        dreg[j] = cdivc(P.m00, P.m10);
    }
    __syncthreads();

    cur = I;
    #pragma unroll
    for (int j = 7; j >= 0; j--) cur = mstep(a[j], cur);
    mnorm(cur);
    mstore(sm[t], cur);
    for (int s = 1; s < 256; s <<= 1) {
        __syncthreads();
        mob nxt; bool has = (t + s < 256);
        if (has) nxt = mload(sm[t + s]);
        __syncthreads();
        if (has) { cur = mmul(cur, nxt); mnorm(cur); mstore(sm[t], cur); }
    }
    __syncthreads();
    P = (t < 255) ? mload(sm[t + 1]) : I;
    #pragma unroll
    for (int j = 7; j >= 0; j--) {
        P = mstep(a[j], P); mnorm(P);
        cplx e = cdivc(P.m00, P.m10);
        cplx den = {dreg[j].x + e.x - a[j].x, dreg[j].y + e.y - a[j].y};
        cplx one = {1.f, 0.f};
        cplx G = cdivc(one, den);
        int i = b * NN + t*8 + j;
        feats[2*i]   = G.x;
        feats[2*i+1] = G.y;
    }
}

// ===== shared GEMM macros: 2-phase double-buffered K-loop with LDS swizzle =====
// LDS layout (per 128x32 buffer): linear [row][32] ushorts, but 16B k-quad slot
// within a row is stored XOR-swizzled: slot p holds (r=p>>2, q=(p&3)^((r>>1)&3)).
// global_load_lds writes linearly (lane*16B); the per-lane GLOBAL k-offset is
// pre-swizzled (kq), and ds_read applies the same XOR (qx). Result: each 16-lane
// b128 read group covers all 32 banks exactly twice (2-way = free, was 8-way).
#define STAGE1(AW, BW, k0) do { \
        gload16(aglob0 + (k0), (AW)); \
        gload16(aglob1 + (k0), (AW) + 16*32); \
        gload16(bglob0 + (k0), (BW)); \
        gload16(bglob1 + (k0), (BW) + 16*32); } while (0)

#define COMP(AA, BB) do { \
        bf16x8 afr[4], bfr[4]; \
        _Pragma("unroll") \
        for (int i = 0; i < 4; i++) \
            afr[i] = *(const bf16x8*)(const void*)((AA) + (wm + i*16 + lm) * 32 + qx); \
        _Pragma("unroll") \
        for (int j = 0; j < 4; j++) \
            bfr[j] = *(const bf16x8*)(const void*)((BB) + (wn + j*16 + lm) * 32 + qx); \
        _Pragma("unroll") \
        for (int i = 0; i < 4; i++) \
            _Pragma("unroll") \
            for (int j = 0; j < 4; j++) \
                acc[i][j] = __builtin_amdgcn_mfma_f32_16x16x32_bf16(afr[i], bfr[j], acc[i][j], 0, 0, 0); \
    } while (0)

// ---------- K5: GEMM1  H = gelu(Xg @ w1t[e]^T + b1[e]) ----------
// grid = (FF/128, TILES): f-block is the FAST dim so same-(expert,f) weight
// panels across consecutive tiles land 24 blocks apart (24%8==0 -> same XCD L2).
__global__ __launch_bounds__(256) void gemm1_kernel(
    const ushort* __restrict__ x_bf, const ushort* __restrict__ w1t, const float* __restrict__ b1,
    const int* __restrict__ ctrl, const int* __restrict__ row_token, ushort* __restrict__ H)
{
    int tile = blockIdx.y;
    int e = ctrl[24 + tile];
    if (e < 0) return;
    int p0 = tile * 128;
    int f0 = blockIdx.x * 128;

    __shared__ ushort As[2][128 * 32];
    __shared__ ushort Bs[2][128 * 32];
    __shared__ int toks[128];

    int tid = threadIdx.x;
    if (tid < 128) { int tk = row_token[p0 + tid]; toks[tid] = tk < 0 ? 0 : tk; }
    __syncthreads();

    int wave = tid >> 6, lane = tid & 63;
    int rsub = lane >> 2;                                  // row within 16-row stage group
    int kq = (((lane & 3) ^ ((rsub >> 1) & 3))) * 8;       // swizzled global k-quad (ushorts)
    int tokA0 = toks[wave*32 + rsub];
    int tokA1 = toks[wave*32 + 16 + rsub];
    const ushort* aglob0 = x_bf + (size_t)tokA0 * DD + kq;
    const ushort* aglob1 = x_bf + (size_t)tokA1 * DD + kq;
    const ushort* w1e = w1t + (size_t)e * (FF * DD);       // [f][d] row stride DD
    const ushort* bglob0 = w1e + (size_t)(f0 + wave*32 + rsub) * DD + kq;
    const ushort* bglob1 = bglob0 + (size_t)16 * DD;
    ushort* AsW0 = &As[0][wave * 32 * 32];
    ushort* BsW0 = &Bs[0][wave * 32 * 32];
    ushort* AsW1 = &As[1][wave * 32 * 32];
    ushort* BsW1 = &Bs[1][wave * 32 * 32];

    floatx4 zero4 = {0.f, 0.f, 0.f, 0.f};
    floatx4 acc[4][4];
    #pragma unroll
    for (int i = 0; i < 4; i++)
        #pragma unroll
        for (int j = 0; j < 4; j++) acc[i][j] = zero4;

    int wm = (wave & 1) * 64, wn = (wave >> 1) * 64;
    int lm = lane & 15, q = lane >> 4;
    int qx = (q ^ ((lm >> 1) & 3)) * 8;                    // swizzled ds_read k-quad

    STAGE1(AsW0, BsW0, 0);
    __syncthreads();
    // 2-phase: issue next-tile stage BEFORE computing current tile; single
    // barrier per K-step drains both (stage latency hides under ds_read+MFMA).
    for (int ks = 0; ks < DD/32; ks += 2) {
        STAGE1(AsW1, BsW1, ks*32 + 32);
        COMP(As[0], Bs[0]);
        __syncthreads();
        if (ks + 2 < DD/32) STAGE1(AsW0, BsW0, ks*32 + 64);
        COMP(As[1], Bs[1]);
        __syncthreads();
    }

    #pragma unroll
    for (int i = 0; i < 4; i++) {
        #pragma unroll
        for (int j = 0; j < 4; j++) {
            int n = wn + j*16 + lm;
            float bias = b1[e * FF + f0 + n];
            #pragma unroll
            for (int r = 0; r < 4; r++) {
                int m = wm + i*16 + q*4 + r;
                float hv = gelu_f(acc[i][j][r] + bias);
                H[(size_t)(p0 + m) * FF + f0 + n] = f2b(hv);
            }
        }
    }
}

// ---------- K6: GEMM2  Y = row_w * (H @ w2t[e]^T + b2[e]) ----------
// grid stays (TILES, DD/128): same tile across d-blocks is 72 apart (72%8==0
// -> same XCD), so the 786KB H-tile is L2-reused across all 6 d-blocks.
__global__ __launch_bounds__(256) void gemm2_kernel(
    const ushort* __restrict__ H, const ushort* __restrict__ w2t, const float* __restrict__ b2,
    const int* __restrict__ ctrl, const float* __restrict__ row_w, float* __restrict__ Y)
{
    int tile = blockIdx.x;
    int e = ctrl[24 + tile];
    if (e < 0) return;
    int p0 = tile * 128;
    int d0 = blockIdx.y * 128;

    __shared__ ushort As[2][128 * 32];
    __shared__ ushort Bs[2][128 * 32];

    int tid = threadIdx.x;
    int wave = tid >> 6, lane = tid & 63;
    int rsub = lane >> 2;
    int kq = (((lane & 3) ^ ((rsub >> 1) & 3))) * 8;
    const ushort* aglob0 = H + (size_t)(p0 + wave*32 + rsub) * FF + kq;
    const ushort* aglob1 = aglob0 + (size_t)16 * FF;
    const ushort* w2e = w2t + (size_t)e * (DD * FF);      // [d][f] row stride FF
    const ushort* bglob0 = w2e + (size_t)(d0 + wave*32 + rsub) * FF + kq;
    const ushort* bglob1 = bglob0 + (size_t)16 * FF;
    ushort* AsW0 = &As[0][wave * 32 * 32];
    ushort* BsW0 = &Bs[0][wave * 32 * 32];
    ushort* AsW1 = &As[1][wave * 32 * 32];
    ushort* BsW1 = &Bs[1][wave * 32 * 32];

    floatx4 zero4 = {0.f, 0.f, 0.f, 0.f};
    floatx4 acc[4][4];
    #pragma unroll
    for (int i = 0; i < 4; i++)
        #pragma unroll
        for (int j = 0; j < 4; j++) acc[i][j] = zero4;

    int wm = (wave & 1) * 64, wn = (wave >> 1) * 64;
    int lm = lane & 15, q = lane >> 4;
    int qx = (q ^ ((lm >> 1) & 3)) * 8;

    STAGE1(AsW0, BsW0, 0);
    __syncthreads();
    for (int ks = 0; ks < FF/32; ks += 2) {
        STAGE1(AsW1, BsW1, ks*32 + 32);
        COMP(As[0], Bs[0]);
        __syncthreads();
        if (ks + 2 < FF/32) STAGE1(AsW0, BsW0, ks*32 + 64);
        COMP(As[1], Bs[1]);
        __syncthreads();
    }

    #pragma unroll
    for (int i = 0; i < 4; i++) {
        #pragma unroll
        for (int j = 0; j < 4; j++) {
            int n = wn + j*16 + lm;
            float bias = b2[e * DD + d0 + n];
            #pragma unroll
            for (int r = 0; r < 4; r++) {
                int m = wm + i*16 + q*4 + r;
                float wgt = row_w[p0 + m];
                Y[(size_t)(p0 + m) * DD + d0 + n] = wgt * (acc[i][j][r] + bias);
            }
        }
    }
}

// ---------- K7: final combine (fp32 out) ----------
__global__ __launch_bounds__(256) void final_kernel(
    const float* __restrict__ Y, const int* __restrict__ slot, const float* __restrict__ feats,
    const float* __restrict__ out_w, const float* __restrict__ out_b,
    const float* __restrict__ bk_scale, float* __restrict__ out)
{
    int idx = blockIdx.x * 256 + threadIdx.x;
    int base = idx * 4;
    int t = base / DD;
    int d = base - t * DD;
    int p0 = slot[2*t], p1 = slot[2*t + 1];
    const float4 ya = *(const float4*)(Y + (size_t)p0 * DD + d);
    const float4 yb = *(const float4*)(Y + (size_t)p1 * DD + d);
    float f0 = feats[2*t], f1 = feats[2*t + 1];
    f0 = fminf(fmaxf(f0, -10.f), 10.f);
    f1 = fminf(fmaxf(f1, -10.f), 10.f);
    float ff[4] = {ya.x + yb.x, ya.y + yb.y, ya.z + yb.z, ya.w + yb.w};
    float4 o;
    float* op = (float*)&o;
    #pragma unroll
    for (int u = 0; u < 4; u++) {
        float spec = f0 * out_w[d + u] + f1 * out_w[DD + d + u] + out_b[d + u];
        op[u] = ff[u] + bk_scale[d + u] * spec;
    }
    *(float4*)(out + base) = o;
}

extern "C" void kernel_launch(void* const* d_in, const int* in_sizes, int n_in,
                              void* d_out, int out_size, void* d_ws, size_t ws_size,
                              hipStream_t stream)
{
    const float* x      = (const float*)d_in[0];
    const float* v_w    = (const float*)d_in[1];
    const float* v_b    = (const float*)d_in[2];
    const float* gate_w = (const float*)d_in[3];
    const float* gate_b = (const float*)d_in[4];
    const float* w1     = (const float*)d_in[5];
    const float* b1     = (const float*)d_in[6];
    const float* w2     = (const float*)d_in[7];
    const float* b2     = (const float*)d_in[8];
    const float* out_w  = (const float*)d_in[9];
    const float* out_b  = (const float*)d_in[10];
    const float* bk_s   = (const float*)d_in[11];

    char* ws = (char*)d_ws;
    int*    ctrl    = (int*)(ws + OFF_CTRL);
    float*  v       = (float*)(ws + OFF_V);
    int*    tok_e   = (int*)(ws + OFF_TOKE);
    float*  tok_w   = (float*)(ws + OFF_TOKW);
    int*    row_tok = (int*)(ws + OFF_ROWTOK);
    float*  row_w   = (float*)(ws + OFF_ROWW);
    int*    slot    = (int*)(ws + OFF_SLOT);
    float*  feats   = (float*)(ws + OFF_FEATS);
    ushort* w2t     = (ushort*)(ws + OFF_W2T);
    ushort* x_bf    = (ushort*)(ws + OFF_XBF);
    ushort* w1t     = (ushort*)(ws + OFF_W1T);
    ushort* H       = (ushort*)(ws + OFF_H);
    float*  Y       = (float*)(ws + OFF_Y);
    float*  out     = (float*)d_out;

    cvt_kernel<<<(TOK*DD)/8/256, 256, 0, stream>>>(x, x_bf, (TOK*DD)/8);
    // w1: [e][768][3072] -> w1t [e][3072][768]
    tcvt_kernel<<<dim3(FF/32, DD/32, EE), 256, 0, stream>>>(w1, w1t, DD, FF);
    // w2: [e][3072][768] -> w2t [e][768][3072]
    tcvt_kernel<<<dim3(DD/32, FF/32, EE), 256, 0, stream>>>(w2, w2t, FF, DD);
    routing_kernel<<<TOK / 4, 256, 0, stream>>>(x, v_w, v_b, gate_w, gate_b, v, tok_e, tok_w);
    setup_scatter_kernel<<<1, 1024, 0, stream>>>(tok_e, tok_w, ctrl, row_tok, row_w, slot);
    bk_scan_kernel<<<BB, 256, 0, stream>>>(v, feats);
    gemm1_kernel<<<dim3(FF / 128, TILES), 256, 0, stream>>>(x_bf, w1t, b1, ctrl, row_tok, H);
    gemm2_kernel<<<dim3(TILES, DD / 128), 256, 0, stream>>>(H, w2t, b2, ctrl, row_w, Y);
    final_kernel<<<(TOK * DD) / 1024, 256, 0, stream>>>(Y, slot, feats, out_w, out_b, bk_s, out);
}

// Round 2
// 256.115 us; speedup vs baseline: 1.0188x; 1.0188x over previous
//
#include <hip/hip_runtime.h>
#include <hip/hip_bf16.h>

#define BB 2
#define NN 2048
#define DD 768
#define EE 8
#define FF 3072
#define TOK (BB*NN)       // 4096
#define ROWS_CAP 9216     // 8192 slots + 8*128 alignment pad
#define TILES 72          // ROWS_CAP / 128

typedef __attribute__((ext_vector_type(8))) __bf16 bf16x8;
typedef __attribute__((ext_vector_type(4))) float floatx4;

// ---------- ws layout (bytes) ----------
#define OFF_CTRL    0ull                    // int[96]: base@16, tile_expert@24
#define OFF_V       1024ull                 // float[4096]
#define OFF_TOKE    17408ull                // int[8192]
#define OFF_TOKW    50176ull                // float[8192]
#define OFF_ROWTOK  82944ull                // int[9216]
#define OFF_ROWW    119808ull               // float[9216]
#define OFF_SLOT    156672ull               // int[8192]
#define OFF_FEATS   189440ull               // float[8192]
// big buffers
#define OFF_W2T     222208ull               // ushort[8*768*3072] = 37,748,736 B   (w2^T: [e][d][f])
#define OFF_XBF     37970944ull             // ushort[4096*768]   = 6,291,456 B
#define OFF_W1T     44262400ull             // ushort[8*3072*768] = 37,748,736 B   (w1^T: [e][f][d])
#define OFF_H       82011136ull             // ushort[9216*3072]  = 56,623,104 B -> end 138,634,240
#define OFF_Y       OFF_XBF                 // float[9216*768] = 28,311,552 B, aliases dead XBF+W1T

__device__ __forceinline__ ushort f2b(float f) {
    union { float f; unsigned int i; } v; v.f = f;
    unsigned int u = v.i;
    unsigned int r = (u + 0x7FFFu + ((u >> 16) & 1u)) >> 16;
    return (ushort)r;
}
__device__ __forceinline__ unsigned int pk2(float lo, float hi) {
    union { float f; unsigned int u; } a, b;
    a.f = lo; b.f = hi;
    unsigned int ra = ((a.u + 0x7FFFu + ((a.u >> 16) & 1u)) >> 16) & 0xFFFFu;
    unsigned int rb = (b.u + 0x7FFFu + ((b.u >> 16) & 1u)) & 0xFFFF0000u;
    return ra | rb;
}
__device__ __forceinline__ float gelu_f(float x) {
    float z = 0.7978845608028654f * x * (1.f + 0.044715f * x * x);
    z = fminf(fmaxf(z, -12.f), 12.f);
    float e = __expf(2.f * z);
    return 0.5f * x * (1.f + (e - 1.f) / (e + 1.f));
}
// async global(16B/lane) -> LDS (wave-uniform base + lane*16)
__device__ __forceinline__ void gload16(const ushort* g, ushort* l) {
    __builtin_amdgcn_global_load_lds((const __attribute__((address_space(1))) void*)g,
                                     (__attribute__((address_space(3))) void*)l,
                                     16, 0, 0);
}

// ---------- complex / Mobius helpers ----------
struct cplx { float x, y; };
__device__ __forceinline__ cplx cmulc(cplx a, cplx b) { return {a.x*b.x - a.y*b.y, a.x*b.y + a.y*b.x}; }
__device__ __forceinline__ cplx caddc(cplx a, cplx b) { return {a.x + b.x, a.y + b.y}; }
__device__ __forceinline__ cplx cdivc(cplx a, cplx b) {
    float s = 1.f / (b.x*b.x + b.y*b.y);
    return {(a.x*b.x + a.y*b.y)*s, (a.y*b.x - a.x*b.y)*s};
}
struct mob { cplx m00, m01, m10, m11; };
__device__ __forceinline__ mob mmul(const mob& A, const mob& B) {
    mob C;
    C.m00 = caddc(cmulc(A.m00, B.m00), cmulc(A.m01, B.m10));
    C.m01 = caddc(cmulc(A.m00, B.m01), cmulc(A.m01, B.m11));
    C.m10 = caddc(cmulc(A.m10, B.m00), cmulc(A.m11, B.m10));
    C.m11 = caddc(cmulc(A.m10, B.m01), cmulc(A.m11, B.m11));
    return C;
}
__device__ __forceinline__ void mnorm(mob& A) {
    float s = fabsf(A.m00.x);
    s = fmaxf(s, fabsf(A.m00.y)); s = fmaxf(s, fabsf(A.m01.x)); s = fmaxf(s, fabsf(A.m01.y));
    s = fmaxf(s, fabsf(A.m10.x)); s = fmaxf(s, fabsf(A.m10.y)); s = fmaxf(s, fabsf(A.m11.x));
    s = fmaxf(s, fabsf(A.m11.y));
    float r = 1.f / fmaxf(s, 1e-30f);
    A.m00.x *= r; A.m00.y *= r; A.m01.x *= r; A.m01.y *= r;
    A.m10.x *= r; A.m10.y *= r; A.m11.x *= r; A.m11.y *= r;
}
__device__ __forceinline__ mob mstep(cplx a, const mob& P) {
    mob C;
    C.m00 = {a.x*P.m00.x - a.y*P.m00.y - P.m10.x, a.x*P.m00.y + a.y*P.m00.x - P.m10.y};
    C.m01 = {a.x*P.m01.x - a.y*P.m01.y - P.m11.x, a.x*P.m01.y + a.y*P.m01.x - P.m11.y};
    C.m10 = P.m00; C.m11 = P.m01;
    return C;
}
__device__ __forceinline__ void mstore(float* s, const mob& A) {
    s[0]=A.m00.x; s[1]=A.m00.y; s[2]=A.m01.x; s[3]=A.m01.y;
    s[4]=A.m10.x; s[5]=A.m10.y; s[6]=A.m11.x; s[7]=A.m11.y;
}
__device__ __forceinline__ mob mload(const float* s) {
    mob A;
    A.m00 = {s[0], s[1]}; A.m01 = {s[2], s[3]};
    A.m10 = {s[4], s[5]}; A.m11 = {s[6], s[7]};
    return A;
}

// ---------- K0b: fp32 -> bf16 bulk convert (8 elems/thread) ----------
__global__ __launch_bounds__(256) void cvt_kernel(
    const float* __restrict__ src, ushort* __restrict__ dst, int n8)
{
    int i = blockIdx.x * 256 + threadIdx.x;
    if (i >= n8) return;
    const float4* s = ((const float4*)src) + (size_t)i * 2;
    float4 a = s[0], b = s[1];
    uint4 o;
    o.x = pk2(a.x, a.y); o.y = pk2(a.z, a.w);
    o.z = pk2(b.x, b.y); o.w = pk2(b.z, b.w);
    *(((uint4*)dst) + i) = o;
}

// ---------- K0c: fp32 [R][C] -> bf16 transposed [C][R], per-expert (blockIdx.z) ----------
__global__ __launch_bounds__(256) void tcvt_kernel(
    const float* __restrict__ src, ushort* __restrict__ dst, int R, int C)
{
    size_t eoff = (size_t)blockIdx.z * R * C;
    const float* s = src + eoff;
    ushort* d = dst + eoff;
    __shared__ float t[32][33];
    int c0 = blockIdx.x * 32, r0 = blockIdx.y * 32;
    int tid = threadIdx.x;
    int tr = tid >> 3, tc = (tid & 7) * 4;
    float4 vsrc = *(const float4*)(s + (size_t)(r0 + tr) * C + c0 + tc);
    t[tr][tc] = vsrc.x; t[tr][tc+1] = vsrc.y; t[tr][tc+2] = vsrc.z; t[tr][tc+3] = vsrc.w;
    __syncthreads();
    ushort4 o;
    o.x = f2b(t[tc  ][tr]);
    o.y = f2b(t[tc+1][tr]);
    o.z = f2b(t[tc+2][tr]);
    o.w = f2b(t[tc+3][tr]);
    *(ushort4*)(d + (size_t)(c0 + tr) * R + r0 + tc) = o;
}

// ---------- K1: routing (one wave per token), fp32 inputs, NO atomics ----------
__global__ __launch_bounds__(256) void routing_kernel(
    const float* __restrict__ x, const float* __restrict__ v_w, const float* __restrict__ v_b,
    const float* __restrict__ gate_w, const float* __restrict__ gate_b,
    float* __restrict__ v_out, int* __restrict__ tok_e, float* __restrict__ tok_w)
{
    int wave = threadIdx.x >> 6, lane = threadIdx.x & 63;
    int t = blockIdx.x * 4 + wave;
    const float* xr = x + (size_t)t * DD;
    float av = 0.f;
    float ag[8] = {0.f, 0.f, 0.f, 0.f, 0.f, 0.f, 0.f, 0.f};
    #pragma unroll
    for (int i = 0; i < 12; i++) {
        int d = lane + 64 * i;
        float xv = xr[d];
        av += xv * v_w[d];
        const float4* g = (const float4*)(gate_w + d * 8);
        float4 g0 = g[0], g1 = g[1];
        ag[0] += xv * g0.x; ag[1] += xv * g0.y; ag[2] += xv * g0.z; ag[3] += xv * g0.w;
        ag[4] += xv * g1.x; ag[5] += xv * g1.y; ag[6] += xv * g1.z; ag[7] += xv * g1.w;
    }
    #pragma unroll
    for (int off = 32; off >= 1; off >>= 1) {
        av += __shfl_xor(av, off);
        #pragma unroll
        for (int e = 0; e < 8; e++) ag[e] += __shfl_xor(ag[e], off);
    }
    if (lane == 0) {
        float vv = av + v_b[0];
        vv = fminf(fmaxf(vv, -3.f), 3.f);
        v_out[t] = vv;
        float lg[8];
        #pragma unroll
        for (int e = 0; e < 8; e++) lg[e] = ag[e] + gate_b[e];
        int e0 = 0;
        #pragma unroll
        for (int e = 1; e < 8; e++) if (lg[e] > lg[e0]) e0 = e;
        int e1 = -1;
        #pragma unroll
        for (int e = 0; e < 8; e++) if (e != e0 && (e1 < 0 || lg[e] > lg[e1])) e1 = e;
        float w0 = 1.f / (1.f + __expf(lg[e1] - lg[e0]));
        tok_e[2*t] = e0; tok_e[2*t+1] = e1;
        tok_w[2*t] = w0; tok_w[2*t+1] = 1.f - w0;
    }
}

// ---------- K2: fused histogram + bases + tile map + scatter (1 block, LDS atomics only) ----------
__global__ __launch_bounds__(1024) void setup_scatter_kernel(
    const int* __restrict__ tok_e, const float* __restrict__ tok_w,
    int* __restrict__ ctrl, int* __restrict__ row_token, float* __restrict__ row_w,
    int* __restrict__ slot)
{
    __shared__ int cnt[8], base[8], cursor[8];
    int tid = threadIdx.x;
    int lane = tid & 63;
    if (tid < 8) { cnt[tid] = 0; cursor[tid] = 0; }
    __syncthreads();

    int mye[8];
    #pragma unroll
    for (int it = 0; it < 8; it++) {
        int idx = it * 1024 + tid;
        int e = tok_e[idx];
        mye[it] = e;
        #pragma unroll
        for (int ex = 0; ex < 8; ex++) {
            unsigned long long m = __ballot(e == ex);
            if (e == ex && lane == (__ffsll((long long)m) - 1))
                atomicAdd(&cnt[ex], (int)__popcll(m));
        }
    }
    __syncthreads();
    if (tid == 0) {
        int b = 0;
        int* te = ctrl + 24;
        for (int i = 0; i < TILES; i++) te[i] = -1;
        #pragma unroll
        for (int e = 0; e < EE; e++) {
            base[e] = b;
            ctrl[16 + e] = b;
            int tiles = (cnt[e] + 127) >> 7;
            int t0 = b >> 7;
            for (int i = 0; i < tiles; i++) te[t0 + i] = e;
            b += tiles << 7;
        }
    }
    // pad rows default: token -1
    for (int p = tid; p < ROWS_CAP; p += 1024) row_token[p] = -1;
    __syncthreads();

    #pragma unroll
    for (int it = 0; it < 8; it++) {
        int idx = it * 1024 + tid;
        int e = mye[it];
        unsigned long long lt = (1ull << lane) - 1ull;
        int p = 0;
        #pragma unroll
        for (int ex = 0; ex < 8; ex++) {
            unsigned long long m = __ballot(e == ex);
            if (e == ex) {
                int leader = __ffsll((long long)m) - 1;
                int pos = (int)__popcll(m & lt);
                int bp = 0;
                if (lane == leader) bp = atomicAdd(&cursor[ex], (int)__popcll(m));
                bp = __shfl(bp, leader);
                p = base[ex] + bp + pos;
            }
        }
        row_token[p] = idx >> 1;
        row_w[p] = tok_w[idx];
        slot[idx] = p;
    }
}

// ---------- K4: BK Green diag via Mobius prefix scan ----------
__global__ __launch_bounds__(256) void bk_scan_kernel(const float* __restrict__ v, float* __restrict__ feats) {
    int b = blockIdx.x;
    int t = threadIdx.x;
    __shared__ float sm[256][8];
    const mob I = {{1.f,0.f},{0.f,0.f},{0.f,0.f},{1.f,0.f}};
    cplx a[8];
    const float* vb = v + (size_t)b * NN;
    #pragma unroll
    for (int j = 0; j < 8; j++) { a[j].x = -2.f + vb[t*8 + j]; a[j].y = -1.f; }

    mob cur = I;
    #pragma unroll
    for (int j = 0; j < 8; j++) cur = mstep(a[j], cur);
    mnorm(cur);
    mstore(sm[t], cur);
    for (int s = 1; s < 256; s <<= 1) {
        __syncthreads();
        mob prev; bool has = (t >= s);
        if (has) prev = mload(sm[t - s]);
        __syncthreads();
        if (has) { cur = mmul(cur, prev); mnorm(cur); mstore(sm[t], cur); }
    }
    __syncthreads();
    mob P = (t > 0) ? mload(sm[t - 1]) : I;
    cplx dreg[8];
    #pragma unroll
    for (int j = 0; j < 8; j++) {
        P = mstep(a[j], P); mnorm(P);
        dreg[j] = cdivc(P.m00, P.m10);
    }
    __syncthreads();

    cur = I;
    #pragma unroll
    for (int j = 7; j >= 0; j--) cur = mstep(a[j], cur);
    mnorm(cur);
    mstore(sm[t], cur);
    for (int s = 1; s < 256; s <<= 1) {
        __syncthreads();
        mob nxt; bool has = (t + s < 256);
        if (has) nxt = mload(sm[t + s]);
        __syncthreads();
        if (has) { cur = mmul(cur, nxt); mnorm(cur); mstore(sm[t], cur); }
    }
    __syncthreads();
    P = (t < 255) ? mload(sm[t + 1]) : I;
    #pragma unroll
    for (int j = 7; j >= 0; j--) {
        P = mstep(a[j], P); mnorm(P);
        cplx e = cdivc(P.m00, P.m10);
        cplx den = {dreg[j].x + e.x - a[j].x, dreg[j].y + e.y - a[j].y};
        cplx one = {1.f, 0.f};
        cplx G = cdivc(one, den);
        int i = b * NN + t*8 + j;
        feats[2*i]   = G.x;
        feats[2*i+1] = G.y;
    }
}

// ===== shared GEMM macros: single-buffer K-loop, WAR-safe register prefetch =====
// LDS layout (per 128x32 buffer): linear [row][32] ushorts; the 16B k-quad slot
// within a row is XOR-swizzled: slot p holds (r=p>>2, q=(p&3)^((r>>1)&3)).
// global_load_lds writes linearly (lane*16B); the per-lane GLOBAL k-offset is
// pre-swizzled (kq), and ds_read applies the same XOR (qx). Each 16-lane b128
// read group covers all 32 banks exactly twice (2-way = free; was 8-way).
//
// K-step structure (single 16.9KB buffer -> ~8 blocks/CU occupancy, vs 4 with
// dbuf which round-1 showed is a net loss):
//   regs <- ds_read; barrier(LDS consumed); STAGE(next) overlaps MFMAs; barrier.
#define STAGE1(AW, BW, k0) do { \
        gload16(aglob0 + (k0), (AW)); \
        gload16(aglob1 + (k0), (AW) + 16*32); \
        gload16(bglob0 + (k0), (BW)); \
        gload16(bglob1 + (k0), (BW) + 16*32); } while (0)

#define LOADFR() do { \
        _Pragma("unroll") \
        for (int i = 0; i < 4; i++) \
            afr[i] = *(const bf16x8*)(const void*)(As + (wm + i*16 + lm) * 32 + qx); \
        _Pragma("unroll") \
        for (int j = 0; j < 4; j++) \
            bfr[j] = *(const bf16x8*)(const void*)(Bs + (wn + j*16 + lm) * 32 + qx); \
    } while (0)

#define MFMAS() do { \
        _Pragma("unroll") \
        for (int i = 0; i < 4; i++) \
            _Pragma("unroll") \
            for (int j = 0; j < 4; j++) \
                acc[i][j] = __builtin_amdgcn_mfma_f32_16x16x32_bf16(afr[i], bfr[j], acc[i][j], 0, 0, 0); \
    } while (0)

// ---------- K5: GEMM1  H = gelu(Xg @ w1t[e]^T + b1[e]) ----------
// grid = (FF/128, TILES): f-block is the FAST dim so same-(expert,f) weight
// panels across consecutive tiles land 24 blocks apart (24%8==0 -> same XCD L2).
__global__ __launch_bounds__(256) void gemm1_kernel(
    const ushort* __restrict__ x_bf, const ushort* __restrict__ w1t, const float* __restrict__ b1,
    const int* __restrict__ ctrl, const int* __restrict__ row_token, ushort* __restrict__ H)
{
    int tile = blockIdx.y;
    int e = ctrl[24 + tile];
    if (e < 0) return;
    int p0 = tile * 128;
    int f0 = blockIdx.x * 128;

    __shared__ ushort As[128 * 32];
    __shared__ ushort Bs[128 * 32];
    __shared__ int toks[128];

    int tid = threadIdx.x;
    if (tid < 128) { int tk = row_token[p0 + tid]; toks[tid] = tk < 0 ? 0 : tk; }
    __syncthreads();

    int wave = tid >> 6, lane = tid & 63;
    int rsub = lane >> 2;                                  // row within 16-row stage group
    int kq = (((lane & 3) ^ ((rsub >> 1) & 3))) * 8;       // swizzled global k-quad (ushorts)
    int tokA0 = toks[wave*32 + rsub];
    int tokA1 = toks[wave*32 + 16 + rsub];
    const ushort* aglob0 = x_bf + (size_t)tokA0 * DD + kq;
    const ushort* aglob1 = x_bf + (size_t)tokA1 * DD + kq;
    const ushort* w1e = w1t + (size_t)e * (FF * DD);       // [f][d] row stride DD
    const ushort* bglob0 = w1e + (size_t)(f0 + wave*32 + rsub) * DD + kq;
    const ushort* bglob1 = bglob0 + (size_t)16 * DD;
    ushort* AsW = As + wave * 32 * 32;
    ushort* BsW = Bs + wave * 32 * 32;

    floatx4 zero4 = {0.f, 0.f, 0.f, 0.f};
    floatx4 acc[4][4];
    #pragma unroll
    for (int i = 0; i < 4; i++)
        #pragma unroll
        for (int j = 0; j < 4; j++) acc[i][j] = zero4;

    int wm = (wave & 1) * 64, wn = (wave >> 1) * 64;
    int lm = lane & 15, q = lane >> 4;
    int qx = (q ^ ((lm >> 1) & 3)) * 8;                    // swizzled ds_read k-quad

    STAGE1(AsW, BsW, 0);
    __syncthreads();
    for (int ks = 0; ks < DD/32; ks++) {
        bf16x8 afr[4], bfr[4];
        LOADFR();
        __syncthreads();                       // LDS fully consumed into regs
        if (ks + 1 < DD/32) STAGE1(AsW, BsW, ks*32 + 32);  // overlaps MFMAs below
        MFMAS();
        __syncthreads();                       // stage drained (vmcnt0 at barrier)
    }

    #pragma unroll
    for (int i = 0; i < 4; i++) {
        #pragma unroll
        for (int j = 0; j < 4; j++) {
            int n = wn + j*16 + lm;
            float bias = b1[e * FF + f0 + n];
            #pragma unroll
            for (int r = 0; r < 4; r++) {
                int m = wm + i*16 + q*4 + r;
                float hv = gelu_f(acc[i][j][r] + bias);
                H[(size_t)(p0 + m) * FF + f0 + n] = f2b(hv);
            }
        }
    }
}

// ---------- K6: GEMM2  Y = row_w * (H @ w2t[e]^T + b2[e]) ----------
// grid stays (TILES, DD/128): same tile across d-blocks is 72 apart (72%8==0
// -> same XCD), so the H-tile is L2-reused across all 6 d-blocks.
__global__ __launch_bounds__(256) void gemm2_kernel(
    const ushort* __restrict__ H, const ushort* __restrict__ w2t, const float* __restrict__ b2,
    const int* __restrict__ ctrl, const float* __restrict__ row_w, float* __restrict__ Y)
{
    int tile = blockIdx.x;
    int e = ctrl[24 + tile];
    if (e < 0) return;
    int p0 = tile * 128;
    int d0 = blockIdx.y * 128;

    __shared__ ushort As[128 * 32];
    __shared__ ushort Bs[128 * 32];

    int tid = threadIdx.x;
    int wave = tid >> 6, lane = tid & 63;
    int rsub = lane >> 2;
    int kq = (((lane & 3) ^ ((rsub >> 1) & 3))) * 8;
    const ushort* aglob0 = H + (size_t)(p0 + wave*32 + rsub) * FF + kq;
    const ushort* aglob1 = aglob0 + (size_t)16 * FF;
    const ushort* w2e = w2t + (size_t)e * (DD * FF);      // [d][f] row stride FF
    const ushort* bglob0 = w2e + (size_t)(d0 + wave*32 + rsub) * FF + kq;
    const ushort* bglob1 = bglob0 + (size_t)16 * FF;
    ushort* AsW = As + wave * 32 * 32;
    ushort* BsW = Bs + wave * 32 * 32;

    floatx4 zero4 = {0.f, 0.f, 0.f, 0.f};
    floatx4 acc[4][4];
    #pragma unroll
    for (int i = 0; i < 4; i++)
        #pragma unroll
        for (int j = 0; j < 4; j++) acc[i][j] = zero4;

    int wm = (wave & 1) * 64, wn = (wave >> 1) * 64;
    int lm = lane & 15, q = lane >> 4;
    int qx = (q ^ ((lm >> 1) & 3)) * 8;

    STAGE1(AsW, BsW, 0);
    __syncthreads();
    for (int ks = 0; ks < FF/32; ks++) {
        bf16x8 afr[4], bfr[4];
        LOADFR();
        __syncthreads();
        if (ks + 1 < FF/32) STAGE1(AsW, BsW, ks*32 + 32);
        MFMAS();
        __syncthreads();
    }

    #pragma unroll
    for (int i = 0; i < 4; i++) {
        #pragma unroll
        for (int j = 0; j < 4; j++) {
            int n = wn + j*16 + lm;
            float bias = b2[e * DD + d0 + n];
            #pragma unroll
            for (int r = 0; r < 4; r++) {
                int m = wm + i*16 + q*4 + r;
                float wgt = row_w[p0 + m];
                Y[(size_t)(p0 + m) * DD + d0 + n] = wgt * (acc[i][j][r] + bias);
            }
        }
    }
}

// ---------- K7: final combine (fp32 out) ----------
__global__ __launch_bounds__(256) void final_kernel(
    const float* __restrict__ Y, const int* __restrict__ slot, const float* __restrict__ feats,
    const float* __restrict__ out_w, const float* __restrict__ out_b,
    const float* __restrict__ bk_scale, float* __restrict__ out)
{
    int idx = blockIdx.x * 256 + threadIdx.x;
    int base = idx * 4;
    int t = base / DD;
    int d = base - t * DD;
    int p0 = slot[2*t], p1 = slot[2*t + 1];
    const float4 ya = *(const float4*)(Y + (size_t)p0 * DD + d);
    const float4 yb = *(const float4*)(Y + (size_t)p1 * DD + d);
    float f0 = feats[2*t], f1 = feats[2*t + 1];
    f0 = fminf(fmaxf(f0, -10.f), 10.f);
    f1 = fminf(fmaxf(f1, -10.f), 10.f);
    float ff[4] = {ya.x + yb.x, ya.y + yb.y, ya.z + yb.z, ya.w + yb.w};
    float4 o;
    float* op = (float*)&o;
    #pragma unroll
    for (int u = 0; u < 4; u++) {
        float spec = f0 * out_w[d + u] + f1 * out_w[DD + d + u] + out_b[d + u];
        op[u] = ff[u] + bk_scale[d + u] * spec;
    }
    *(float4*)(out + base) = o;
}

extern "C" void kernel_launch(void* const* d_in, const int* in_sizes, int n_in,
                              void* d_out, int out_size, void* d_ws, size_t ws_size,
                              hipStream_t stream)
{
    const float* x      = (const float*)d_in[0];
    const float* v_w    = (const float*)d_in[1];
    const float* v_b    = (const float*)d_in[2];
    const float* gate_w = (const float*)d_in[3];
    const float* gate_b = (const float*)d_in[4];
    const float* w1     = (const float*)d_in[5];
    const float* b1     = (const float*)d_in[6];
    const float* w2     = (const float*)d_in[7];
    const float* b2     = (const float*)d_in[8];
    const float* out_w  = (const float*)d_in[9];
    const float* out_b  = (const float*)d_in[10];
    const float* bk_s   = (const float*)d_in[11];

    char* ws = (char*)d_ws;
    int*    ctrl    = (int*)(ws + OFF_CTRL);
    float*  v       = (float*)(ws + OFF_V);
    int*    tok_e   = (int*)(ws + OFF_TOKE);
    float*  tok_w   = (float*)(ws + OFF_TOKW);
    int*    row_tok = (int*)(ws + OFF_ROWTOK);
    float*  row_w   = (float*)(ws + OFF_ROWW);
    int*    slot    = (int*)(ws + OFF_SLOT);
    float*  feats   = (float*)(ws + OFF_FEATS);
    ushort* w2t     = (ushort*)(ws + OFF_W2T);
    ushort* x_bf    = (ushort*)(ws + OFF_XBF);
    ushort* w1t     = (ushort*)(ws + OFF_W1T);
    ushort* H       = (ushort*)(ws + OFF_H);
    float*  Y       = (float*)(ws + OFF_Y);
    float*  out     = (float*)d_out;

    cvt_kernel<<<(TOK*DD)/8/256, 256, 0, stream>>>(x, x_bf, (TOK*DD)/8);
    // w1: [e][768][3072] -> w1t [e][3072][768]
    tcvt_kernel<<<dim3(FF/32, DD/32, EE), 256, 0, stream>>>(w1, w1t, DD, FF);
    // w2: [e][3072][768] -> w2t [e][768][3072]
    tcvt_kernel<<<dim3(DD/32, FF/32, EE), 256, 0, stream>>>(w2, w2t, FF, DD);
    routing_kernel<<<TOK / 4, 256, 0, stream>>>(x, v_w, v_b, gate_w, gate_b, v, tok_e, tok_w);
    setup_scatter_kernel<<<1, 1024, 0, stream>>>(tok_e, tok_w, ctrl, row_tok, row_w, slot);
    bk_scan_kernel<<<BB, 256, 0, stream>>>(v, feats);
    gemm1_kernel<<<dim3(FF / 128, TILES), 256, 0, stream>>>(x_bf, w1t, b1, ctrl, row_tok, H);
    gemm2_kernel<<<dim3(TILES, DD / 128), 256, 0, stream>>>(H, w2t, b2, ctrl, row_w, Y);
    final_kernel<<<(TOK * DD) / 1024, 256, 0, stream>>>(Y, slot, feats, out_w, out_b, bk_s, out);
}

// Round 4
// 217.755 us; speedup vs baseline: 1.1983x; 1.1762x over previous
//
#include <hip/hip_runtime.h>
#include <hip/hip_bf16.h>

#define BB 2
#define NN 2048
#define DD 768
#define EE 8
#define FF 3072
#define TOK (BB*NN)       // 4096
#define ROWS_CAP 9216     // 8192 slots + 8*128 alignment pad
#define TILES 72          // ROWS_CAP / 128

typedef __attribute__((ext_vector_type(8))) __bf16 bf16x8;
typedef __attribute__((ext_vector_type(4))) float floatx4;

// ---------- ws layout (bytes) ----------
#define OFF_CTRL    0ull                    // int[96]: base@16, tile_expert@24
#define OFF_V       1024ull                 // float[4096]
#define OFF_TOKE    17408ull                // int[8192]
#define OFF_TOKW    50176ull                // float[8192]
#define OFF_ROWTOK  82944ull                // int[9216]
#define OFF_ROWW    119808ull               // float[9216]
#define OFF_SLOT    156672ull               // int[8192]
#define OFF_FEATS   189440ull               // float[8192]
// big buffers
#define OFF_W2T     222208ull               // ushort[8*768*3072] = 37,748,736 B   (w2^T: [e][d][f])
#define OFF_XBF     37970944ull             // ushort[4096*768]   = 6,291,456 B
#define OFF_W1T     44262400ull             // ushort[8*3072*768] = 37,748,736 B   (w1^T: [e][f][d])
#define OFF_H       82011136ull             // ushort[9216*3072]  = 56,623,104 B -> end 138,634,240
#define OFF_Y       OFF_XBF                 // float[9216*768] = 28,311,552 B, aliases dead XBF+W1T

__device__ __forceinline__ ushort f2b(float f) {
    union { float f; unsigned int i; } v; v.f = f;
    unsigned int u = v.i;
    unsigned int r = (u + 0x7FFFu + ((u >> 16) & 1u)) >> 16;
    return (ushort)r;
}
__device__ __forceinline__ unsigned int pk2(float lo, float hi) {
    union { float f; unsigned int u; } a, b;
    a.f = lo; b.f = hi;
    unsigned int ra = ((a.u + 0x7FFFu + ((a.u >> 16) & 1u)) >> 16) & 0xFFFFu;
    unsigned int rb = (b.u + 0x7FFFu + ((b.u >> 16) & 1u)) & 0xFFFF0000u;
    return ra | rb;
}
__device__ __forceinline__ float gelu_f(float x) {
    float z = 0.7978845608028654f * x * (1.f + 0.044715f * x * x);
    z = fminf(fmaxf(z, -12.f), 12.f);
    float e = __expf(2.f * z);
    return 0.5f * x * (1.f + (e - 1.f) / (e + 1.f));
}
// async global(16B/lane) -> LDS (wave-uniform base + lane*16)
__device__ __forceinline__ void gload16(const ushort* g, ushort* l) {
    __builtin_amdgcn_global_load_lds((const __attribute__((address_space(1))) void*)g,
                                     (__attribute__((address_space(3))) void*)l,
                                     16, 0, 0);
}

// ---------- complex / Mobius helpers ----------
struct cplx { float x, y; };
__device__ __forceinline__ cplx cmulc(cplx a, cplx b) { return {a.x*b.x - a.y*b.y, a.x*b.y + a.y*b.x}; }
__device__ __forceinline__ cplx caddc(cplx a, cplx b) { return {a.x + b.x, a.y + b.y}; }
__device__ __forceinline__ cplx cdivc(cplx a, cplx b) {
    float s = 1.f / (b.x*b.x + b.y*b.y);
    return {(a.x*b.x + a.y*b.y)*s, (a.y*b.x - a.x*b.y)*s};
}
struct mob { cplx m00, m01, m10, m11; };
__device__ __forceinline__ mob mmul(const mob& A, const mob& B) {
    mob C;
    C.m00 = caddc(cmulc(A.m00, B.m00), cmulc(A.m01, B.m10));
    C.m01 = caddc(cmulc(A.m00, B.m01), cmulc(A.m01, B.m11));
    C.m10 = caddc(cmulc(A.m10, B.m00), cmulc(A.m11, B.m10));
    C.m11 = caddc(cmulc(A.m10, B.m01), cmulc(A.m11, B.m11));
    return C;
}
__device__ __forceinline__ void mnorm(mob& A) {
    float s = fabsf(A.m00.x);
    s = fmaxf(s, fabsf(A.m00.y)); s = fmaxf(s, fabsf(A.m01.x)); s = fmaxf(s, fabsf(A.m01.y));
    s = fmaxf(s, fabsf(A.m10.x)); s = fmaxf(s, fabsf(A.m10.y)); s = fmaxf(s, fabsf(A.m11.x));
    s = fmaxf(s, fabsf(A.m11.y));
    float r = 1.f / fmaxf(s, 1e-30f);
    A.m00.x *= r; A.m00.y *= r; A.m01.x *= r; A.m01.y *= r;
    A.m10.x *= r; A.m10.y *= r; A.m11.x *= r; A.m11.y *= r;
}
__device__ __forceinline__ mob mstep(cplx a, const mob& P) {
    mob C;
    C.m00 = {a.x*P.m00.x - a.y*P.m00.y - P.m10.x, a.x*P.m00.y + a.y*P.m00.x - P.m10.y};
    C.m01 = {a.x*P.m01.x - a.y*P.m01.y - P.m11.x, a.x*P.m01.y + a.y*P.m01.x - P.m11.y};
    C.m10 = P.m00; C.m11 = P.m01;
    return C;
}
__device__ __forceinline__ void mstore(float* s, const mob& A) {
    s[0]=A.m00.x; s[1]=A.m00.y; s[2]=A.m01.x; s[3]=A.m01.y;
    s[4]=A.m10.x; s[5]=A.m10.y; s[6]=A.m11.x; s[7]=A.m11.y;
}
__device__ __forceinline__ mob mload(const float* s) {
    mob A;
    A.m00 = {s[0], s[1]}; A.m01 = {s[2], s[3]};
    A.m10 = {s[4], s[5]}; A.m11 = {s[6], s[7]};
    return A;
}

// ================= PREP: fused {x->bf16 cvt | routing | w1^T cvt | w2^T cvt} =================
// Independent memory-bound phases overlapped in ONE launch (block-range dispatch)
// instead of 4 serial launches; saves 3 launch gaps + overlaps ~145MB of traffic.
#define NB_CVT   ((TOK*DD)/8/256)           // 1536
#define NB_ROUTE (TOK/4)                    // 1024
#define NB_T1    ((FF/32)*(DD/32)*EE)       // 18432  (w1: R=DD rows, C=FF cols)
#define NB_T2    ((DD/32)*(FF/32)*EE)       // 18432  (w2: R=FF, C=DD)

__device__ __forceinline__ void cvt_body(const float* __restrict__ src, ushort* __restrict__ dst, int i) {
    const float4* s = ((const float4*)src) + (size_t)i * 2;
    float4 a = s[0], b = s[1];
    uint4 o;
    o.x = pk2(a.x, a.y); o.y = pk2(a.z, a.w);
    o.z = pk2(b.x, b.y); o.w = pk2(b.z, b.w);
    *(((uint4*)dst) + i) = o;
}

__device__ __forceinline__ void tcvt_body(const float* __restrict__ src, ushort* __restrict__ dst,
                                          int R, int C, int bx, int by, int bz,
                                          float (*t)[33]) {
    size_t eoff = (size_t)bz * R * C;
    const float* s = src + eoff;
    ushort* d = dst + eoff;
    int c0 = bx * 32, r0 = by * 32;
    int tid = threadIdx.x;
    int tr = tid >> 3, tc = (tid & 7) * 4;
    float4 vsrc = *(const float4*)(s + (size_t)(r0 + tr) * C + c0 + tc);
    t[tr][tc] = vsrc.x; t[tr][tc+1] = vsrc.y; t[tr][tc+2] = vsrc.z; t[tr][tc+3] = vsrc.w;
    __syncthreads();
    ushort4 o;
    o.x = f2b(t[tc  ][tr]);
    o.y = f2b(t[tc+1][tr]);
    o.z = f2b(t[tc+2][tr]);
    o.w = f2b(t[tc+3][tr]);
    *(ushort4*)(d + (size_t)(c0 + tr) * R + r0 + tc) = o;
}

__device__ __forceinline__ void routing_body(
    const float* __restrict__ x, const float* __restrict__ v_w, const float* __restrict__ v_b,
    const float* __restrict__ gate_w, const float* __restrict__ gate_b,
    float* __restrict__ v_out, int* __restrict__ tok_e, float* __restrict__ tok_w, int blk)
{
    int wave = threadIdx.x >> 6, lane = threadIdx.x & 63;
    int t = blk * 4 + wave;
    const float* xr = x + (size_t)t * DD;
    float av = 0.f;
    float ag[8] = {0.f, 0.f, 0.f, 0.f, 0.f, 0.f, 0.f, 0.f};
    #pragma unroll
    for (int i = 0; i < 12; i++) {
        int d = lane + 64 * i;
        float xv = xr[d];
        av += xv * v_w[d];
        const float4* g = (const float4*)(gate_w + d * 8);
        float4 g0 = g[0], g1 = g[1];
        ag[0] += xv * g0.x; ag[1] += xv * g0.y; ag[2] += xv * g0.z; ag[3] += xv * g0.w;
        ag[4] += xv * g1.x; ag[5] += xv * g1.y; ag[6] += xv * g1.z; ag[7] += xv * g1.w;
    }
    #pragma unroll
    for (int off = 32; off >= 1; off >>= 1) {
        av += __shfl_xor(av, off);
        #pragma unroll
        for (int e = 0; e < 8; e++) ag[e] += __shfl_xor(ag[e], off);
    }
    if (lane == 0) {
        float vv = av + v_b[0];
        vv = fminf(fmaxf(vv, -3.f), 3.f);
        v_out[t] = vv;
        float lg[8];
        #pragma unroll
        for (int e = 0; e < 8; e++) lg[e] = ag[e] + gate_b[e];
        int e0 = 0;
        #pragma unroll
        for (int e = 1; e < 8; e++) if (lg[e] > lg[e0]) e0 = e;
        int e1 = -1;
        #pragma unroll
        for (int e = 0; e < 8; e++) if (e != e0 && (e1 < 0 || lg[e] > lg[e1])) e1 = e;
        float w0 = 1.f / (1.f + __expf(lg[e1] - lg[e0]));
        tok_e[2*t] = e0; tok_e[2*t+1] = e1;
        tok_w[2*t] = w0; tok_w[2*t+1] = 1.f - w0;
    }
}

__global__ __launch_bounds__(256) void prep_kernel(
    const float* __restrict__ x, ushort* __restrict__ x_bf,
    const float* __restrict__ v_w, const float* __restrict__ v_b,
    const float* __restrict__ gate_w, const float* __restrict__ gate_b,
    float* __restrict__ v_out, int* __restrict__ tok_e, float* __restrict__ tok_w,
    const float* __restrict__ w1, ushort* __restrict__ w1t,
    const float* __restrict__ w2, ushort* __restrict__ w2t)
{
    __shared__ float t[32][33];
    int id = blockIdx.x;
    if (id < NB_CVT) {
        cvt_body(x, x_bf, id * 256 + threadIdx.x);
        return;
    }
    id -= NB_CVT;
    if (id < NB_ROUTE) {
        routing_body(x, v_w, v_b, gate_w, gate_b, v_out, tok_e, tok_w, id);
        return;
    }
    id -= NB_ROUTE;
    if (id < NB_T1) {
        int bx = id % (FF/32); int by = (id / (FF/32)) % (DD/32); int bz = id / ((FF/32)*(DD/32));
        tcvt_body(w1, w1t, DD, FF, bx, by, bz, t);
        return;
    }
    id -= NB_T1;
    {
        int bx = id % (DD/32); int by = (id / (DD/32)) % (FF/32); int bz = id / ((DD/32)*(FF/32));
        tcvt_body(w2, w2t, FF, DD, bx, by, bz, t);
    }
}

// ============ SETUP+BK: block 0 = scatter setup (1024 thr), blocks 1..2 = BK scan ============
__device__ void setup_body(
    const int* __restrict__ tok_e, const float* __restrict__ tok_w,
    int* __restrict__ ctrl, int* __restrict__ row_token, float* __restrict__ row_w,
    int* __restrict__ slot)
{
    __shared__ int cnt[8], base[8], cursor[8];
    int tid = threadIdx.x;
    int lane = tid & 63;
    if (tid < 8) { cnt[tid] = 0; cursor[tid] = 0; }
    __syncthreads();

    int mye[8];
    #pragma unroll
    for (int it = 0; it < 8; it++) {
        int idx = it * 1024 + tid;
        int e = tok_e[idx];
        mye[it] = e;
        #pragma unroll
        for (int ex = 0; ex < 8; ex++) {
            unsigned long long m = __ballot(e == ex);
            if (e == ex && lane == (__ffsll((long long)m) - 1))
                atomicAdd(&cnt[ex], (int)__popcll(m));
        }
    }
    __syncthreads();
    if (tid == 0) {
        int b = 0;
        int* te = ctrl + 24;
        for (int i = 0; i < TILES; i++) te[i] = -1;
        #pragma unroll
        for (int e = 0; e < EE; e++) {
            base[e] = b;
            ctrl[16 + e] = b;
            int tiles = (cnt[e] + 127) >> 7;
            int t0 = b >> 7;
            for (int i = 0; i < tiles; i++) te[t0 + i] = e;
            b += tiles << 7;
        }
    }
    for (int p = tid; p < ROWS_CAP; p += 1024) row_token[p] = -1;
    __syncthreads();

    #pragma unroll
    for (int it = 0; it < 8; it++) {
        int idx = it * 1024 + tid;
        int e = mye[it];
        unsigned long long lt = (1ull << lane) - 1ull;
        int p = 0;
        #pragma unroll
        for (int ex = 0; ex < 8; ex++) {
            unsigned long long m = __ballot(e == ex);
            if (e == ex) {
                int leader = __ffsll((long long)m) - 1;
                int pos = (int)__popcll(m & lt);
                int bp = 0;
                if (lane == leader) bp = atomicAdd(&cursor[ex], (int)__popcll(m));
                bp = __shfl(bp, leader);
                p = base[ex] + bp + pos;
            }
        }
        row_token[p] = idx >> 1;
        row_w[p] = tok_w[idx];
        slot[idx] = p;
    }
}

// BK scan body for one batch row; runs inside a 1024-thread block: threads >=256
// only participate in barriers (all __syncthreads in uniform control flow).
__device__ void bk_body(int b, const float* __restrict__ v, float* __restrict__ feats) {
    int t = threadIdx.x;
    bool act = t < 256;
    __shared__ float sm[256][8];
    const mob I = {{1.f,0.f},{0.f,0.f},{0.f,0.f},{1.f,0.f}};
    cplx a[8];
    const float* vb = v + (size_t)b * NN;
    if (act) {
        #pragma unroll
        for (int j = 0; j < 8; j++) { a[j].x = -2.f + vb[t*8 + j]; a[j].y = -1.f; }
    }

    mob cur = I;
    if (act) {
        #pragma unroll
        for (int j = 0; j < 8; j++) cur = mstep(a[j], cur);
        mnorm(cur);
        mstore(sm[t], cur);
    }
    for (int s = 1; s < 256; s <<= 1) {
        __syncthreads();
        mob prev; bool has = act && (t >= s);
        if (has) prev = mload(sm[t - s]);
        __syncthreads();
        if (has) { cur = mmul(cur, prev); mnorm(cur); mstore(sm[t], cur); }
    }
    __syncthreads();
    cplx dreg[8];
    if (act) {
        mob P = (t > 0) ? mload(sm[t - 1]) : I;
        #pragma unroll
        for (int j = 0; j < 8; j++) {
            P = mstep(a[j], P); mnorm(P);
            dreg[j] = cdivc(P.m00, P.m10);
        }
    }
    __syncthreads();

    cur = I;
    if (act) {
        #pragma unroll
        for (int j = 7; j >= 0; j--) cur = mstep(a[j], cur);
        mnorm(cur);
        mstore(sm[t], cur);
    }
    for (int s = 1; s < 256; s <<= 1) {
        __syncthreads();
        mob nxt; bool has = act && (t + s < 256);
        if (has) nxt = mload(sm[t + s]);
        __syncthreads();
        if (has) { cur = mmul(cur, nxt); mnorm(cur); mstore(sm[t], cur); }
    }
    __syncthreads();
    if (act) {
        mob P = (t < 255) ? mload(sm[t + 1]) : I;
        #pragma unroll
        for (int j = 7; j >= 0; j--) {
            P = mstep(a[j], P); mnorm(P);
            cplx e = cdivc(P.m00, P.m10);
            cplx den = {dreg[j].x + e.x - a[j].x, dreg[j].y + e.y - a[j].y};
            cplx one = {1.f, 0.f};
            cplx G = cdivc(one, den);
            int i = b * NN + t*8 + j;
            feats[2*i]   = G.x;
            feats[2*i+1] = G.y;
        }
    }
}

__global__ __launch_bounds__(1024) void setup_bk_kernel(
    const int* __restrict__ tok_e, const float* __restrict__ tok_w,
    int* __restrict__ ctrl, int* __restrict__ row_token, float* __restrict__ row_w,
    int* __restrict__ slot, const float* __restrict__ v, float* __restrict__ feats)
{
    if (blockIdx.x == 0) setup_body(tok_e, tok_w, ctrl, row_token, row_w, slot);
    else                 bk_body(blockIdx.x - 1, v, feats);
}

// ===== GEMM K-loop: 2-deep pipeline, counted vmcnt, raw barriers (T3/T4-lite) =====
// LDS swizzle unchanged from round 1/2 (0 bank conflicts): slot p holds
// (r=p>>2, q=(p&3)^((r>>1)&3)); global src pre-swizzled (kq), ds_read XOR (qx).
//
// Pipeline invariants (4 gloads per wave per group):
//   prologue: stage group0->slot0, group1->slot1 (8 in flight)
//   iter ks:  vmcnt(4) [group ks arrived; vmcnt(0) on last iter]
//             s_barrier            [all waves' quarters arrived]
//             ds_read fragments from slot ks&1
//             lgkmcnt(0); sched_barrier  [reads landed in regs]
//             s_barrier            [slot ks&1 free to overwrite]
//             stage group ks+2 -> slot ks&1   [stays in flight across barriers]
//             setprio(1); 16 MFMA; setprio(0)
// No vmcnt(0) drain in steady state: stage latency spans 2 full iterations.
#define STAGE1(AW, BW, k0) do { \
        gload16(aglob0 + (k0), (AW)); \
        gload16(aglob1 + (k0), (AW) + 16*32); \
        gload16(bglob0 + (k0), (BW)); \
        gload16(bglob1 + (k0), (BW) + 16*32); } while (0)

#define LOADFR2(APTR, BPTR) do { \
        _Pragma("unroll") \
        for (int i = 0; i < 4; i++) \
            afr[i] = *(const bf16x8*)(const void*)((APTR) + (wm + i*16 + lm) * 32 + qx); \
        _Pragma("unroll") \
        for (int j = 0; j < 4; j++) \
            bfr[j] = *(const bf16x8*)(const void*)((BPTR) + (wn + j*16 + lm) * 32 + qx); \
    } while (0)

#define MFMAS() do { \
        _Pragma("unroll") \
        for (int i = 0; i < 4; i++) \
            _Pragma("unroll") \
            for (int j = 0; j < 4; j++) \
                acc[i][j] = __builtin_amdgcn_mfma_f32_16x16x32_bf16(afr[i], bfr[j], acc[i][j], 0, 0, 0); \
    } while (0)

#define PIPE_LOOP(NK) do { \
    STAGE1(AsW0, BsW0, 0); \
    STAGE1(AsW1, BsW1, 32); \
    for (int ks = 0; ks < (NK); ks++) { \
        int cur = ks & 1; \
        const ushort* Ab = cur ? As[1] : As[0]; \
        const ushort* Bb = cur ? Bs[1] : Bs[0]; \
        ushort* AsN = cur ? AsW1 : AsW0; \
        ushort* BsN = cur ? BsW1 : BsW0; \
        if (ks < (NK) - 1) { asm volatile("s_waitcnt vmcnt(4)" ::: "memory"); } \
        else               { asm volatile("s_waitcnt vmcnt(0)" ::: "memory"); } \
        __builtin_amdgcn_s_barrier(); \
        bf16x8 afr[4], bfr[4]; \
        LOADFR2(Ab, Bb); \
        asm volatile("s_waitcnt lgkmcnt(0)" ::: "memory"); \
        __builtin_amdgcn_sched_barrier(0); \
        __builtin_amdgcn_s_barrier(); \
        if (ks + 2 < (NK)) STAGE1(AsN, BsN, ks*32 + 64); \
        __builtin_amdgcn_s_setprio(1); \
        MFMAS(); \
        __builtin_amdgcn_s_setprio(0); \
    } } while (0)

// ---------- K5: GEMM1  H = gelu(Xg @ w1t[e]^T + b1[e]) ----------
// grid = (FF/128, TILES): f-block fast dim -> same-(e,f) weight panels land on
// the same XCD L2 (delta 24 % 8 == 0). FETCH 62MB confirmed round 2.
__global__ __launch_bounds__(256) void gemm1_kernel(
    const ushort* __restrict__ x_bf, const ushort* __restrict__ w1t, const float* __restrict__ b1,
    const int* __restrict__ ctrl, const int* __restrict__ row_token, ushort* __restrict__ H)
{
    int tile = blockIdx.y;
    int e = ctrl[24 + tile];
    if (e < 0) return;
    int p0 = tile * 128;
    int f0 = blockIdx.x * 128;

    __shared__ ushort As[2][128 * 32];
    __shared__ ushort Bs[2][128 * 32];
    __shared__ int toks[128];

    int tid = threadIdx.x;
    if (tid < 128) { int tk = row_token[p0 + tid]; toks[tid] = tk < 0 ? 0 : tk; }
    __syncthreads();

    int wave = tid >> 6, lane = tid & 63;
    int rsub = lane >> 2;                                  // row within 16-row stage group
    int kq = (((lane & 3) ^ ((rsub >> 1) & 3))) * 8;       // swizzled global k-quad (ushorts)
    int tokA0 = toks[wave*32 + rsub];
    int tokA1 = toks[wave*32 + 16 + rsub];
    const ushort* aglob0 = x_bf + (size_t)tokA0 * DD + kq;
    const ushort* aglob1 = x_bf + (size_t)tokA1 * DD + kq;
    const ushort* w1e = w1t + (size_t)e * (FF * DD);       // [f][d] row stride DD
    const ushort* bglob0 = w1e + (size_t)(f0 + wave*32 + rsub) * DD + kq;
    const ushort* bglob1 = bglob0 + (size_t)16 * DD;
    ushort* AsW0 = &As[0][wave * 32 * 32];
    ushort* BsW0 = &Bs[0][wave * 32 * 32];
    ushort* AsW1 = &As[1][wave * 32 * 32];
    ushort* BsW1 = &Bs[1][wave * 32 * 32];

    floatx4 zero4 = {0.f, 0.f, 0.f, 0.f};
    floatx4 acc[4][4];
    #pragma unroll
    for (int i = 0; i < 4; i++)
        #pragma unroll
        for (int j = 0; j < 4; j++) acc[i][j] = zero4;

    int wm = (wave & 1) * 64, wn = (wave >> 1) * 64;
    int lm = lane & 15, q = lane >> 4;
    int qx = (q ^ ((lm >> 1) & 3)) * 8;                    // swizzled ds_read k-quad

    PIPE_LOOP(DD/32);

    #pragma unroll
    for (int i = 0; i < 4; i++) {
        #pragma unroll
        for (int j = 0; j < 4; j++) {
            int n = wn + j*16 + lm;
            float bias = b1[e * FF + f0 + n];
            #pragma unroll
            for (int r = 0; r < 4; r++) {
                int m = wm + i*16 + q*4 + r;
                float hv = gelu_f(acc[i][j][r] + bias);
                H[(size_t)(p0 + m) * FF + f0 + n] = f2b(hv);
            }
        }
    }
}

// ---------- K6: GEMM2  Y = row_w * (H @ w2t[e]^T + b2[e]) ----------
__global__ __launch_bounds__(256) void gemm2_kernel(
    const ushort* __restrict__ H, const ushort* __restrict__ w2t, const float* __restrict__ b2,
    const int* __restrict__ ctrl, const float* __restrict__ row_w, float* __restrict__ Y)
{
    int tile = blockIdx.x;
    int e = ctrl[24 + tile];
    if (e < 0) return;
    int p0 = tile * 128;
    int d0 = blockIdx.y * 128;

    __shared__ ushort As[2][128 * 32];
    __shared__ ushort Bs[2][128 * 32];

    int tid = threadIdx.x;
    int wave = tid >> 6, lane = tid & 63;
    int rsub = lane >> 2;
    int kq = (((lane & 3) ^ ((rsub >> 1) & 3))) * 8;
    const ushort* aglob0 = H + (size_t)(p0 + wave*32 + rsub) * FF + kq;
    const ushort* aglob1 = aglob0 + (size_t)16 * FF;
    const ushort* w2e = w2t + (size_t)e * (DD * FF);      // [d][f] row stride FF
    const ushort* bglob0 = w2e + (size_t)(d0 + wave*32 + rsub) * FF + kq;
    const ushort* bglob1 = bglob0 + (size_t)16 * FF;
    ushort* AsW0 = &As[0][wave * 32 * 32];
    ushort* BsW0 = &Bs[0][wave * 32 * 32];
    ushort* AsW1 = &As[1][wave * 32 * 32];
    ushort* BsW1 = &Bs[1][wave * 32 * 32];

    floatx4 zero4 = {0.f, 0.f, 0.f, 0.f};
    floatx4 acc[4][4];
    #pragma unroll
    for (int i = 0; i < 4; i++)
        #pragma unroll
        for (int j = 0; j < 4; j++) acc[i][j] = zero4;

    int wm = (wave & 1) * 64, wn = (wave >> 1) * 64;
    int lm = lane & 15, q = lane >> 4;
    int qx = (q ^ ((lm >> 1) & 3)) * 8;

    PIPE_LOOP(FF/32);

    #pragma unroll
    for (int i = 0; i < 4; i++) {
        #pragma unroll
        for (int j = 0; j < 4; j++) {
            int n = wn + j*16 + lm;
            float bias = b2[e * DD + d0 + n];
            #pragma unroll
            for (int r = 0; r < 4; r++) {
                int m = wm + i*16 + q*4 + r;
                float wgt = row_w[p0 + m];
                Y[(size_t)(p0 + m) * DD + d0 + n] = wgt * (acc[i][j][r] + bias);
            }
        }
    }
}

// ---------- K7: final combine (fp32 out) ----------
__global__ __launch_bounds__(256) void final_kernel(
    const float* __restrict__ Y, const int* __restrict__ slot, const float* __restrict__ feats,
    const float* __restrict__ out_w, const float* __restrict__ out_b,
    const float* __restrict__ bk_scale, float* __restrict__ out)
{
    int idx = blockIdx.x * 256 + threadIdx.x;
    int base = idx * 4;
    int t = base / DD;
    int d = base - t * DD;
    int p0 = slot[2*t], p1 = slot[2*t + 1];
    const float4 ya = *(const float4*)(Y + (size_t)p0 * DD + d);
    const float4 yb = *(const float4*)(Y + (size_t)p1 * DD + d);
    float f0 = feats[2*t], f1 = feats[2*t + 1];
    f0 = fminf(fmaxf(f0, -10.f), 10.f);
    f1 = fminf(fmaxf(f1, -10.f), 10.f);
    float ff[4] = {ya.x + yb.x, ya.y + yb.y, ya.z + yb.z, ya.w + yb.w};
    float4 o;
    float* op = (float*)&o;
    #pragma unroll
    for (int u = 0; u < 4; u++) {
        float spec = f0 * out_w[d + u] + f1 * out_w[DD + d + u] + out_b[d + u];
        op[u] = ff[u] + bk_scale[d + u] * spec;
    }
    *(float4*)(out + base) = o;
}

extern "C" void kernel_launch(void* const* d_in, const int* in_sizes, int n_in,
                              void* d_out, int out_size, void* d_ws, size_t ws_size,
                              hipStream_t stream)
{
    const float* x      = (const float*)d_in[0];
    const float* v_w    = (const float*)d_in[1];
    const float* v_b    = (const float*)d_in[2];
    const float* gate_w = (const float*)d_in[3];
    const float* gate_b = (const float*)d_in[4];
    const float* w1     = (const float*)d_in[5];
    const float* b1     = (const float*)d_in[6];
    const float* w2     = (const float*)d_in[7];
    const float* b2     = (const float*)d_in[8];
    const float* out_w  = (const float*)d_in[9];
    const float* out_b  = (const float*)d_in[10];
    const float* bk_s   = (const float*)d_in[11];

    char* ws = (char*)d_ws;
    int*    ctrl    = (int*)(ws + OFF_CTRL);
    float*  v       = (float*)(ws + OFF_V);
    int*    tok_e   = (int*)(ws + OFF_TOKE);
    float*  tok_w   = (float*)(ws + OFF_TOKW);
    int*    row_tok = (int*)(ws + OFF_ROWTOK);
    float*  row_w   = (float*)(ws + OFF_ROWW);
    int*    slot    = (int*)(ws + OFF_SLOT);
    float*  feats   = (float*)(ws + OFF_FEATS);
    ushort* w2t     = (ushort*)(ws + OFF_W2T);
    ushort* x_bf    = (ushort*)(ws + OFF_XBF);
    ushort* w1t     = (ushort*)(ws + OFF_W1T);
    ushort* H       = (ushort*)(ws + OFF_H);
    float*  Y       = (float*)(ws + OFF_Y);
    float*  out     = (float*)d_out;

    prep_kernel<<<NB_CVT + NB_ROUTE + NB_T1 + NB_T2, 256, 0, stream>>>(
        x, x_bf, v_w, v_b, gate_w, gate_b, v, tok_e, tok_w, w1, w1t, w2, w2t);
    setup_bk_kernel<<<1 + BB, 1024, 0, stream>>>(tok_e, tok_w, ctrl, row_tok, row_w, slot, v, feats);
    gemm1_kernel<<<dim3(FF / 128, TILES), 256, 0, stream>>>(x_bf, w1t, b1, ctrl, row_tok, H);
    gemm2_kernel<<<dim3(TILES, DD / 128), 256, 0, stream>>>(H, w2t, b2, ctrl, row_w, Y);
    final_kernel<<<(TOK * DD) / 1024, 256, 0, stream>>>(Y, slot, feats, out_w, out_b, bk_s, out);
}

// Round 5
// 209.909 us; speedup vs baseline: 1.2431x; 1.0374x over previous
//
#include <hip/hip_runtime.h>
#include <hip/hip_bf16.h>

#define BB 2
#define NN 2048
#define DD 768
#define EE 8
#define FF 3072
#define TOK (BB*NN)       // 4096
#define ROWS_CAP 9216     // 8192 slots + 8*128 alignment pad
#define TILES 72          // ROWS_CAP / 128

typedef __attribute__((ext_vector_type(8))) __bf16 bf16x8;
typedef __attribute__((ext_vector_type(4))) float floatx4;

// ---------- ws layout (bytes) ----------
#define OFF_CTRL    0ull                    // int[96]: base@16, tile_expert@24
#define OFF_V       1024ull                 // float[4096]
#define OFF_TOKE    17408ull                // int[8192]
#define OFF_TOKW    50176ull                // float[8192]
#define OFF_ROWTOK  82944ull                // int[9216]
#define OFF_ROWW    119808ull               // float[9216]
#define OFF_SLOT    156672ull               // int[8192]
#define OFF_FEATS   189440ull               // float[8192]
// big buffers
#define OFF_W2T     222208ull               // ushort[8*768*3072] = 37,748,736 B   (w2^T: [e][d][f])
#define OFF_XBF     37970944ull             // ushort[4096*768]   = 6,291,456 B
#define OFF_W1T     44262400ull             // ushort[8*3072*768] = 37,748,736 B   (w1^T: [e][f][d])
#define OFF_H       82011136ull             // ushort[9216*3072]  = 56,623,104 B -> end 138,634,240
#define OFF_Y       OFF_XBF                 // float[9216*768] = 28,311,552 B, aliases dead XBF+W1T

__device__ __forceinline__ ushort f2b(float f) {
    union { float f; unsigned int i; } v; v.f = f;
    unsigned int u = v.i;
    unsigned int r = (u + 0x7FFFu + ((u >> 16) & 1u)) >> 16;
    return (ushort)r;
}
__device__ __forceinline__ unsigned int pk2(float lo, float hi) {
    union { float f; unsigned int u; } a, b;
    a.f = lo; b.f = hi;
    unsigned int ra = ((a.u + 0x7FFFu + ((a.u >> 16) & 1u)) >> 16) & 0xFFFFu;
    unsigned int rb = (b.u + 0x7FFFu + ((b.u >> 16) & 1u)) & 0xFFFF0000u;
    return ra | rb;
}
__device__ __forceinline__ float gelu_f(float x) {
    float z = 0.7978845608028654f * x * (1.f + 0.044715f * x * x);
    z = fminf(fmaxf(z, -12.f), 12.f);
    float e = __expf(2.f * z);
    return 0.5f * x * (1.f + (e - 1.f) / (e + 1.f));
}
// async global(16B/lane) -> LDS (wave-uniform base + lane*16)
__device__ __forceinline__ void gload16(const ushort* g, ushort* l) {
    __builtin_amdgcn_global_load_lds((const __attribute__((address_space(1))) void*)g,
                                     (__attribute__((address_space(3))) void*)l,
                                     16, 0, 0);
}

// ---------- complex / Mobius helpers ----------
struct cplx { float x, y; };
__device__ __forceinline__ cplx cmulc(cplx a, cplx b) { return {a.x*b.x - a.y*b.y, a.x*b.y + a.y*b.x}; }
__device__ __forceinline__ cplx caddc(cplx a, cplx b) { return {a.x + b.x, a.y + b.y}; }
__device__ __forceinline__ cplx cdivc(cplx a, cplx b) {
    float s = 1.f / (b.x*b.x + b.y*b.y);
    return {(a.x*b.x + a.y*b.y)*s, (a.y*b.x - a.x*b.y)*s};
}
struct mob { cplx m00, m01, m10, m11; };
__device__ __forceinline__ mob mmul(const mob& A, const mob& B) {
    mob C;
    C.m00 = caddc(cmulc(A.m00, B.m00), cmulc(A.m01, B.m10));
    C.m01 = caddc(cmulc(A.m00, B.m01), cmulc(A.m01, B.m11));
    C.m10 = caddc(cmulc(A.m10, B.m00), cmulc(A.m11, B.m10));
    C.m11 = caddc(cmulc(A.m10, B.m01), cmulc(A.m11, B.m11));
    return C;
}
__device__ __forceinline__ void mnorm(mob& A) {
    float s = fabsf(A.m00.x);
    s = fmaxf(s, fabsf(A.m00.y)); s = fmaxf(s, fabsf(A.m01.x)); s = fmaxf(s, fabsf(A.m01.y));
    s = fmaxf(s, fabsf(A.m10.x)); s = fmaxf(s, fabsf(A.m10.y)); s = fmaxf(s, fabsf(A.m11.x));
    s = fmaxf(s, fabsf(A.m11.y));
    float r = 1.f / fmaxf(s, 1e-30f);
    A.m00.x *= r; A.m00.y *= r; A.m01.x *= r; A.m01.y *= r;
    A.m10.x *= r; A.m10.y *= r; A.m11.x *= r; A.m11.y *= r;
}
__device__ __forceinline__ mob mstep(cplx a, const mob& P) {
    mob C;
    C.m00 = {a.x*P.m00.x - a.y*P.m00.y - P.m10.x, a.x*P.m00.y + a.y*P.m00.x - P.m10.y};
    C.m01 = {a.x*P.m01.x - a.y*P.m01.y - P.m11.x, a.x*P.m01.y + a.y*P.m01.x - P.m11.y};
    C.m10 = P.m00; C.m11 = P.m01;
    return C;
}
__device__ __forceinline__ void mstore(float* s, const mob& A) {
    s[0]=A.m00.x; s[1]=A.m00.y; s[2]=A.m01.x; s[3]=A.m01.y;
    s[4]=A.m10.x; s[5]=A.m10.y; s[6]=A.m11.x; s[7]=A.m11.y;
}
__device__ __forceinline__ mob mload(const float* s) {
    mob A;
    A.m00 = {s[0], s[1]}; A.m01 = {s[2], s[3]};
    A.m10 = {s[4], s[5]}; A.m11 = {s[6], s[7]};
    return A;
}

// ================= PREP: fused {x->bf16 cvt | routing | w1^T cvt | w2^T cvt} =================
#define NB_CVT   ((TOK*DD)/8/256)           // 1536
#define NB_ROUTE (TOK/4)                    // 1024
#define NB_T1    ((FF/32)*(DD/32)*EE)       // 18432  (w1: R=DD rows, C=FF cols)
#define NB_T2    ((DD/32)*(FF/32)*EE)       // 18432  (w2: R=FF, C=DD)

__device__ __forceinline__ void cvt_body(const float* __restrict__ src, ushort* __restrict__ dst, int i) {
    const float4* s = ((const float4*)src) + (size_t)i * 2;
    float4 a = s[0], b = s[1];
    uint4 o;
    o.x = pk2(a.x, a.y); o.y = pk2(a.z, a.w);
    o.z = pk2(b.x, b.y); o.w = pk2(b.z, b.w);
    *(((uint4*)dst) + i) = o;
}

__device__ __forceinline__ void tcvt_body(const float* __restrict__ src, ushort* __restrict__ dst,
                                          int R, int C, int bx, int by, int bz,
                                          float (*t)[33]) {
    size_t eoff = (size_t)bz * R * C;
    const float* s = src + eoff;
    ushort* d = dst + eoff;
    int c0 = bx * 32, r0 = by * 32;
    int tid = threadIdx.x;
    int tr = tid >> 3, tc = (tid & 7) * 4;
    float4 vsrc = *(const float4*)(s + (size_t)(r0 + tr) * C + c0 + tc);
    t[tr][tc] = vsrc.x; t[tr][tc+1] = vsrc.y; t[tr][tc+2] = vsrc.z; t[tr][tc+3] = vsrc.w;
    __syncthreads();
    ushort4 o;
    o.x = f2b(t[tc  ][tr]);
    o.y = f2b(t[tc+1][tr]);
    o.z = f2b(t[tc+2][tr]);
    o.w = f2b(t[tc+3][tr]);
    *(ushort4*)(d + (size_t)(c0 + tr) * R + r0 + tc) = o;
}

__device__ __forceinline__ void routing_body(
    const float* __restrict__ x, const float* __restrict__ v_w, const float* __restrict__ v_b,
    const float* __restrict__ gate_w, const float* __restrict__ gate_b,
    float* __restrict__ v_out, int* __restrict__ tok_e, float* __restrict__ tok_w, int blk)
{
    int wave = threadIdx.x >> 6, lane = threadIdx.x & 63;
    int t = blk * 4 + wave;
    const float* xr = x + (size_t)t * DD;
    float av = 0.f;
    float ag[8] = {0.f, 0.f, 0.f, 0.f, 0.f, 0.f, 0.f, 0.f};
    #pragma unroll
    for (int i = 0; i < 12; i++) {
        int d = lane + 64 * i;
        float xv = xr[d];
        av += xv * v_w[d];
        const float4* g = (const float4*)(gate_w + d * 8);
        float4 g0 = g[0], g1 = g[1];
        ag[0] += xv * g0.x; ag[1] += xv * g0.y; ag[2] += xv * g0.z; ag[3] += xv * g0.w;
        ag[4] += xv * g1.x; ag[5] += xv * g1.y; ag[6] += xv * g1.z; ag[7] += xv * g1.w;
    }
    #pragma unroll
    for (int off = 32; off >= 1; off >>= 1) {
        av += __shfl_xor(av, off);
        #pragma unroll
        for (int e = 0; e < 8; e++) ag[e] += __shfl_xor(ag[e], off);
    }
    if (lane == 0) {
        float vv = av + v_b[0];
        vv = fminf(fmaxf(vv, -3.f), 3.f);
        v_out[t] = vv;
        float lg[8];
        #pragma unroll
        for (int e = 0; e < 8; e++) lg[e] = ag[e] + gate_b[e];
        int e0 = 0;
        #pragma unroll
        for (int e = 1; e < 8; e++) if (lg[e] > lg[e0]) e0 = e;
        int e1 = -1;
        #pragma unroll
        for (int e = 0; e < 8; e++) if (e != e0 && (e1 < 0 || lg[e] > lg[e1])) e1 = e;
        float w0 = 1.f / (1.f + __expf(lg[e1] - lg[e0]));
        tok_e[2*t] = e0; tok_e[2*t+1] = e1;
        tok_w[2*t] = w0; tok_w[2*t+1] = 1.f - w0;
    }
}

__global__ __launch_bounds__(256) void prep_kernel(
    const float* __restrict__ x, ushort* __restrict__ x_bf,
    const float* __restrict__ v_w, const float* __restrict__ v_b,
    const float* __restrict__ gate_w, const float* __restrict__ gate_b,
    float* __restrict__ v_out, int* __restrict__ tok_e, float* __restrict__ tok_w,
    const float* __restrict__ w1, ushort* __restrict__ w1t,
    const float* __restrict__ w2, ushort* __restrict__ w2t)
{
    __shared__ float t[32][33];
    int id = blockIdx.x;
    if (id < NB_CVT) {
        cvt_body(x, x_bf, id * 256 + threadIdx.x);
        return;
    }
    id -= NB_CVT;
    if (id < NB_ROUTE) {
        routing_body(x, v_w, v_b, gate_w, gate_b, v_out, tok_e, tok_w, id);
        return;
    }
    id -= NB_ROUTE;
    if (id < NB_T1) {
        int bx = id % (FF/32); int by = (id / (FF/32)) % (DD/32); int bz = id / ((FF/32)*(DD/32));
        tcvt_body(w1, w1t, DD, FF, bx, by, bz, t);
        return;
    }
    id -= NB_T1;
    {
        int bx = id % (DD/32); int by = (id / (DD/32)) % (FF/32); int bz = id / ((DD/32)*(FF/32));
        tcvt_body(w2, w2t, FF, DD, bx, by, bz, t);
    }
}

// ============ SETUP+BK: block 0 = scatter setup (1024 thr), blocks 1..2 = BK scan ============
__device__ void setup_body(
    const int* __restrict__ tok_e, const float* __restrict__ tok_w,
    int* __restrict__ ctrl, int* __restrict__ row_token, float* __restrict__ row_w,
    int* __restrict__ slot)
{
    __shared__ int cnt[8], base[8], cursor[8];
    int tid = threadIdx.x;
    int lane = tid & 63;
    if (tid < 8) { cnt[tid] = 0; cursor[tid] = 0; }
    __syncthreads();

    int mye[8];
    #pragma unroll
    for (int it = 0; it < 8; it++) {
        int idx = it * 1024 + tid;
        int e = tok_e[idx];
        mye[it] = e;
        #pragma unroll
        for (int ex = 0; ex < 8; ex++) {
            unsigned long long m = __ballot(e == ex);
            if (e == ex && lane == (__ffsll((long long)m) - 1))
                atomicAdd(&cnt[ex], (int)__popcll(m));
        }
    }
    __syncthreads();
    if (tid == 0) {
        int b = 0;
        int* te = ctrl + 24;
        for (int i = 0; i < TILES; i++) te[i] = -1;
        #pragma unroll
        for (int e = 0; e < EE; e++) {
            base[e] = b;
            ctrl[16 + e] = b;
            int tiles = (cnt[e] + 127) >> 7;
            int t0 = b >> 7;
            for (int i = 0; i < tiles; i++) te[t0 + i] = e;
            b += tiles << 7;
        }
    }
    for (int p = tid; p < ROWS_CAP; p += 1024) row_token[p] = -1;
    __syncthreads();

    #pragma unroll
    for (int it = 0; it < 8; it++) {
        int idx = it * 1024 + tid;
        int e = mye[it];
        unsigned long long lt = (1ull << lane) - 1ull;
        int p = 0;
        #pragma unroll
        for (int ex = 0; ex < 8; ex++) {
            unsigned long long m = __ballot(e == ex);
            if (e == ex) {
                int leader = __ffsll((long long)m) - 1;
                int pos = (int)__popcll(m & lt);
                int bp = 0;
                if (lane == leader) bp = atomicAdd(&cursor[ex], (int)__popcll(m));
                bp = __shfl(bp, leader);
                p = base[ex] + bp + pos;
            }
        }
        row_token[p] = idx >> 1;
        row_w[p] = tok_w[idx];
        slot[idx] = p;
    }
}

// BK scan body for one batch row inside a 1024-thread block (threads >=256 barrier-only).
__device__ void bk_body(int b, const float* __restrict__ v, float* __restrict__ feats) {
    int t = threadIdx.x;
    bool act = t < 256;
    __shared__ float sm[256][8];
    const mob I = {{1.f,0.f},{0.f,0.f},{0.f,0.f},{1.f,0.f}};
    cplx a[8];
    const float* vb = v + (size_t)b * NN;
    if (act) {
        #pragma unroll
        for (int j = 0; j < 8; j++) { a[j].x = -2.f + vb[t*8 + j]; a[j].y = -1.f; }
    }

    mob cur = I;
    if (act) {
        #pragma unroll
        for (int j = 0; j < 8; j++) cur = mstep(a[j], cur);
        mnorm(cur);
        mstore(sm[t], cur);
    }
    for (int s = 1; s < 256; s <<= 1) {
        __syncthreads();
        mob prev; bool has = act && (t >= s);
        if (has) prev = mload(sm[t - s]);
        __syncthreads();
        if (has) { cur = mmul(cur, prev); mnorm(cur); mstore(sm[t], cur); }
    }
    __syncthreads();
    cplx dreg[8];
    if (act) {
        mob P = (t > 0) ? mload(sm[t - 1]) : I;
        #pragma unroll
        for (int j = 0; j < 8; j++) {
            P = mstep(a[j], P); mnorm(P);
            dreg[j] = cdivc(P.m00, P.m10);
        }
    }
    __syncthreads();

    cur = I;
    if (act) {
        #pragma unroll
        for (int j = 7; j >= 0; j--) cur = mstep(a[j], cur);
        mnorm(cur);
        mstore(sm[t], cur);
    }
    for (int s = 1; s < 256; s <<= 1) {
        __syncthreads();
        mob nxt; bool has = act && (t + s < 256);
        if (has) nxt = mload(sm[t + s]);
        __syncthreads();
        if (has) { cur = mmul(cur, nxt); mnorm(cur); mstore(sm[t], cur); }
    }
    __syncthreads();
    if (act) {
        mob P = (t < 255) ? mload(sm[t + 1]) : I;
        #pragma unroll
        for (int j = 7; j >= 0; j--) {
            P = mstep(a[j], P); mnorm(P);
            cplx e = cdivc(P.m00, P.m10);
            cplx den = {dreg[j].x + e.x - a[j].x, dreg[j].y + e.y - a[j].y};
            cplx one = {1.f, 0.f};
            cplx G = cdivc(one, den);
            int i = b * NN + t*8 + j;
            feats[2*i]   = G.x;
            feats[2*i+1] = G.y;
        }
    }
}

__global__ __launch_bounds__(1024) void setup_bk_kernel(
    const int* __restrict__ tok_e, const float* __restrict__ tok_w,
    int* __restrict__ ctrl, int* __restrict__ row_token, float* __restrict__ row_w,
    int* __restrict__ slot, const float* __restrict__ v, float* __restrict__ feats)
{
    if (blockIdx.x == 0) setup_body(tok_e, tok_w, ctrl, row_token, row_w, slot);
    else                 bk_body(blockIdx.x - 1, v, feats);
}

// ===== GEMM K-loop: BK=64, 2-deep pipeline, counted vmcnt, raw barriers =====
// LDS buffer: [128][64] ushorts (128B rows). Swizzle: the 16B k-quad at
// (row r, logical quad qq) is stored at physical quad qq^(r&7). Stage side:
// gload_lds writes linearly (lane -> row lane>>3, slot lane&7), so the GLOBAL
// source k-offset is pre-swizzled: kq = ((lane&7)^((lane>>3)&7))*8. Read side
// applies the same XOR: qx = (qq^(lm&7))*16B. A 16-lane b128 read group (rows
// r..r+15, fixed qq) then covers all 8 quad slots twice -> 2-way (free).
//
// Per K64 step (8 gloads/wave/group, BK=64 -> 32 MFMA per 2 barriers):
//   prologue: stage g0->slot0, g1->slot1 (16 loads in flight)
//   iter ks:  vmcnt(8) [group ks arrived; vmcnt(0) last iter]; s_barrier
//             ds_read sub0 (8xb128); MFMA sub0 (16)  [overlaps sub1 reads]
//             ds_read sub1 (8xb128); lgkmcnt(0); sched_barrier; s_barrier
//             stage group ks+2 -> this slot (stays in flight across barriers)
//             MFMA sub1 (16)
#define STAGE64(AW, BW, k0) do { \
        _Pragma("unroll") \
        for (int g = 0; g < 4; g++) { \
            gload16(ag[g] + (k0), (AW) + g*8*64); \
            gload16(bg[g] + (k0), (BW) + g*8*64); \
        } } while (0)

#define LOADFR64(APTR, BPTR, QX) do { \
        _Pragma("unroll") \
        for (int i = 0; i < 4; i++) \
            afr[i] = *(const bf16x8*)(const void*)((APTR) + (wm + i*16 + lm) * 64 + (QX)); \
        _Pragma("unroll") \
        for (int j = 0; j < 4; j++) \
            bfr[j] = *(const bf16x8*)(const void*)((BPTR) + (wn + j*16 + lm) * 64 + (QX)); \
    } while (0)

#define MFMAS() do { \
        _Pragma("unroll") \
        for (int i = 0; i < 4; i++) \
            _Pragma("unroll") \
            for (int j = 0; j < 4; j++) \
                acc[i][j] = __builtin_amdgcn_mfma_f32_16x16x32_bf16(afr[i], bfr[j], acc[i][j], 0, 0, 0); \
    } while (0)

#define PIPE64(NK) do { \
    STAGE64(AsW0, BsW0, 0); \
    STAGE64(AsW1, BsW1, 64); \
    for (int ks = 0; ks < (NK); ks++) { \
        int cur = ks & 1; \
        const ushort* Ab = cur ? As[1] : As[0]; \
        const ushort* Bb = cur ? Bs[1] : Bs[0]; \
        ushort* AsN = cur ? AsW1 : AsW0; \
        ushort* BsN = cur ? BsW1 : BsW0; \
        if (ks < (NK) - 1) { asm volatile("s_waitcnt vmcnt(8)" ::: "memory"); } \
        else               { asm volatile("s_waitcnt vmcnt(0)" ::: "memory"); } \
        __builtin_amdgcn_s_barrier(); \
        { \
            bf16x8 afr[4], bfr[4]; \
            LOADFR64(Ab, Bb, qx0); \
            __builtin_amdgcn_s_setprio(1); \
            MFMAS(); \
            __builtin_amdgcn_s_setprio(0); \
        } \
        { \
            bf16x8 afr[4], bfr[4]; \
            LOADFR64(Ab, Bb, qx0 ^ 32); \
            asm volatile("s_waitcnt lgkmcnt(0)" ::: "memory"); \
            __builtin_amdgcn_sched_barrier(0); \
            __builtin_amdgcn_s_barrier(); \
            if (ks + 2 < (NK)) STAGE64(AsN, BsN, ks*64 + 128); \
            __builtin_amdgcn_s_setprio(1); \
            MFMAS(); \
            __builtin_amdgcn_s_setprio(0); \
        } \
    } } while (0)

// ---------- K5: GEMM1  H = gelu(Xg @ w1t[e]^T + b1[e]) ----------
// grid = (FF/128, TILES): f-block fast dim -> same-(e,f) weight panels land on
// the same XCD L2 (delta 24 % 8 == 0). FETCH 62MB confirmed round 2/4.
__global__ __launch_bounds__(256) void gemm1_kernel(
    const ushort* __restrict__ x_bf, const ushort* __restrict__ w1t, const float* __restrict__ b1,
    const int* __restrict__ ctrl, const int* __restrict__ row_token, ushort* __restrict__ H)
{
    int tile = blockIdx.y;
    int e = ctrl[24 + tile];
    if (e < 0) return;
    int p0 = tile * 128;
    int f0 = blockIdx.x * 128;

    __shared__ ushort As[2][128 * 64];
    __shared__ ushort Bs[2][128 * 64];
    __shared__ int toks[128];

    int tid = threadIdx.x;
    if (tid < 128) { int tk = row_token[p0 + tid]; toks[tid] = tk < 0 ? 0 : tk; }
    __syncthreads();

    int wave = tid >> 6, lane = tid & 63;
    int srow = lane >> 3;                                   // row within 8-row gload group
    int kq = (((lane & 7) ^ (srow & 7))) * 8;               // swizzled global k-quad (ushorts)
    const ushort* ag[4];
    #pragma unroll
    for (int g = 0; g < 4; g++) {
        int tk = toks[wave*32 + g*8 + srow];
        ag[g] = x_bf + (size_t)tk * DD + kq;
    }
    const ushort* w1e = w1t + (size_t)e * (FF * DD);        // [f][d] row stride DD
    const ushort* bg[4];
    #pragma unroll
    for (int g = 0; g < 4; g++)
        bg[g] = w1e + (size_t)(f0 + wave*32 + g*8 + srow) * DD + kq;
    ushort* AsW0 = &As[0][wave * 32 * 64];
    ushort* BsW0 = &Bs[0][wave * 32 * 64];
    ushort* AsW1 = &As[1][wave * 32 * 64];
    ushort* BsW1 = &Bs[1][wave * 32 * 64];

    floatx4 zero4 = {0.f, 0.f, 0.f, 0.f};
    floatx4 acc[4][4];
    #pragma unroll
    for (int i = 0; i < 4; i++)
        #pragma unroll
        for (int j = 0; j < 4; j++) acc[i][j] = zero4;

    int wm = (wave & 1) * 64, wn = (wave >> 1) * 64;
    int lm = lane & 15, q = lane >> 4;
    int qx0 = (q ^ (lm & 7)) * 8;                           // swizzled ds_read quad, sub0

    PIPE64(DD/64);

    #pragma unroll
    for (int i = 0; i < 4; i++) {
        #pragma unroll
        for (int j = 0; j < 4; j++) {
            int n = wn + j*16 + lm;
            float bias = b1[e * FF + f0 + n];
            #pragma unroll
            for (int r = 0; r < 4; r++) {
                int m = wm + i*16 + q*4 + r;
                float hv = gelu_f(acc[i][j][r] + bias);
                H[(size_t)(p0 + m) * FF + f0 + n] = f2b(hv);
            }
        }
    }
}

// ---------- K6: GEMM2  Y = row_w * (H @ w2t[e]^T + b2[e]) ----------
// grid (TILES, DD/128): same tile across d-blocks is 72 apart (72%8==0 -> same
// XCD), so the H-tile is L2-reused across all 6 d-blocks.
__global__ __launch_bounds__(256) void gemm2_kernel(
    const ushort* __restrict__ H, const ushort* __restrict__ w2t, const float* __restrict__ b2,
    const int* __restrict__ ctrl, const float* __restrict__ row_w, float* __restrict__ Y)
{
    int tile = blockIdx.x;
    int e = ctrl[24 + tile];
    if (e < 0) return;
    int p0 = tile * 128;
    int d0 = blockIdx.y * 128;

    __shared__ ushort As[2][128 * 64];
    __shared__ ushort Bs[2][128 * 64];

    int tid = threadIdx.x;
    int wave = tid >> 6, lane = tid & 63;
    int srow = lane >> 3;
    int kq = (((lane & 7) ^ (srow & 7))) * 8;
    const ushort* ag[4];
    #pragma unroll
    for (int g = 0; g < 4; g++)
        ag[g] = H + (size_t)(p0 + wave*32 + g*8 + srow) * FF + kq;
    const ushort* w2e = w2t + (size_t)e * (DD * FF);       // [d][f] row stride FF
    const ushort* bg[4];
    #pragma unroll
    for (int g = 0; g < 4; g++)
        bg[g] = w2e + (size_t)(d0 + wave*32 + g*8 + srow) * FF + kq;
    ushort* AsW0 = &As[0][wave * 32 * 64];
    ushort* BsW0 = &Bs[0][wave * 32 * 64];
    ushort* AsW1 = &As[1][wave * 32 * 64];
    ushort* BsW1 = &Bs[1][wave * 32 * 64];

    floatx4 zero4 = {0.f, 0.f, 0.f, 0.f};
    floatx4 acc[4][4];
    #pragma unroll
    for (int i = 0; i < 4; i++)
        #pragma unroll
        for (int j = 0; j < 4; j++) acc[i][j] = zero4;

    int wm = (wave & 1) * 64, wn = (wave >> 1) * 64;
    int lm = lane & 15, q = lane >> 4;
    int qx0 = (q ^ (lm & 7)) * 8;

    PIPE64(FF/64);

    #pragma unroll
    for (int i = 0; i < 4; i++) {
        #pragma unroll
        for (int j = 0; j < 4; j++) {
            int n = wn + j*16 + lm;
            float bias = b2[e * DD + d0 + n];
            #pragma unroll
            for (int r = 0; r < 4; r++) {
                int m = wm + i*16 + q*4 + r;
                float wgt = row_w[p0 + m];
                Y[(size_t)(p0 + m) * DD + d0 + n] = wgt * (acc[i][j][r] + bias);
            }
        }
    }
}

// ---------- K7: final combine (fp32 out) ----------
__global__ __launch_bounds__(256) void final_kernel(
    const float* __restrict__ Y, const int* __restrict__ slot, const float* __restrict__ feats,
    const float* __restrict__ out_w, const float* __restrict__ out_b,
    const float* __restrict__ bk_scale, float* __restrict__ out)
{
    int idx = blockIdx.x * 256 + threadIdx.x;
    int base = idx * 4;
    int t = base / DD;
    int d = base - t * DD;
    int p0 = slot[2*t], p1 = slot[2*t + 1];
    const float4 ya = *(const float4*)(Y + (size_t)p0 * DD + d);
    const float4 yb = *(const float4*)(Y + (size_t)p1 * DD + d);
    float f0 = feats[2*t], f1 = feats[2*t + 1];
    f0 = fminf(fmaxf(f0, -10.f), 10.f);
    f1 = fminf(fmaxf(f1, -10.f), 10.f);
    float ff[4] = {ya.x + yb.x, ya.y + yb.y, ya.z + yb.z, ya.w + yb.w};
    float4 o;
    float* op = (float*)&o;
    #pragma unroll
    for (int u = 0; u < 4; u++) {
        float spec = f0 * out_w[d + u] + f1 * out_w[DD + d + u] + out_b[d + u];
        op[u] = ff[u] + bk_scale[d + u] * spec;
    }
    *(float4*)(out + base) = o;
}

extern "C" void kernel_launch(void* const* d_in, const int* in_sizes, int n_in,
                              void* d_out, int out_size, void* d_ws, size_t ws_size,
                              hipStream_t stream)
{
    const float* x      = (const float*)d_in[0];
    const float* v_w    = (const float*)d_in[1];
    const float* v_b    = (const float*)d_in[2];
    const float* gate_w = (const float*)d_in[3];
    const float* gate_b = (const float*)d_in[4];
    const float* w1     = (const float*)d_in[5];
    const float* b1     = (const float*)d_in[6];
    const float* w2     = (const float*)d_in[7];
    const float* b2     = (const float*)d_in[8];
    const float* out_w  = (const float*)d_in[9];
    const float* out_b  = (const float*)d_in[10];
    const float* bk_s   = (const float*)d_in[11];

    char* ws = (char*)d_ws;
    int*    ctrl    = (int*)(ws + OFF_CTRL);
    float*  v       = (float*)(ws + OFF_V);
    int*    tok_e   = (int*)(ws + OFF_TOKE);
    float*  tok_w   = (float*)(ws + OFF_TOKW);
    int*    row_tok = (int*)(ws + OFF_ROWTOK);
    float*  row_w   = (float*)(ws + OFF_ROWW);
    int*    slot    = (int*)(ws + OFF_SLOT);
    float*  feats   = (float*)(ws + OFF_FEATS);
    ushort* w2t     = (ushort*)(ws + OFF_W2T);
    ushort* x_bf    = (ushort*)(ws + OFF_XBF);
    ushort* w1t     = (ushort*)(ws + OFF_W1T);
    ushort* H       = (ushort*)(ws + OFF_H);
    float*  Y       = (float*)(ws + OFF_Y);
    float*  out     = (float*)d_out;

    prep_kernel<<<NB_CVT + NB_ROUTE + NB_T1 + NB_T2, 256, 0, stream>>>(
        x, x_bf, v_w, v_b, gate_w, gate_b, v, tok_e, tok_w, w1, w1t, w2, w2t);
    setup_bk_kernel<<<1 + BB, 1024, 0, stream>>>(tok_e, tok_w, ctrl, row_tok, row_w, slot, v, feats);
    gemm1_kernel<<<dim3(FF / 128, TILES), 256, 0, stream>>>(x_bf, w1t, b1, ctrl, row_tok, H);
    gemm2_kernel<<<dim3(TILES, DD / 128), 256, 0, stream>>>(H, w2t, b2, ctrl, row_w, Y);
    final_kernel<<<(TOK * DD) / 1024, 256, 0, stream>>>(Y, slot, feats, out_w, out_b, bk_s, out);
}

// Round 6
// 209.107 us; speedup vs baseline: 1.2479x; 1.0038x over previous
//
#include <hip/hip_runtime.h>
#include <hip/hip_bf16.h>

#define BB 2
#define NN 2048
#define DD 768
#define EE 8
#define FF 3072
#define TOK (BB*NN)       // 4096
#define ROWS_CAP 9216     // 8192 slots + 8*128 alignment pad
#define TILES 72          // ROWS_CAP / 128

typedef __attribute__((ext_vector_type(8))) __bf16 bf16x8;
typedef __attribute__((ext_vector_type(4))) float floatx4;

// ---------- ws layout (bytes) ----------
#define OFF_CTRL    0ull                    // int[96]: base@16, tile_expert@24
#define OFF_V       1024ull                 // float[4096]
#define OFF_TOKE    17408ull                // int[8192]
#define OFF_TOKW    50176ull                // float[8192]
#define OFF_ROWTOK  82944ull                // int[9216]
#define OFF_ROWW    119808ull               // float[9216]
#define OFF_SLOT    156672ull               // int[8192]
#define OFF_FEATS   189440ull               // float[8192]
// big buffers
#define OFF_W2T     222208ull               // ushort[8*768*3072] = 37,748,736 B   (w2^T: [e][d][f])
#define OFF_XBF     37970944ull             // ushort[4096*768]   = 6,291,456 B
#define OFF_W1T     44262400ull             // ushort[8*3072*768] = 37,748,736 B   (w1^T: [e][f][d])
#define OFF_H       82011136ull             // ushort[9216*3072]  = 56,623,104 B -> end 138,634,240
#define OFF_Y       OFF_XBF                 // float[9216*768] = 28,311,552 B, aliases dead XBF+W1T

__device__ __forceinline__ ushort f2b(float f) {
    union { float f; unsigned int i; } v; v.f = f;
    unsigned int u = v.i;
    unsigned int r = (u + 0x7FFFu + ((u >> 16) & 1u)) >> 16;
    return (ushort)r;
}
__device__ __forceinline__ unsigned int pk2(float lo, float hi) {
    union { float f; unsigned int u; } a, b;
    a.f = lo; b.f = hi;
    unsigned int ra = ((a.u + 0x7FFFu + ((a.u >> 16) & 1u)) >> 16) & 0xFFFFu;
    unsigned int rb = (b.u + 0x7FFFu + ((b.u >> 16) & 1u)) & 0xFFFF0000u;
    return ra | rb;
}
__device__ __forceinline__ float gelu_f(float x) {
    float z = 0.7978845608028654f * x * (1.f + 0.044715f * x * x);
    z = fminf(fmaxf(z, -12.f), 12.f);
    float e = __expf(2.f * z);
    return 0.5f * x * (1.f + (e - 1.f) / (e + 1.f));
}
// async global(16B/lane) -> LDS (wave-uniform base + lane*16)
__device__ __forceinline__ void gload16(const ushort* g, ushort* l) {
    __builtin_amdgcn_global_load_lds((const __attribute__((address_space(1))) void*)g,
                                     (__attribute__((address_space(3))) void*)l,
                                     16, 0, 0);
}

// ---------- complex / Mobius helpers ----------
struct cplx { float x, y; };
__device__ __forceinline__ cplx cmulc(cplx a, cplx b) { return {a.x*b.x - a.y*b.y, a.x*b.y + a.y*b.x}; }
__device__ __forceinline__ cplx caddc(cplx a, cplx b) { return {a.x + b.x, a.y + b.y}; }
__device__ __forceinline__ cplx cdivc(cplx a, cplx b) {
    float s = 1.f / (b.x*b.x + b.y*b.y);
    return {(a.x*b.x + a.y*b.y)*s, (a.y*b.x - a.x*b.y)*s};
}
struct mob { cplx m00, m01, m10, m11; };
__device__ __forceinline__ mob mmul(const mob& A, const mob& B) {
    mob C;
    C.m00 = caddc(cmulc(A.m00, B.m00), cmulc(A.m01, B.m10));
    C.m01 = caddc(cmulc(A.m00, B.m01), cmulc(A.m01, B.m11));
    C.m10 = caddc(cmulc(A.m10, B.m00), cmulc(A.m11, B.m10));
    C.m11 = caddc(cmulc(A.m10, B.m01), cmulc(A.m11, B.m11));
    return C;
}
__device__ __forceinline__ void mnorm(mob& A) {
    float s = fabsf(A.m00.x);
    s = fmaxf(s, fabsf(A.m00.y)); s = fmaxf(s, fabsf(A.m01.x)); s = fmaxf(s, fabsf(A.m01.y));
    s = fmaxf(s, fabsf(A.m10.x)); s = fmaxf(s, fabsf(A.m10.y)); s = fmaxf(s, fabsf(A.m11.x));
    s = fmaxf(s, fabsf(A.m11.y));
    float r = 1.f / fmaxf(s, 1e-30f);
    A.m00.x *= r; A.m00.y *= r; A.m01.x *= r; A.m01.y *= r;
    A.m10.x *= r; A.m10.y *= r; A.m11.x *= r; A.m11.y *= r;
}
__device__ __forceinline__ mob mstep(cplx a, const mob& P) {
    mob C;
    C.m00 = {a.x*P.m00.x - a.y*P.m00.y - P.m10.x, a.x*P.m00.y + a.y*P.m00.x - P.m10.y};
    C.m01 = {a.x*P.m01.x - a.y*P.m01.y - P.m11.x, a.x*P.m01.y + a.y*P.m01.x - P.m11.y};
    C.m10 = P.m00; C.m11 = P.m01;
    return C;
}
__device__ __forceinline__ void mstore(float* s, const mob& A) {
    s[0]=A.m00.x; s[1]=A.m00.y; s[2]=A.m01.x; s[3]=A.m01.y;
    s[4]=A.m10.x; s[5]=A.m10.y; s[6]=A.m11.x; s[7]=A.m11.y;
}
__device__ __forceinline__ mob mload(const float* s) {
    mob A;
    A.m00 = {s[0], s[1]}; A.m01 = {s[2], s[3]};
    A.m10 = {s[4], s[5]}; A.m11 = {s[6], s[7]};
    return A;
}

// ================= PREP: fused {x->bf16 cvt | routing | w1^T cvt | w2^T cvt} =================
// tcvt4: 32x128 strip per block, 4 float4 loads in flight per thread (4x MLP vs
// the 1-load round-5 version that sat at 3.1 TB/s, latency-bound). 4x fewer blocks.
#define NB_CVT   ((TOK*DD)/8/256)           // 1536
#define NB_ROUTE (TOK/4)                    // 1024
#define NB_T1    ((FF/128)*(DD/32)*EE)      // 4608  (w1: R=DD rows, C=FF cols)
#define NB_T2    ((DD/128)*(FF/32)*EE)      // 4608  (w2: R=FF, C=DD)

__device__ __forceinline__ void cvt_body(const float* __restrict__ src, ushort* __restrict__ dst, int i) {
    const float4* s = ((const float4*)src) + (size_t)i * 2;
    float4 a = s[0], b = s[1];
    uint4 o;
    o.x = pk2(a.x, a.y); o.y = pk2(a.z, a.w);
    o.z = pk2(b.x, b.y); o.w = pk2(b.z, b.w);
    *(((uint4*)dst) + i) = o;
}

__device__ __forceinline__ void tcvt4_body(const float* __restrict__ src, ushort* __restrict__ dst,
                                           int R, int C, int bx, int by, int bz,
                                           float (*t)[33]) {
    size_t eoff = (size_t)bz * R * C;
    const float* s = src + eoff;
    ushort* d = dst + eoff;
    int c0 = bx * 128, r0 = by * 32;
    int tid = threadIdx.x;
    int tr = tid >> 3, tc = (tid & 7) * 4;
    // all 4 loads issued before any LDS phase -> 4 in flight
    float4 v[4];
    const float* srow = s + (size_t)(r0 + tr) * C + c0 + tc;
    #pragma unroll
    for (int k = 0; k < 4; k++) v[k] = *(const float4*)(srow + k * 32);
    #pragma unroll
    for (int k = 0; k < 4; k++) {
        __syncthreads();   // WAR vs previous sub-tile's reads
        t[tr][tc] = v[k].x; t[tr][tc+1] = v[k].y; t[tr][tc+2] = v[k].z; t[tr][tc+3] = v[k].w;
        __syncthreads();
        ushort4 o;
        o.x = f2b(t[tc  ][tr]);
        o.y = f2b(t[tc+1][tr]);
        o.z = f2b(t[tc+2][tr]);
        o.w = f2b(t[tc+3][tr]);
        *(ushort4*)(d + (size_t)(c0 + k*32 + tr) * R + r0 + tc) = o;
    }
}

__device__ __forceinline__ void routing_body(
    const float* __restrict__ x, const float* __restrict__ v_w, const float* __restrict__ v_b,
    const float* __restrict__ gate_w, const float* __restrict__ gate_b,
    float* __restrict__ v_out, int* __restrict__ tok_e, float* __restrict__ tok_w, int blk)
{
    int wave = threadIdx.x >> 6, lane = threadIdx.x & 63;
    int t = blk * 4 + wave;
    const float* xr = x + (size_t)t * DD;
    float av = 0.f;
    float ag[8] = {0.f, 0.f, 0.f, 0.f, 0.f, 0.f, 0.f, 0.f};
    #pragma unroll
    for (int i = 0; i < 12; i++) {
        int d = lane + 64 * i;
        float xv = xr[d];
        av += xv * v_w[d];
        const float4* g = (const float4*)(gate_w + d * 8);
        float4 g0 = g[0], g1 = g[1];
        ag[0] += xv * g0.x; ag[1] += xv * g0.y; ag[2] += xv * g0.z; ag[3] += xv * g0.w;
        ag[4] += xv * g1.x; ag[5] += xv * g1.y; ag[6] += xv * g1.z; ag[7] += xv * g1.w;
    }
    #pragma unroll
    for (int off = 32; off >= 1; off >>= 1) {
        av += __shfl_xor(av, off);
        #pragma unroll
        for (int e = 0; e < 8; e++) ag[e] += __shfl_xor(ag[e], off);
    }
    if (lane == 0) {
        float vv = av + v_b[0];
        vv = fminf(fmaxf(vv, -3.f), 3.f);
        v_out[t] = vv;
        float lg[8];
        #pragma unroll
        for (int e = 0; e < 8; e++) lg[e] = ag[e] + gate_b[e];
        int e0 = 0;
        #pragma unroll
        for (int e = 1; e < 8; e++) if (lg[e] > lg[e0]) e0 = e;
        int e1 = -1;
        #pragma unroll
        for (int e = 0; e < 8; e++) if (e != e0 && (e1 < 0 || lg[e] > lg[e1])) e1 = e;
        float w0 = 1.f / (1.f + __expf(lg[e1] - lg[e0]));
        tok_e[2*t] = e0; tok_e[2*t+1] = e1;
        tok_w[2*t] = w0; tok_w[2*t+1] = 1.f - w0;
    }
}

__global__ __launch_bounds__(256) void prep_kernel(
    const float* __restrict__ x, ushort* __restrict__ x_bf,
    const float* __restrict__ v_w, const float* __restrict__ v_b,
    const float* __restrict__ gate_w, const float* __restrict__ gate_b,
    float* __restrict__ v_out, int* __restrict__ tok_e, float* __restrict__ tok_w,
    const float* __restrict__ w1, ushort* __restrict__ w1t,
    const float* __restrict__ w2, ushort* __restrict__ w2t)
{
    __shared__ float t[32][33];
    int id = blockIdx.x;
    if (id < NB_CVT) {
        cvt_body(x, x_bf, id * 256 + threadIdx.x);
        return;
    }
    id -= NB_CVT;
    if (id < NB_ROUTE) {
        routing_body(x, v_w, v_b, gate_w, gate_b, v_out, tok_e, tok_w, id);
        return;
    }
    id -= NB_ROUTE;
    if (id < NB_T1) {
        int bx = id % (FF/128); int by = (id / (FF/128)) % (DD/32); int bz = id / ((FF/128)*(DD/32));
        tcvt4_body(w1, w1t, DD, FF, bx, by, bz, t);
        return;
    }
    id -= NB_T1;
    {
        int bx = id % (DD/128); int by = (id / (DD/128)) % (FF/32); int bz = id / ((DD/128)*(FF/32));
        tcvt4_body(w2, w2t, FF, DD, bx, by, bz, t);
    }
}

// ============ SETUP+BK: block 0 = scatter setup (1024 thr), blocks 1..2 = BK scan ============
__device__ void setup_body(
    const int* __restrict__ tok_e, const float* __restrict__ tok_w,
    int* __restrict__ ctrl, int* __restrict__ row_token, float* __restrict__ row_w,
    int* __restrict__ slot)
{
    __shared__ int cnt[8], base[8], cursor[8];
    int tid = threadIdx.x;
    int lane = tid & 63;
    if (tid < 8) { cnt[tid] = 0; cursor[tid] = 0; }
    __syncthreads();

    int mye[8];
    #pragma unroll
    for (int it = 0; it < 8; it++) {
        int idx = it * 1024 + tid;
        int e = tok_e[idx];
        mye[it] = e;
        #pragma unroll
        for (int ex = 0; ex < 8; ex++) {
            unsigned long long m = __ballot(e == ex);
            if (e == ex && lane == (__ffsll((long long)m) - 1))
                atomicAdd(&cnt[ex], (int)__popcll(m));
        }
    }
    __syncthreads();
    if (tid == 0) {
        int b = 0;
        int* te = ctrl + 24;
        for (int i = 0; i < TILES; i++) te[i] = -1;
        #pragma unroll
        for (int e = 0; e < EE; e++) {
            base[e] = b;
            ctrl[16 + e] = b;
            int tiles = (cnt[e] + 127) >> 7;
            int t0 = b >> 7;
            for (int i = 0; i < tiles; i++) te[t0 + i] = e;
            b += tiles << 7;
        }
    }
    for (int p = tid; p < ROWS_CAP; p += 1024) row_token[p] = -1;
    __syncthreads();

    #pragma unroll
    for (int it = 0; it < 8; it++) {
        int idx = it * 1024 + tid;
        int e = mye[it];
        unsigned long long lt = (1ull << lane) - 1ull;
        int p = 0;
        #pragma unroll
        for (int ex = 0; ex < 8; ex++) {
            unsigned long long m = __ballot(e == ex);
            if (e == ex) {
                int leader = __ffsll((long long)m) - 1;
                int pos = (int)__popcll(m & lt);
                int bp = 0;
                if (lane == leader) bp = atomicAdd(&cursor[ex], (int)__popcll(m));
                bp = __shfl(bp, leader);
                p = base[ex] + bp + pos;
            }
        }
        row_token[p] = idx >> 1;
        row_w[p] = tok_w[idx];
        slot[idx] = p;
    }
}

// BK scan body for one batch row inside a 1024-thread block (threads >=256 barrier-only).
__device__ void bk_body(int b, const float* __restrict__ v, float* __restrict__ feats) {
    int t = threadIdx.x;
    bool act = t < 256;
    __shared__ float sm[256][8];
    const mob I = {{1.f,0.f},{0.f,0.f},{0.f,0.f},{1.f,0.f}};
    cplx a[8];
    const float* vb = v + (size_t)b * NN;
    if (act) {
        #pragma unroll
        for (int j = 0; j < 8; j++) { a[j].x = -2.f + vb[t*8 + j]; a[j].y = -1.f; }
    }

    mob cur = I;
    if (act) {
        #pragma unroll
        for (int j = 0; j < 8; j++) cur = mstep(a[j], cur);
        mnorm(cur);
        mstore(sm[t], cur);
    }
    for (int s = 1; s < 256; s <<= 1) {
        __syncthreads();
        mob prev; bool has = act && (t >= s);
        if (has) prev = mload(sm[t - s]);
        __syncthreads();
        if (has) { cur = mmul(cur, prev); mnorm(cur); mstore(sm[t], cur); }
    }
    __syncthreads();
    cplx dreg[8];
    if (act) {
        mob P = (t > 0) ? mload(sm[t - 1]) : I;
        #pragma unroll
        for (int j = 0; j < 8; j++) {
            P = mstep(a[j], P); mnorm(P);
            dreg[j] = cdivc(P.m00, P.m10);
        }
    }
    __syncthreads();

    cur = I;
    if (act) {
        #pragma unroll
        for (int j = 7; j >= 0; j--) cur = mstep(a[j], cur);
        mnorm(cur);
        mstore(sm[t], cur);
    }
    for (int s = 1; s < 256; s <<= 1) {
        __syncthreads();
        mob nxt; bool has = act && (t + s < 256);
        if (has) nxt = mload(sm[t + s]);
        __syncthreads();
        if (has) { cur = mmul(cur, nxt); mnorm(cur); mstore(sm[t], cur); }
    }
    __syncthreads();
    if (act) {
        mob P = (t < 255) ? mload(sm[t + 1]) : I;
        #pragma unroll
        for (int j = 7; j >= 0; j--) {
            P = mstep(a[j], P); mnorm(P);
            cplx e = cdivc(P.m00, P.m10);
            cplx den = {dreg[j].x + e.x - a[j].x, dreg[j].y + e.y - a[j].y};
            cplx one = {1.f, 0.f};
            cplx G = cdivc(one, den);
            int i = b * NN + t*8 + j;
            feats[2*i]   = G.x;
            feats[2*i+1] = G.y;
        }
    }
}

__global__ __launch_bounds__(1024) void setup_bk_kernel(
    const int* __restrict__ tok_e, const float* __restrict__ tok_w,
    int* __restrict__ ctrl, int* __restrict__ row_token, float* __restrict__ row_w,
    int* __restrict__ slot, const float* __restrict__ v, float* __restrict__ feats)
{
    if (blockIdx.x == 0) setup_body(tok_e, tok_w, ctrl, row_token, row_w, slot);
    else                 bk_body(blockIdx.x - 1, v, feats);
}

#define MFMAS() do { \
        _Pragma("unroll") \
        for (int i = 0; i < 4; i++) \
            _Pragma("unroll") \
            for (int j = 0; j < 4; j++) \
                acc[i][j] = __builtin_amdgcn_mfma_f32_16x16x32_bf16(afr[i], bfr[j], acc[i][j], 0, 0, 0); \
    } while (0)

// ---------- K5: GEMM1  H = gelu(Xg @ w1t[e]^T + b1[e]) ----------
// 256-row x 128-f tile, 8 waves (512 thr), BK=32, counted-vmcnt 2-deep pipeline.
// Expert regions are 128-aligned, so a 256-tile's two M-halves may belong to
// different experts: Bs holds TWO 128-row panels (half h = rows h*128..h*128+127,
// expert te[2*tile+h]). Wave w: wm=(w>>1)*64, wn=(w&1)*64; its half = w>>2, and
// it stages exactly the B rows it consumes (dest row w*32 = (w>>2)*128+(w&3)*32).
// vs round-5 128x128: A-staging bytes /2, blocks /2 (864), 16 waves/CU (2 blk).
// Swizzle identical to round 4 (0 bank conflicts verified).
__global__ __launch_bounds__(512, 4) void gemm1_kernel(
    const ushort* __restrict__ x_bf, const ushort* __restrict__ w1t, const float* __restrict__ b1,
    const int* __restrict__ ctrl, const int* __restrict__ row_token, ushort* __restrict__ H)
{
    int tile = blockIdx.y;                     // 256-row tile, 0..35
    int e0 = ctrl[24 + 2*tile];
    if (e0 < 0) return;
    int e1 = ctrl[24 + 2*tile + 1];
    if (e1 < 0) e1 = e0;                       // half1 all-pad: compute garbage, never read
    int p0 = tile * 256;
    int f0 = blockIdx.x * 128;

    __shared__ ushort As[2][256 * 32];
    __shared__ ushort Bs[2][256 * 32];         // rows 0-127: e0 panel, 128-255: e1 panel
    __shared__ int toks[256];

    int tid = threadIdx.x;
    if (tid < 256) { int tk = row_token[p0 + tid]; toks[tid] = tk < 0 ? 0 : tk; }
    __syncthreads();

    int wave = tid >> 6, lane = tid & 63;
    int rsub = lane >> 2;                                  // row within 16-row gload group
    int kq = (((lane & 3) ^ ((rsub >> 1) & 3))) * 8;       // swizzled global k-quad (ushorts)
    int tokA0 = toks[wave*32 + rsub];
    int tokA1 = toks[wave*32 + 16 + rsub];
    const ushort* aglob0 = x_bf + (size_t)tokA0 * DD + kq;
    const ushort* aglob1 = x_bf + (size_t)tokA1 * DD + kq;
    int eh = (wave >> 2) ? e1 : e0;                        // this wave's half-expert
    const ushort* w1e = w1t + (size_t)eh * (FF * DD);      // [f][d] row stride DD
    const ushort* bglob0 = w1e + (size_t)(f0 + (wave & 3)*32 + rsub) * DD + kq;
    const ushort* bglob1 = bglob0 + (size_t)16 * DD;
    ushort* AsW0 = &As[0][wave * 32 * 32];
    ushort* BsW0 = &Bs[0][wave * 32 * 32];
    ushort* AsW1 = &As[1][wave * 32 * 32];
    ushort* BsW1 = &Bs[1][wave * 32 * 32];

    floatx4 zero4 = {0.f, 0.f, 0.f, 0.f};
    floatx4 acc[4][4];
    #pragma unroll
    for (int i = 0; i < 4; i++)
        #pragma unroll
        for (int j = 0; j < 4; j++) acc[i][j] = zero4;

    int wm = (wave >> 1) * 64, wn = (wave & 1) * 64;
    int bbase = (wave >> 2) * 128;                         // B panel base row for this half
    int lm = lane & 15, q = lane >> 4;
    int qx = (q ^ ((lm >> 1) & 3)) * 8;                    // swizzled ds_read k-quad

    // prologue: 2 groups in flight (4 gloads each per wave)
    #define G1_STAGE(AW, BW, k0) do { \
        gload16(aglob0 + (k0), (AW)); \
        gload16(aglob1 + (k0), (AW) + 16*32); \
        gload16(bglob0 + (k0), (BW)); \
        gload16(bglob1 + (k0), (BW) + 16*32); } while (0)

    G1_STAGE(AsW0, BsW0, 0);
    G1_STAGE(AsW1, BsW1, 32);
    const int NK = DD / 32;                                // 24
    for (int ks = 0; ks < NK; ks++) {
        int cur = ks & 1;
        const ushort* Ab = cur ? As[1] : As[0];
        const ushort* Bb = cur ? Bs[1] : Bs[0];
        ushort* AsN = cur ? AsW1 : AsW0;
        ushort* BsN = cur ? BsW1 : BsW0;
        if (ks < NK - 1) { asm volatile("s_waitcnt vmcnt(4)" ::: "memory"); }
        else             { asm volatile("s_waitcnt vmcnt(0)" ::: "memory"); }
        __builtin_amdgcn_s_barrier();
        bf16x8 afr[4], bfr[4];
        #pragma unroll
        for (int i = 0; i < 4; i++)
            afr[i] = *(const bf16x8*)(const void*)(Ab + (wm + i*16 + lm) * 32 + qx);
        #pragma unroll
        for (int j = 0; j < 4; j++)
            bfr[j] = *(const bf16x8*)(const void*)(Bb + (bbase + wn + j*16 + lm) * 32 + qx);
        asm volatile("s_waitcnt lgkmcnt(0)" ::: "memory");
        __builtin_amdgcn_sched_barrier(0);
        __builtin_amdgcn_s_barrier();
        if (ks + 2 < NK) G1_STAGE(AsN, BsN, ks*32 + 64);
        __builtin_amdgcn_s_setprio(1);
        MFMAS();
        __builtin_amdgcn_s_setprio(0);
    }
    #undef G1_STAGE

    #pragma unroll
    for (int i = 0; i < 4; i++) {
        #pragma unroll
        for (int j = 0; j < 4; j++) {
            int n = wn + j*16 + lm;
            float bias = b1[eh * FF + f0 + n];
            #pragma unroll
            for (int r = 0; r < 4; r++) {
                int m = wm + i*16 + q*4 + r;
                float hv = gelu_f(acc[i][j][r] + bias);
                H[(size_t)(p0 + m) * FF + f0 + n] = f2b(hv);
            }
        }
    }
}

// ---------- K6: GEMM2  Y = row_w * (H @ w2t[e]^T + b2[e]) ---------- (unchanged, BK=64)
#define STAGE64(AW, BW, k0) do { \
        _Pragma("unroll") \
        for (int g = 0; g < 4; g++) { \
            gload16(ag[g] + (k0), (AW) + g*8*64); \
            gload16(bg[g] + (k0), (BW) + g*8*64); \
        } } while (0)

#define LOADFR64(APTR, BPTR, QX) do { \
        _Pragma("unroll") \
        for (int i = 0; i < 4; i++) \
            afr[i] = *(const bf16x8*)(const void*)((APTR) + (wm + i*16 + lm) * 64 + (QX)); \
        _Pragma("unroll") \
        for (int j = 0; j < 4; j++) \
            bfr[j] = *(const bf16x8*)(const void*)((BPTR) + (wn + j*16 + lm) * 64 + (QX)); \
    } while (0)

#define PIPE64(NK) do { \
    STAGE64(AsW0, BsW0, 0); \
    STAGE64(AsW1, BsW1, 64); \
    for (int ks = 0; ks < (NK); ks++) { \
        int cur = ks & 1; \
        const ushort* Ab = cur ? As[1] : As[0]; \
        const ushort* Bb = cur ? Bs[1] : Bs[0]; \
        ushort* AsN = cur ? AsW1 : AsW0; \
        ushort* BsN = cur ? BsW1 : BsW0; \
        if (ks < (NK) - 1) { asm volatile("s_waitcnt vmcnt(8)" ::: "memory"); } \
        else               { asm volatile("s_waitcnt vmcnt(0)" ::: "memory"); } \
        __builtin_amdgcn_s_barrier(); \
        { \
            bf16x8 afr[4], bfr[4]; \
            LOADFR64(Ab, Bb, qx0); \
            __builtin_amdgcn_s_setprio(1); \
            MFMAS(); \
            __builtin_amdgcn_s_setprio(0); \
        } \
        { \
            bf16x8 afr[4], bfr[4]; \
            LOADFR64(Ab, Bb, qx0 ^ 32); \
            asm volatile("s_waitcnt lgkmcnt(0)" ::: "memory"); \
            __builtin_amdgcn_sched_barrier(0); \
            __builtin_amdgcn_s_barrier(); \
            if (ks + 2 < (NK)) STAGE64(AsN, BsN, ks*64 + 128); \
            __builtin_amdgcn_s_setprio(1); \
            MFMAS(); \
            __builtin_amdgcn_s_setprio(0); \
        } \
    } } while (0)

__global__ __launch_bounds__(256) void gemm2_kernel(
    const ushort* __restrict__ H, const ushort* __restrict__ w2t, const float* __restrict__ b2,
    const int* __restrict__ ctrl, const float* __restrict__ row_w, float* __restrict__ Y)
{
    int tile = blockIdx.x;
    int e = ctrl[24 + tile];
    if (e < 0) return;
    int p0 = tile * 128;
    int d0 = blockIdx.y * 128;

    __shared__ ushort As[2][128 * 64];
    __shared__ ushort Bs[2][128 * 64];

    int tid = threadIdx.x;
    int wave = tid >> 6, lane = tid & 63;
    int srow = lane >> 3;
    int kq = (((lane & 7) ^ (srow & 7))) * 8;
    const ushort* ag[4];
    #pragma unroll
    for (int g = 0; g < 4; g++)
        ag[g] = H + (size_t)(p0 + wave*32 + g*8 + srow) * FF + kq;
    const ushort* w2e = w2t + (size_t)e * (DD * FF);      // [d][f] row stride FF
    const ushort* bg[4];
    #pragma unroll
    for (int g = 0; g < 4; g++)
        bg[g] = w2e + (size_t)(d0 + wave*32 + g*8 + srow) * FF + kq;
    ushort* AsW0 = &As[0][wave * 32 * 64];
    ushort* BsW0 = &Bs[0][wave * 32 * 64];
    ushort* AsW1 = &As[1][wave * 32 * 64];
    ushort* BsW1 = &Bs[1][wave * 32 * 64];

    floatx4 zero4 = {0.f, 0.f, 0.f, 0.f};
    floatx4 acc[4][4];
    #pragma unroll
    for (int i = 0; i < 4; i++)
        #pragma unroll
        for (int j = 0; j < 4; j++) acc[i][j] = zero4;

    int wm = (wave & 1) * 64, wn = (wave >> 1) * 64;
    int lm = lane & 15, q = lane >> 4;
    int qx0 = (q ^ (lm & 7)) * 8;

    PIPE64(FF/64);

    #pragma unroll
    for (int i = 0; i < 4; i++) {
        #pragma unroll
        for (int j = 0; j < 4; j++) {
            int n = wn + j*16 + lm;
            float bias = b2[e * DD + d0 + n];
            #pragma unroll
            for (int r = 0; r < 4; r++) {
                int m = wm + i*16 + q*4 + r;
                float wgt = row_w[p0 + m];
                Y[(size_t)(p0 + m) * DD + d0 + n] = wgt * (acc[i][j][r] + bias);
            }
        }
    }
}

// ---------- K7: final combine (fp32 out) ----------
__global__ __launch_bounds__(256) void final_kernel(
    const float* __restrict__ Y, const int* __restrict__ slot, const float* __restrict__ feats,
    const float* __restrict__ out_w, const float* __restrict__ out_b,
    const float* __restrict__ bk_scale, float* __restrict__ out)
{
    int idx = blockIdx.x * 256 + threadIdx.x;
    int base = idx * 4;
    int t = base / DD;
    int d = base - t * DD;
    int p0 = slot[2*t], p1 = slot[2*t + 1];
    const float4 ya = *(const float4*)(Y + (size_t)p0 * DD + d);
    const float4 yb = *(const float4*)(Y + (size_t)p1 * DD + d);
    float f0 = feats[2*t], f1 = feats[2*t + 1];
    f0 = fminf(fmaxf(f0, -10.f), 10.f);
    f1 = fminf(fmaxf(f1, -10.f), 10.f);
    float ff[4] = {ya.x + yb.x, ya.y + yb.y, ya.z + yb.z, ya.w + yb.w};
    float4 o;
    float* op = (float*)&o;
    #pragma unroll
    for (int u = 0; u < 4; u++) {
        float spec = f0 * out_w[d + u] + f1 * out_w[DD + d + u] + out_b[d + u];
        op[u] = ff[u] + bk_scale[d + u] * spec;
    }
    *(float4*)(out + base) = o;
}

extern "C" void kernel_launch(void* const* d_in, const int* in_sizes, int n_in,
                              void* d_out, int out_size, void* d_ws, size_t ws_size,
                              hipStream_t stream)
{
    const float* x      = (const float*)d_in[0];
    const float* v_w    = (const float*)d_in[1];
    const float* v_b    = (const float*)d_in[2];
    const float* gate_w = (const float*)d_in[3];
    const float* gate_b = (const float*)d_in[4];
    const float* w1     = (const float*)d_in[5];
    const float* b1     = (const float*)d_in[6];
    const float* w2     = (const float*)d_in[7];
    const float* b2     = (const float*)d_in[8];
    const float* out_w  = (const float*)d_in[9];
    const float* out_b  = (const float*)d_in[10];
    const float* bk_s   = (const float*)d_in[11];

    char* ws = (char*)d_ws;
    int*    ctrl    = (int*)(ws + OFF_CTRL);
    float*  v       = (float*)(ws + OFF_V);
    int*    tok_e   = (int*)(ws + OFF_TOKE);
    float*  tok_w   = (float*)(ws + OFF_TOKW);
    int*    row_tok = (int*)(ws + OFF_ROWTOK);
    float*  row_w   = (float*)(ws + OFF_ROWW);
    int*    slot    = (int*)(ws + OFF_SLOT);
    float*  feats   = (float*)(ws + OFF_FEATS);
    ushort* w2t     = (ushort*)(ws + OFF_W2T);
    ushort* x_bf    = (ushort*)(ws + OFF_XBF);
    ushort* w1t     = (ushort*)(ws + OFF_W1T);
    ushort* H       = (ushort*)(ws + OFF_H);
    float*  Y       = (float*)(ws + OFF_Y);
    float*  out     = (float*)d_out;

    prep_kernel<<<NB_CVT + NB_ROUTE + NB_T1 + NB_T2, 256, 0, stream>>>(
        x, x_bf, v_w, v_b, gate_w, gate_b, v, tok_e, tok_w, w1, w1t, w2, w2t);
    setup_bk_kernel<<<1 + BB, 1024, 0, stream>>>(tok_e, tok_w, ctrl, row_tok, row_w, slot, v, feats);
    gemm1_kernel<<<dim3(FF / 128, TILES / 2), 512, 0, stream>>>(x_bf, w1t, b1, ctrl, row_tok, H);
    gemm2_kernel<<<dim3(TILES, DD / 128), 256, 0, stream>>>(H, w2t, b2, ctrl, row_w, Y);
    final_kernel<<<(TOK * DD) / 1024, 256, 0, stream>>>(Y, slot, feats, out_w, out_b, bk_s, out);
}

// Round 7
// 207.713 us; speedup vs baseline: 1.2562x; 1.0067x over previous
//
#include <hip/hip_runtime.h>
#include <hip/hip_bf16.h>

#define BB 2
#define NN 2048
#define DD 768
#define EE 8
#define FF 3072
#define TOK (BB*NN)       // 4096
#define ROWS_CAP 9216     // 8192 slots + 8*128 alignment pad
#define TILES 72          // ROWS_CAP / 128

typedef __attribute__((ext_vector_type(8))) __bf16 bf16x8;
typedef __attribute__((ext_vector_type(4))) float floatx4;

// ---------- ws layout (bytes) ----------
#define OFF_CTRL    0ull                    // int[96]: base@16, tile_expert@24
#define OFF_V       1024ull                 // float[4096]
#define OFF_TOKE    17408ull                // int[8192]
#define OFF_TOKW    50176ull                // float[8192]
#define OFF_ROWTOK  82944ull                // int[9216]
#define OFF_ROWW    119808ull               // float[9216]
#define OFF_SLOT    156672ull               // int[8192]
#define OFF_FEATS   189440ull               // float[8192]
// big buffers
#define OFF_W2T     222208ull               // ushort[8*768*3072] = 37,748,736 B   (w2^T: [e][d][f])
#define OFF_XBF     37970944ull             // ushort[4096*768]   = 6,291,456 B
#define OFF_W1T     44262400ull             // ushort[8*3072*768] = 37,748,736 B   (w1^T: [e][f][d])
#define OFF_H       82011136ull             // ushort[9216*3072]  = 56,623,104 B -> end 138,634,240
#define OFF_Y       OFF_XBF                 // float[9216*768] = 28,311,552 B, aliases dead XBF+W1T

__device__ __forceinline__ ushort f2b(float f) {
    union { float f; unsigned int i; } v; v.f = f;
    unsigned int u = v.i;
    unsigned int r = (u + 0x7FFFu + ((u >> 16) & 1u)) >> 16;
    return (ushort)r;
}
__device__ __forceinline__ unsigned int pk2(float lo, float hi) {
    union { float f; unsigned int u; } a, b;
    a.f = lo; b.f = hi;
    unsigned int ra = ((a.u + 0x7FFFu + ((a.u >> 16) & 1u)) >> 16) & 0xFFFFu;
    unsigned int rb = (b.u + 0x7FFFu + ((b.u >> 16) & 1u)) & 0xFFFF0000u;
    return ra | rb;
}
__device__ __forceinline__ float gelu_f(float x) {
    float z = 0.7978845608028654f * x * (1.f + 0.044715f * x * x);
    z = fminf(fmaxf(z, -12.f), 12.f);
    float e = __expf(2.f * z);
    return 0.5f * x * (1.f + (e - 1.f) / (e + 1.f));
}
// async global(16B/lane) -> LDS (wave-uniform base + lane*16)
__device__ __forceinline__ void gload16(const ushort* g, ushort* l) {
    __builtin_amdgcn_global_load_lds((const __attribute__((address_space(1))) void*)g,
                                     (__attribute__((address_space(3))) void*)l,
                                     16, 0, 0);
}

// ---------- complex / Mobius helpers ----------
struct cplx { float x, y; };
__device__ __forceinline__ cplx cmulc(cplx a, cplx b) { return {a.x*b.x - a.y*b.y, a.x*b.y + a.y*b.x}; }
__device__ __forceinline__ cplx caddc(cplx a, cplx b) { return {a.x + b.x, a.y + b.y}; }
__device__ __forceinline__ cplx cdivc(cplx a, cplx b) {
    float s = 1.f / (b.x*b.x + b.y*b.y);
    return {(a.x*b.x + a.y*b.y)*s, (a.y*b.x - a.x*b.y)*s};
}
struct mob { cplx m00, m01, m10, m11; };
__device__ __forceinline__ mob mmul(const mob& A, const mob& B) {
    mob C;
    C.m00 = caddc(cmulc(A.m00, B.m00), cmulc(A.m01, B.m10));
    C.m01 = caddc(cmulc(A.m00, B.m01), cmulc(A.m01, B.m11));
    C.m10 = caddc(cmulc(A.m10, B.m00), cmulc(A.m11, B.m10));
    C.m11 = caddc(cmulc(A.m10, B.m01), cmulc(A.m11, B.m11));
    return C;
}
__device__ __forceinline__ void mnorm(mob& A) {
    float s = fabsf(A.m00.x);
    s = fmaxf(s, fabsf(A.m00.y)); s = fmaxf(s, fabsf(A.m01.x)); s = fmaxf(s, fabsf(A.m01.y));
    s = fmaxf(s, fabsf(A.m10.x)); s = fmaxf(s, fabsf(A.m10.y)); s = fmaxf(s, fabsf(A.m11.x));
    s = fmaxf(s, fabsf(A.m11.y));
    float r = 1.f / fmaxf(s, 1e-30f);
    A.m00.x *= r; A.m00.y *= r; A.m01.x *= r; A.m01.y *= r;
    A.m10.x *= r; A.m10.y *= r; A.m11.x *= r; A.m11.y *= r;
}
__device__ __forceinline__ mob mstep(cplx a, const mob& P) {
    mob C;
    C.m00 = {a.x*P.m00.x - a.y*P.m00.y - P.m10.x, a.x*P.m00.y + a.y*P.m00.x - P.m10.y};
    C.m01 = {a.x*P.m01.x - a.y*P.m01.y - P.m11.x, a.x*P.m01.y + a.y*P.m01.x - P.m11.y};
    C.m10 = P.m00; C.m11 = P.m01;
    return C;
}
__device__ __forceinline__ void mstore(float* s, const mob& A) {
    s[0]=A.m00.x; s[1]=A.m00.y; s[2]=A.m01.x; s[3]=A.m01.y;
    s[4]=A.m10.x; s[5]=A.m10.y; s[6]=A.m11.x; s[7]=A.m11.y;
}
__device__ __forceinline__ mob mload(const float* s) {
    mob A;
    A.m00 = {s[0], s[1]}; A.m01 = {s[2], s[3]};
    A.m10 = {s[4], s[5]}; A.m11 = {s[6], s[7]};
    return A;
}

// ================= PREP: fused {x->bf16 cvt | routing | w1^T cvt | w2^T cvt} =================
// tcvt4: 32x128 strip per block, 4 float4 loads in flight per thread (4x MLP vs
// the 1-load round-5 version that sat at 3.1 TB/s, latency-bound). 4x fewer blocks.
#define NB_CVT   ((TOK*DD)/8/256)           // 1536
#define NB_ROUTE (TOK/4)                    // 1024
#define NB_T1    ((FF/128)*(DD/32)*EE)      // 4608  (w1: R=DD rows, C=FF cols)
#define NB_T2    ((DD/128)*(FF/32)*EE)      // 4608  (w2: R=FF, C=DD)

__device__ __forceinline__ void cvt_body(const float* __restrict__ src, ushort* __restrict__ dst, int i) {
    const float4* s = ((const float4*)src) + (size_t)i * 2;
    float4 a = s[0], b = s[1];
    uint4 o;
    o.x = pk2(a.x, a.y); o.y = pk2(a.z, a.w);
    o.z = pk2(b.x, b.y); o.w = pk2(b.z, b.w);
    *(((uint4*)dst) + i) = o;
}

__device__ __forceinline__ void tcvt4_body(const float* __restrict__ src, ushort* __restrict__ dst,
                                           int R, int C, int bx, int by, int bz,
                                           float (*t)[33]) {
    size_t eoff = (size_t)bz * R * C;
    const float* s = src + eoff;
    ushort* d = dst + eoff;
    int c0 = bx * 128, r0 = by * 32;
    int tid = threadIdx.x;
    int tr = tid >> 3, tc = (tid & 7) * 4;
    // all 4 loads issued before any LDS phase -> 4 in flight
    float4 v[4];
    const float* srow = s + (size_t)(r0 + tr) * C + c0 + tc;
    #pragma unroll
    for (int k = 0; k < 4; k++) v[k] = *(const float4*)(srow + k * 32);
    #pragma unroll
    for (int k = 0; k < 4; k++) {
        __syncthreads();   // WAR vs previous sub-tile's reads
        t[tr][tc] = v[k].x; t[tr][tc+1] = v[k].y; t[tr][tc+2] = v[k].z; t[tr][tc+3] = v[k].w;
        __syncthreads();
        ushort4 o;
        o.x = f2b(t[tc  ][tr]);
        o.y = f2b(t[tc+1][tr]);
        o.z = f2b(t[tc+2][tr]);
        o.w = f2b(t[tc+3][tr]);
        *(ushort4*)(d + (size_t)(c0 + k*32 + tr) * R + r0 + tc) = o;
    }
}

__device__ __forceinline__ void routing_body(
    const float* __restrict__ x, const float* __restrict__ v_w, const float* __restrict__ v_b,
    const float* __restrict__ gate_w, const float* __restrict__ gate_b,
    float* __restrict__ v_out, int* __restrict__ tok_e, float* __restrict__ tok_w, int blk)
{
    int wave = threadIdx.x >> 6, lane = threadIdx.x & 63;
    int t = blk * 4 + wave;
    const float* xr = x + (size_t)t * DD;
    float av = 0.f;
    float ag[8] = {0.f, 0.f, 0.f, 0.f, 0.f, 0.f, 0.f, 0.f};
    #pragma unroll
    for (int i = 0; i < 12; i++) {
        int d = lane + 64 * i;
        float xv = xr[d];
        av += xv * v_w[d];
        const float4* g = (const float4*)(gate_w + d * 8);
        float4 g0 = g[0], g1 = g[1];
        ag[0] += xv * g0.x; ag[1] += xv * g0.y; ag[2] += xv * g0.z; ag[3] += xv * g0.w;
        ag[4] += xv * g1.x; ag[5] += xv * g1.y; ag[6] += xv * g1.z; ag[7] += xv * g1.w;
    }
    #pragma unroll
    for (int off = 32; off >= 1; off >>= 1) {
        av += __shfl_xor(av, off);
        #pragma unroll
        for (int e = 0; e < 8; e++) ag[e] += __shfl_xor(ag[e], off);
    }
    if (lane == 0) {
        float vv = av + v_b[0];
        vv = fminf(fmaxf(vv, -3.f), 3.f);
        v_out[t] = vv;
        float lg[8];
        #pragma unroll
        for (int e = 0; e < 8; e++) lg[e] = ag[e] + gate_b[e];
        int e0 = 0;
        #pragma unroll
        for (int e = 1; e < 8; e++) if (lg[e] > lg[e0]) e0 = e;
        int e1 = -1;
        #pragma unroll
        for (int e = 0; e < 8; e++) if (e != e0 && (e1 < 0 || lg[e] > lg[e1])) e1 = e;
        float w0 = 1.f / (1.f + __expf(lg[e1] - lg[e0]));
        tok_e[2*t] = e0; tok_e[2*t+1] = e1;
        tok_w[2*t] = w0; tok_w[2*t+1] = 1.f - w0;
    }
}

__global__ __launch_bounds__(256) void prep_kernel(
    const float* __restrict__ x, ushort* __restrict__ x_bf,
    const float* __restrict__ v_w, const float* __restrict__ v_b,
    const float* __restrict__ gate_w, const float* __restrict__ gate_b,
    float* __restrict__ v_out, int* __restrict__ tok_e, float* __restrict__ tok_w,
    const float* __restrict__ w1, ushort* __restrict__ w1t,
    const float* __restrict__ w2, ushort* __restrict__ w2t)
{
    __shared__ float t[32][33];
    int id = blockIdx.x;
    if (id < NB_CVT) {
        cvt_body(x, x_bf, id * 256 + threadIdx.x);
        return;
    }
    id -= NB_CVT;
    if (id < NB_ROUTE) {
        routing_body(x, v_w, v_b, gate_w, gate_b, v_out, tok_e, tok_w, id);
        return;
    }
    id -= NB_ROUTE;
    if (id < NB_T1) {
        int bx = id % (FF/128); int by = (id / (FF/128)) % (DD/32); int bz = id / ((FF/128)*(DD/32));
        tcvt4_body(w1, w1t, DD, FF, bx, by, bz, t);
        return;
    }
    id -= NB_T1;
    {
        int bx = id % (DD/128); int by = (id / (DD/128)) % (FF/32); int bz = id / ((DD/128)*(FF/32));
        tcvt4_body(w2, w2t, FF, DD, bx, by, bz, t);
    }
}

// ============ SETUP+BK: block 0 = scatter setup (1024 thr), blocks 1..2 = BK scan ============
__device__ void setup_body(
    const int* __restrict__ tok_e, const float* __restrict__ tok_w,
    int* __restrict__ ctrl, int* __restrict__ row_token, float* __restrict__ row_w,
    int* __restrict__ slot)
{
    __shared__ int cnt[8], base[8], cursor[8];
    int tid = threadIdx.x;
    int lane = tid & 63;
    if (tid < 8) { cnt[tid] = 0; cursor[tid] = 0; }
    __syncthreads();

    int mye[8];
    #pragma unroll
    for (int it = 0; it < 8; it++) {
        int idx = it * 1024 + tid;
        int e = tok_e[idx];
        mye[it] = e;
        #pragma unroll
        for (int ex = 0; ex < 8; ex++) {
            unsigned long long m = __ballot(e == ex);
            if (e == ex && lane == (__ffsll((long long)m) - 1))
                atomicAdd(&cnt[ex], (int)__popcll(m));
        }
    }
    __syncthreads();
    if (tid == 0) {
        int b = 0;
        int* te = ctrl + 24;
        for (int i = 0; i < TILES; i++) te[i] = -1;
        #pragma unroll
        for (int e = 0; e < EE; e++) {
            base[e] = b;
            ctrl[16 + e] = b;
            int tiles = (cnt[e] + 127) >> 7;
            int t0 = b >> 7;
            for (int i = 0; i < tiles; i++) te[t0 + i] = e;
            b += tiles << 7;
        }
    }
    for (int p = tid; p < ROWS_CAP; p += 1024) row_token[p] = -1;
    __syncthreads();

    #pragma unroll
    for (int it = 0; it < 8; it++) {
        int idx = it * 1024 + tid;
        int e = mye[it];
        unsigned long long lt = (1ull << lane) - 1ull;
        int p = 0;
        #pragma unroll
        for (int ex = 0; ex < 8; ex++) {
            unsigned long long m = __ballot(e == ex);
            if (e == ex) {
                int leader = __ffsll((long long)m) - 1;
                int pos = (int)__popcll(m & lt);
                int bp = 0;
                if (lane == leader) bp = atomicAdd(&cursor[ex], (int)__popcll(m));
                bp = __shfl(bp, leader);
                p = base[ex] + bp + pos;
            }
        }
        row_token[p] = idx >> 1;
        row_w[p] = tok_w[idx];
        slot[idx] = p;
    }
}

// BK scan body for one batch row inside a 1024-thread block (threads >=256 barrier-only).
__device__ void bk_body(int b, const float* __restrict__ v, float* __restrict__ feats) {
    int t = threadIdx.x;
    bool act = t < 256;
    __shared__ float sm[256][8];
    const mob I = {{1.f,0.f},{0.f,0.f},{0.f,0.f},{1.f,0.f}};
    cplx a[8];
    const float* vb = v + (size_t)b * NN;
    if (act) {
        #pragma unroll
        for (int j = 0; j < 8; j++) { a[j].x = -2.f + vb[t*8 + j]; a[j].y = -1.f; }
    }

    mob cur = I;
    if (act) {
        #pragma unroll
        for (int j = 0; j < 8; j++) cur = mstep(a[j], cur);
        mnorm(cur);
        mstore(sm[t], cur);
    }
    for (int s = 1; s < 256; s <<= 1) {
        __syncthreads();
        mob prev; bool has = act && (t >= s);
        if (has) prev = mload(sm[t - s]);
        __syncthreads();
        if (has) { cur = mmul(cur, prev); mnorm(cur); mstore(sm[t], cur); }
    }
    __syncthreads();
    cplx dreg[8];
    if (act) {
        mob P = (t > 0) ? mload(sm[t - 1]) : I;
        #pragma unroll
        for (int j = 0; j < 8; j++) {
            P = mstep(a[j], P); mnorm(P);
            dreg[j] = cdivc(P.m00, P.m10);
        }
    }
    __syncthreads();

    cur = I;
    if (act) {
        #pragma unroll
        for (int j = 7; j >= 0; j--) cur = mstep(a[j], cur);
        mnorm(cur);
        mstore(sm[t], cur);
    }
    for (int s = 1; s < 256; s <<= 1) {
        __syncthreads();
        mob nxt; bool has = act && (t + s < 256);
        if (has) nxt = mload(sm[t + s]);
        __syncthreads();
        if (has) { cur = mmul(cur, nxt); mnorm(cur); mstore(sm[t], cur); }
    }
    __syncthreads();
    if (act) {
        mob P = (t < 255) ? mload(sm[t + 1]) : I;
        #pragma unroll
        for (int j = 7; j >= 0; j--) {
            P = mstep(a[j], P); mnorm(P);
            cplx e = cdivc(P.m00, P.m10);
            cplx den = {dreg[j].x + e.x - a[j].x, dreg[j].y + e.y - a[j].y};
            cplx one = {1.f, 0.f};
            cplx G = cdivc(one, den);
            int i = b * NN + t*8 + j;
            feats[2*i]   = G.x;
            feats[2*i+1] = G.y;
        }
    }
}

__global__ __launch_bounds__(1024) void setup_bk_kernel(
    const int* __restrict__ tok_e, const float* __restrict__ tok_w,
    int* __restrict__ ctrl, int* __restrict__ row_token, float* __restrict__ row_w,
    int* __restrict__ slot, const float* __restrict__ v, float* __restrict__ feats)
{
    if (blockIdx.x == 0) setup_body(tok_e, tok_w, ctrl, row_token, row_w, slot);
    else                 bk_body(blockIdx.x - 1, v, feats);
}

#define MFMAS() do { \
        _Pragma("unroll") \
        for (int i = 0; i < 4; i++) \
            _Pragma("unroll") \
            for (int j = 0; j < 4; j++) \
                acc[i][j] = __builtin_amdgcn_mfma_f32_16x16x32_bf16(afr[i], bfr[j], acc[i][j], 0, 0, 0); \
    } while (0)

// ---------- K5: GEMM1  H = gelu(Xg @ w1t[e]^T + b1[e]) ----------
// 256-row x 128-f tile, 8 waves (512 thr), BK=32, counted-vmcnt 2-deep pipeline.
// Expert regions are 128-aligned, so a 256-tile's two M-halves may belong to
// different experts: Bs holds TWO 128-row panels (half h = rows h*128..h*128+127,
// expert te[2*tile+h]). Wave w: wm=(w>>1)*64, wn=(w&1)*64; its half = w>>2, and
// it stages exactly the B rows it consumes (dest row w*32 = (w>>2)*128+(w&3)*32).
// vs round-5 128x128: A-staging bytes /2, blocks /2 (864), 16 waves/CU (2 blk).
// Swizzle identical to round 4 (0 bank conflicts verified).
__global__ __launch_bounds__(512, 4) void gemm1_kernel(
    const ushort* __restrict__ x_bf, const ushort* __restrict__ w1t, const float* __restrict__ b1,
    const int* __restrict__ ctrl, const int* __restrict__ row_token, ushort* __restrict__ H)
{
    int tile = blockIdx.y;                     // 256-row tile, 0..35
    int e0 = ctrl[24 + 2*tile];
    if (e0 < 0) return;
    int e1 = ctrl[24 + 2*tile + 1];
    if (e1 < 0) e1 = e0;                       // half1 all-pad: compute garbage, never read
    int p0 = tile * 256;
    int f0 = blockIdx.x * 128;

    __shared__ ushort As[2][256 * 32];
    __shared__ ushort Bs[2][256 * 32];         // rows 0-127: e0 panel, 128-255: e1 panel
    __shared__ int toks[256];

    int tid = threadIdx.x;
    if (tid < 256) { int tk = row_token[p0 + tid]; toks[tid] = tk < 0 ? 0 : tk; }
    __syncthreads();

    int wave = tid >> 6, lane = tid & 63;
    int rsub = lane >> 2;                                  // row within 16-row gload group
    int kq = (((lane & 3) ^ ((rsub >> 1) & 3))) * 8;       // swizzled global k-quad (ushorts)
    int tokA0 = toks[wave*32 + rsub];
    int tokA1 = toks[wave*32 + 16 + rsub];
    const ushort* aglob0 = x_bf + (size_t)tokA0 * DD + kq;
    const ushort* aglob1 = x_bf + (size_t)tokA1 * DD + kq;
    int eh = (wave >> 2) ? e1 : e0;                        // this wave's half-expert
    const ushort* w1e = w1t + (size_t)eh * (FF * DD);      // [f][d] row stride DD
    const ushort* bglob0 = w1e + (size_t)(f0 + (wave & 3)*32 + rsub) * DD + kq;
    const ushort* bglob1 = bglob0 + (size_t)16 * DD;
    ushort* AsW0 = &As[0][wave * 32 * 32];
    ushort* BsW0 = &Bs[0][wave * 32 * 32];
    ushort* AsW1 = &As[1][wave * 32 * 32];
    ushort* BsW1 = &Bs[1][wave * 32 * 32];

    floatx4 zero4 = {0.f, 0.f, 0.f, 0.f};
    floatx4 acc[4][4];
    #pragma unroll
    for (int i = 0; i < 4; i++)
        #pragma unroll
        for (int j = 0; j < 4; j++) acc[i][j] = zero4;

    int wm = (wave >> 1) * 64, wn = (wave & 1) * 64;
    int bbase = (wave >> 2) * 128;                         // B panel base row for this half
    int lm = lane & 15, q = lane >> 4;
    int qx = (q ^ ((lm >> 1) & 3)) * 8;                    // swizzled ds_read k-quad

    // prologue: 2 groups in flight (4 gloads each per wave)
    #define G1_STAGE(AW, BW, k0) do { \
        gload16(aglob0 + (k0), (AW)); \
        gload16(aglob1 + (k0), (AW) + 16*32); \
        gload16(bglob0 + (k0), (BW)); \
        gload16(bglob1 + (k0), (BW) + 16*32); } while (0)

    G1_STAGE(AsW0, BsW0, 0);
    G1_STAGE(AsW1, BsW1, 32);
    const int NK = DD / 32;                                // 24
    for (int ks = 0; ks < NK; ks++) {
        int cur = ks & 1;
        const ushort* Ab = cur ? As[1] : As[0];
        const ushort* Bb = cur ? Bs[1] : Bs[0];
        ushort* AsN = cur ? AsW1 : AsW0;
        ushort* BsN = cur ? BsW1 : BsW0;
        if (ks < NK - 1) { asm volatile("s_waitcnt vmcnt(4)" ::: "memory"); }
        else             { asm volatile("s_waitcnt vmcnt(0)" ::: "memory"); }
        __builtin_amdgcn_s_barrier();
        bf16x8 afr[4], bfr[4];
        #pragma unroll
        for (int i = 0; i < 4; i++)
            afr[i] = *(const bf16x8*)(const void*)(Ab + (wm + i*16 + lm) * 32 + qx);
        #pragma unroll
        for (int j = 0; j < 4; j++)
            bfr[j] = *(const bf16x8*)(const void*)(Bb + (bbase + wn + j*16 + lm) * 32 + qx);
        asm volatile("s_waitcnt lgkmcnt(0)" ::: "memory");
        __builtin_amdgcn_sched_barrier(0);
        __builtin_amdgcn_s_barrier();
        if (ks + 2 < NK) G1_STAGE(AsN, BsN, ks*32 + 64);
        __builtin_amdgcn_s_setprio(1);
        MFMAS();
        __builtin_amdgcn_s_setprio(0);
    }
    #undef G1_STAGE

    #pragma unroll
    for (int i = 0; i < 4; i++) {
        #pragma unroll
        for (int j = 0; j < 4; j++) {
            int n = wn + j*16 + lm;
            float bias = b1[eh * FF + f0 + n];
            #pragma unroll
            for (int r = 0; r < 4; r++) {
                int m = wm + i*16 + q*4 + r;
                float hv = gelu_f(acc[i][j][r] + bias);
                H[(size_t)(p0 + m) * FF + f0 + n] = f2b(hv);
            }
        }
    }
}

// ---------- K6: GEMM2  Y = row_w * (H @ w2t[e]^T + b2[e]) ---------- (unchanged, BK=64)
#define STAGE64(AW, BW, k0) do { \
        _Pragma("unroll") \
        for (int g = 0; g < 4; g++) { \
            gload16(ag[g] + (k0), (AW) + g*8*64); \
            gload16(bg[g] + (k0), (BW) + g*8*64); \
        } } while (0)

#define LOADFR64(APTR, BPTR, QX) do { \
        _Pragma("unroll") \
        for (int i = 0; i < 4; i++) \
            afr[i] = *(const bf16x8*)(const void*)((APTR) + (wm + i*16 + lm) * 64 + (QX)); \
        _Pragma("unroll") \
        for (int j = 0; j < 4; j++) \
            bfr[j] = *(const bf16x8*)(const void*)((BPTR) + (wn + j*16 + lm) * 64 + (QX)); \
    } while (0)

#define PIPE64(NK) do { \
    STAGE64(AsW0, BsW0, 0); \
    STAGE64(AsW1, BsW1, 64); \
    for (int ks = 0; ks < (NK); ks++) { \
        int cur = ks & 1; \
        const ushort* Ab = cur ? As[1] : As[0]; \
        const ushort* Bb = cur ? Bs[1] : Bs[0]; \
        ushort* AsN = cur ? AsW1 : AsW0; \
        ushort* BsN = cur ? BsW1 : BsW0; \
        if (ks < (NK) - 1) { asm volatile("s_waitcnt vmcnt(8)" ::: "memory"); } \
        else               { asm volatile("s_waitcnt vmcnt(0)" ::: "memory"); } \
        __builtin_amdgcn_s_barrier(); \
        { \
            bf16x8 afr[4], bfr[4]; \
            LOADFR64(Ab, Bb, qx0); \
            __builtin_amdgcn_s_setprio(1); \
            MFMAS(); \
            __builtin_amdgcn_s_setprio(0); \
        } \
        { \
            bf16x8 afr[4], bfr[4]; \
            LOADFR64(Ab, Bb, qx0 ^ 32); \
            asm volatile("s_waitcnt lgkmcnt(0)" ::: "memory"); \
            __builtin_amdgcn_sched_barrier(0); \
            __builtin_amdgcn_s_barrier(); \
            if (ks + 2 < (NK)) STAGE64(AsN, BsN, ks*64 + 128); \
            __builtin_amdgcn_s_setprio(1); \
            MFMAS(); \
            __builtin_amdgcn_s_setprio(0); \
        } \
    } } while (0)

__global__ __launch_bounds__(256) void gemm2_kernel(
    const ushort* __restrict__ H, const ushort* __restrict__ w2t, const float* __restrict__ b2,
    const int* __restrict__ ctrl, const float* __restrict__ row_w, float* __restrict__ Y)
{
    int tile = blockIdx.x;
    int e = ctrl[24 + tile];
    if (e < 0) return;
    int p0 = tile * 128;
    int d0 = blockIdx.y * 128;

    __shared__ ushort As[2][128 * 64];
    __shared__ ushort Bs[2][128 * 64];

    int tid = threadIdx.x;
    int wave = tid >> 6, lane = tid & 63;
    int srow = lane >> 3;
    int kq = (((lane & 7) ^ (srow & 7))) * 8;
    const ushort* ag[4];
    #pragma unroll
    for (int g = 0; g < 4; g++)
        ag[g] = H + (size_t)(p0 + wave*32 + g*8 + srow) * FF + kq;
    const ushort* w2e = w2t + (size_t)e * (DD * FF);      // [d][f] row stride FF
    const ushort* bg[4];
    #pragma unroll
    for (int g = 0; g < 4; g++)
        bg[g] = w2e + (size_t)(d0 + wave*32 + g*8 + srow) * FF + kq;
    ushort* AsW0 = &As[0][wave * 32 * 64];
    ushort* BsW0 = &Bs[0][wave * 32 * 64];
    ushort* AsW1 = &As[1][wave * 32 * 64];
    ushort* BsW1 = &Bs[1][wave * 32 * 64];

    floatx4 zero4 = {0.f, 0.f, 0.f, 0.f};
    floatx4 acc[4][4];
    #pragma unroll
    for (int i = 0; i < 4; i++)
        #pragma unroll
        for (int j = 0; j < 4; j++) acc[i][j] = zero4;

    int wm = (wave & 1) * 64, wn = (wave >> 1) * 64;
    int lm = lane & 15, q = lane >> 4;
    int qx0 = (q ^ (lm & 7)) * 8;

    PIPE64(FF/64);

    #pragma unroll
    for (int i = 0; i < 4; i++) {
        #pragma unroll
        for (int j = 0; j < 4; j++) {
            int n = wn + j*16 + lm;
            float bias = b2[e * DD + d0 + n];
            #pragma unroll
            for (int r = 0; r < 4; r++) {
                int m = wm + i*16 + q*4 + r;
                float wgt = row_w[p0 + m];
                Y[(size_t)(p0 + m) * DD + d0 + n] = wgt * (acc[i][j][r] + bias);
            }
        }
    }
}

// ---------- K7: final combine (fp32 out) ----------
__global__ __launch_bounds__(256) void final_kernel(
    const float* __restrict__ Y, const int* __restrict__ slot, const float* __restrict__ feats,
    const float* __restrict__ out_w, const float* __restrict__ out_b,
    const float* __restrict__ bk_scale, float* __restrict__ out)
{
    int idx = blockIdx.x * 256 + threadIdx.x;
    int base = idx * 4;
    int t = base / DD;
    int d = base - t * DD;
    int p0 = slot[2*t], p1 = slot[2*t + 1];
    const float4 ya = *(const float4*)(Y + (size_t)p0 * DD + d);
    const float4 yb = *(const float4*)(Y + (size_t)p1 * DD + d);
    float f0 = feats[2*t], f1 = feats[2*t + 1];
    f0 = fminf(fmaxf(f0, -10.f), 10.f);
    f1 = fminf(fmaxf(f1, -10.f), 10.f);
    float ff[4] = {ya.x + yb.x, ya.y + yb.y, ya.z + yb.z, ya.w + yb.w};
    float4 o;
    float* op = (float*)&o;
    #pragma unroll
    for (int u = 0; u < 4; u++) {
        float spec = f0 * out_w[d + u] + f1 * out_w[DD + d + u] + out_b[d + u];
        op[u] = ff[u] + bk_scale[d + u] * spec;
    }
    *(float4*)(out + base) = o;
}

extern "C" void kernel_launch(void* const* d_in, const int* in_sizes, int n_in,
                              void* d_out, int out_size, void* d_ws, size_t ws_size,
                              hipStream_t stream)
{
    const float* x      = (const float*)d_in[0];
    const float* v_w    = (const float*)d_in[1];
    const float* v_b    = (const float*)d_in[2];
    const float* gate_w = (const float*)d_in[3];
    const float* gate_b = (const float*)d_in[4];
    const float* w1     = (const float*)d_in[5];
    const float* b1     = (const float*)d_in[6];
    const float* w2     = (const float*)d_in[7];
    const float* b2     = (const float*)d_in[8];
    const float* out_w  = (const float*)d_in[9];
    const float* out_b  = (const float*)d_in[10];
    const float* bk_s   = (const float*)d_in[11];

    char* ws = (char*)d_ws;
    int*    ctrl    = (int*)(ws + OFF_CTRL);
    float*  v       = (float*)(ws + OFF_V);
    int*    tok_e   = (int*)(ws + OFF_TOKE);
    float*  tok_w   = (float*)(ws + OFF_TOKW);
    int*    row_tok = (int*)(ws + OFF_ROWTOK);
    float*  row_w   = (float*)(ws + OFF_ROWW);
    int*    slot    = (int*)(ws + OFF_SLOT);
    float*  feats   = (float*)(ws + OFF_FEATS);
    ushort* w2t     = (ushort*)(ws + OFF_W2T);
    ushort* x_bf    = (ushort*)(ws + OFF_XBF);
    ushort* w1t     = (ushort*)(ws + OFF_W1T);
    ushort* H       = (ushort*)(ws + OFF_H);
    float*  Y       = (float*)(ws + OFF_Y);
    float*  out     = (float*)d_out;

    prep_kernel<<<NB_CVT + NB_ROUTE + NB_T1 + NB_T2, 256, 0, stream>>>(
        x, x_bf, v_w, v_b, gate_w, gate_b, v, tok_e, tok_w, w1, w1t, w2, w2t);
    setup_bk_kernel<<<1 + BB, 1024, 0, stream>>>(tok_e, tok_w, ctrl, row_tok, row_w, slot, v, feats);
    gemm1_kernel<<<dim3(FF / 128, TILES / 2), 512, 0, stream>>>(x_bf, w1t, b1, ctrl, row_tok, H);
    gemm2_kernel<<<dim3(TILES, DD / 128), 256, 0, stream>>>(H, w2t, b2, ctrl, row_w, Y);
    final_kernel<<<(TOK * DD) / 1024, 256, 0, stream>>>(Y, slot, feats, out_w, out_b, bk_s, out);
}

// Round 8
// 197.824 us; speedup vs baseline: 1.3190x; 1.0500x over previous
//
#include <hip/hip_runtime.h>
#include <hip/hip_bf16.h>

#define BB 2
#define NN 2048
#define DD 768
#define EE 8
#define FF 3072
#define TOK (BB*NN)       // 4096
#define ROWS_CAP 9216     // 8192 slots + 8*128 alignment pad
#define TILES 72          // ROWS_CAP / 128

typedef __attribute__((ext_vector_type(8))) __bf16 bf16x8;
typedef __attribute__((ext_vector_type(4))) float floatx4;

// ---------- ws layout (bytes) ----------
#define OFF_CTRL    0ull
#define OFF_V       1024ull
#define OFF_TOKE    17408ull
#define OFF_TOKW    50176ull
#define OFF_ROWTOK  82944ull
#define OFF_ROWW    119808ull
#define OFF_SLOT    156672ull
#define OFF_FEATS   189440ull
#define OFF_W2T     222208ull               // ushort[8*768*3072] (w2^T: [e][d][f'], f' perm)
#define OFF_XBF     37970944ull             // ushort[4096*768]
#define OFF_W1T     44262400ull             // ushort[8*3072*768] (w1^T: [e][f][d])
#define OFF_H       82011136ull             // ushort[9216*3072]  (f' perm layout)
#define OFF_Y       OFF_XBF                 // float[9216*768], aliases dead XBF+W1T

__device__ __forceinline__ ushort f2b(float f) {
    union { float f; unsigned int i; } v; v.f = f;
    unsigned int u = v.i;
    unsigned int r = (u + 0x7FFFu + ((u >> 16) & 1u)) >> 16;
    return (ushort)r;
}
__device__ __forceinline__ unsigned int pk2(float lo, float hi) {
    union { float f; unsigned int u; } a, b;
    a.f = lo; b.f = hi;
    unsigned int ra = ((a.u + 0x7FFFu + ((a.u >> 16) & 1u)) >> 16) & 0xFFFFu;
    unsigned int rb = (b.u + 0x7FFFu + ((b.u >> 16) & 1u)) & 0xFFFF0000u;
    return ra | rb;
}
__device__ __forceinline__ float gelu_f(float x) {
    float z = 0.7978845608028654f * x * (1.f + 0.044715f * x * x);
    z = fminf(fmaxf(z, -12.f), 12.f);
    float e = __expf(2.f * z);
    return 0.5f * x * (1.f + (e - 1.f) / (e + 1.f));
}
__device__ __forceinline__ void gload16(const ushort* g, ushort* l) {
    __builtin_amdgcn_global_load_lds((const __attribute__((address_space(1))) void*)g,
                                     (__attribute__((address_space(3))) void*)l,
                                     16, 0, 0);
}

// ---------- complex / Mobius helpers ----------
struct cplx { float x, y; };
__device__ __forceinline__ cplx cmulc(cplx a, cplx b) { return {a.x*b.x - a.y*b.y, a.x*b.y + a.y*b.x}; }
__device__ __forceinline__ cplx caddc(cplx a, cplx b) { return {a.x + b.x, a.y + b.y}; }
__device__ __forceinline__ cplx cdivc(cplx a, cplx b) {
    float s = 1.f / (b.x*b.x + b.y*b.y);
    return {(a.x*b.x + a.y*b.y)*s, (a.y*b.x - a.x*b.y)*s};
}
struct mob { cplx m00, m01, m10, m11; };
__device__ __forceinline__ mob mmul(const mob& A, const mob& B) {
    mob C;
    C.m00 = caddc(cmulc(A.m00, B.m00), cmulc(A.m01, B.m10));
    C.m01 = caddc(cmulc(A.m00, B.m01), cmulc(A.m01, B.m11));
    C.m10 = caddc(cmulc(A.m10, B.m00), cmulc(A.m11, B.m10));
    C.m11 = caddc(cmulc(A.m10, B.m01), cmulc(A.m11, B.m11));
    return C;
}
__device__ __forceinline__ void mnorm(mob& A) {
    float s = fabsf(A.m00.x);
    s = fmaxf(s, fabsf(A.m00.y)); s = fmaxf(s, fabsf(A.m01.x)); s = fmaxf(s, fabsf(A.m01.y));
    s = fmaxf(s, fabsf(A.m10.x)); s = fmaxf(s, fabsf(A.m10.y)); s = fmaxf(s, fabsf(A.m11.x));
    s = fmaxf(s, fabsf(A.m11.y));
    float r = 1.f / fmaxf(s, 1e-30f);
    A.m00.x *= r; A.m00.y *= r; A.m01.x *= r; A.m01.y *= r;
    A.m10.x *= r; A.m10.y *= r; A.m11.x *= r; A.m11.y *= r;
}
__device__ __forceinline__ mob mstep(cplx a, const mob& P) {
    mob C;
    C.m00 = {a.x*P.m00.x - a.y*P.m00.y - P.m10.x, a.x*P.m00.y + a.y*P.m00.x - P.m10.y};
    C.m01 = {a.x*P.m01.x - a.y*P.m01.y - P.m11.x, a.x*P.m01.y + a.y*P.m01.x - P.m11.y};
    C.m10 = P.m00; C.m11 = P.m01;
    return C;
}
__device__ __forceinline__ void mstore(float* s, const mob& A) {
    s[0]=A.m00.x; s[1]=A.m00.y; s[2]=A.m01.x; s[3]=A.m01.y;
    s[4]=A.m10.x; s[5]=A.m10.y; s[6]=A.m11.x; s[7]=A.m11.y;
}
__device__ __forceinline__ mob mload(const float* s) {
    mob A;
    A.m00 = {s[0], s[1]}; A.m01 = {s[2], s[3]};
    A.m10 = {s[4], s[5]}; A.m11 = {s[6], s[7]};
    return A;
}

// ============ 64x64 transpose-convert: fp32 [Rs][Cs] tile -> bf16 [Cs][Rs] ============
// 4 float4 loads in flight; convert->LDS TRANSPOSED bf16 [64 c][72 r-pad]; read 16B
// rows; store 16B/lane (8 lanes -> 128B contiguous segments: no partial-line RMW).
// PERM (w2 only): dst f-index permuted within 32-groups, pos(b*16+lm) = lm*2+b,
// matching gemm1's paired-bf16 H store; gemm2 consumes both in stored order.
template<bool PERM>
__device__ __forceinline__ void tcvt64_body(
    const float* __restrict__ src, ushort* __restrict__ dst,
    int Rs, int Cs, int r0, int c0, ushort* __restrict__ tT /* [64*72] */, int tid)
{
    int lr = tid >> 2;                  // src row 0..63
    int lc0 = (tid & 3) * 16;           // src col base (16 floats per thread)
    const float* sp = src + (size_t)(r0 + lr) * Cs + c0 + lc0;
    float4 v[4];
    #pragma unroll
    for (int u = 0; u < 4; u++) v[u] = *(const float4*)(sp + 4*u);
    #pragma unroll
    for (int u = 0; u < 4; u++) {
        tT[(lc0 + 4*u + 0) * 72 + lr] = f2b(v[u].x);
        tT[(lc0 + 4*u + 1) * 72 + lr] = f2b(v[u].y);
        tT[(lc0 + 4*u + 2) * 72 + lr] = f2b(v[u].z);
        tT[(lc0 + 4*u + 3) * 72 + lr] = f2b(v[u].w);
    }
    __syncthreads();
    int chunk = tid & 7;                // 8 r-elements = 16B per store
    #pragma unroll
    for (int pass = 0; pass < 2; pass++) {
        int c = (tid >> 3) + pass * 32; // out row (src col) 0..63
        size_t off = (size_t)(c0 + c) * Rs + r0 + chunk * 8;
        if (PERM) {
            int a64 = chunk * 8;
            int g32 = (a64 >> 5) * 32;
            int a = a64 & 31;
            ushort o8[8] __attribute__((aligned(16)));
            #pragma unroll
            for (int k = 0; k < 8; k++) {
                int pk = a + k;                               // permuted pos within 32
                int rl = g32 + (pk >> 1) + ((pk & 1) << 4);   // logical r (inverse perm)
                o8[k] = tT[c * 72 + rl];
            }
            *(uint4*)(dst + off) = *(const uint4*)o8;
        } else {
            *(uint4*)(dst + off) = *(const uint4*)(tT + c * 72 + chunk * 8);
        }
    }
}

// ================= PREP1: {x->bf16 cvt | routing | w1^T} (w2^T moved into gemm1 launch) ========
#define NB_CVT   ((TOK*DD)/8/256)           // 1536
#define NB_ROUTE (TOK/4)                    // 1024
#define NB_W1T   (12*48*EE)                 // 4608 (w1: 768/64 r-tiles x 3072/64 c-tiles x 8)

__device__ __forceinline__ void cvt_body(const float* __restrict__ src, ushort* __restrict__ dst, int i) {
    const float4* s = ((const float4*)src) + (size_t)i * 2;
    float4 a = s[0], b = s[1];
    uint4 o;
    o.x = pk2(a.x, a.y); o.y = pk2(a.z, a.w);
    o.z = pk2(b.x, b.y); o.w = pk2(b.z, b.w);
    *(((uint4*)dst) + i) = o;
}

__device__ __forceinline__ void routing_body(
    const float* __restrict__ x, const float* __restrict__ v_w, const float* __restrict__ v_b,
    const float* __restrict__ gate_w, const float* __restrict__ gate_b,
    float* __restrict__ v_out, int* __restrict__ tok_e, float* __restrict__ tok_w, int blk)
{
    int wave = threadIdx.x >> 6, lane = threadIdx.x & 63;
    int t = blk * 4 + wave;
    const float* xr = x + (size_t)t * DD;
    float av = 0.f;
    float ag[8] = {0.f, 0.f, 0.f, 0.f, 0.f, 0.f, 0.f, 0.f};
    #pragma unroll
    for (int i = 0; i < 12; i++) {
        int d = lane + 64 * i;
        float xv = xr[d];
        av += xv * v_w[d];
        const float4* g = (const float4*)(gate_w + d * 8);
        float4 g0 = g[0], g1 = g[1];
        ag[0] += xv * g0.x; ag[1] += xv * g0.y; ag[2] += xv * g0.z; ag[3] += xv * g0.w;
        ag[4] += xv * g1.x; ag[5] += xv * g1.y; ag[6] += xv * g1.z; ag[7] += xv * g1.w;
    }
    #pragma unroll
    for (int off = 32; off >= 1; off >>= 1) {
        av += __shfl_xor(av, off);
        #pragma unroll
        for (int e = 0; e < 8; e++) ag[e] += __shfl_xor(ag[e], off);
    }
    if (lane == 0) {
        float vv = av + v_b[0];
        vv = fminf(fmaxf(vv, -3.f), 3.f);
        v_out[t] = vv;
        float lg[8];
        #pragma unroll
        for (int e = 0; e < 8; e++) lg[e] = ag[e] + gate_b[e];
        int e0 = 0;
        #pragma unroll
        for (int e = 1; e < 8; e++) if (lg[e] > lg[e0]) e0 = e;
        int e1 = -1;
        #pragma unroll
        for (int e = 0; e < 8; e++) if (e != e0 && (e1 < 0 || lg[e] > lg[e1])) e1 = e;
        float w0 = 1.f / (1.f + __expf(lg[e1] - lg[e0]));
        tok_e[2*t] = e0; tok_e[2*t+1] = e1;
        tok_w[2*t] = w0; tok_w[2*t+1] = 1.f - w0;
    }
}

__global__ __launch_bounds__(256) void prep1_kernel(
    const float* __restrict__ x, ushort* __restrict__ x_bf,
    const float* __restrict__ v_w, const float* __restrict__ v_b,
    const float* __restrict__ gate_w, const float* __restrict__ gate_b,
    float* __restrict__ v_out, int* __restrict__ tok_e, float* __restrict__ tok_w,
    const float* __restrict__ w1, ushort* __restrict__ w1t)
{
    __shared__ __align__(16) ushort tT[64 * 72];
    int id = blockIdx.x;
    if (id < NB_CVT) {
        cvt_body(x, x_bf, id * 256 + threadIdx.x);
        return;
    }
    id -= NB_CVT;
    if (id < NB_ROUTE) {
        routing_body(x, v_w, v_b, gate_w, gate_b, v_out, tok_e, tok_w, id);
        return;
    }
    id -= NB_ROUTE;
    // w1 [e][768][3072] -> w1t [e][3072][768], no perm
    int e = id / (12 * 48);
    int rem = id - e * 12 * 48;
    int cy = rem / 12;             // c-tile 0..47 (f)
    int rx = rem - cy * 12;        // r-tile 0..11 (d), fast
    tcvt64_body<false>(w1 + (size_t)e * DD * FF, w1t + (size_t)e * FF * DD,
                       DD, FF, rx * 64, cy * 64, tT, threadIdx.x);
}

// ============ SETUP+BK ============
__device__ void setup_body(
    const int* __restrict__ tok_e, const float* __restrict__ tok_w,
    int* __restrict__ ctrl, int* __restrict__ row_token, float* __restrict__ row_w,
    int* __restrict__ slot)
{
    __shared__ int cnt[8], base[8], cursor[8];
    int tid = threadIdx.x;
    int lane = tid & 63;
    if (tid < 8) { cnt[tid] = 0; cursor[tid] = 0; }
    __syncthreads();

    int mye[8];
    #pragma unroll
    for (int it = 0; it < 8; it++) {
        int idx = it * 1024 + tid;
        int e = tok_e[idx];
        mye[it] = e;
        #pragma unroll
        for (int ex = 0; ex < 8; ex++) {
            unsigned long long m = __ballot(e == ex);
            if (e == ex && lane == (__ffsll((long long)m) - 1))
                atomicAdd(&cnt[ex], (int)__popcll(m));
        }
    }
    __syncthreads();
    if (tid == 0) {
        int b = 0;
        int* te = ctrl + 24;
        for (int i = 0; i < TILES; i++) te[i] = -1;
        #pragma unroll
        for (int e = 0; e < EE; e++) {
            base[e] = b;
            ctrl[16 + e] = b;
            int tiles = (cnt[e] + 127) >> 7;
            int t0 = b >> 7;
            for (int i = 0; i < tiles; i++) te[t0 + i] = e;
            b += tiles << 7;
        }
    }
    for (int p = tid; p < ROWS_CAP; p += 1024) row_token[p] = -1;
    __syncthreads();

    #pragma unroll
    for (int it = 0; it < 8; it++) {
        int idx = it * 1024 + tid;
        int e = mye[it];
        unsigned long long lt = (1ull << lane) - 1ull;
        int p = 0;
        #pragma unroll
        for (int ex = 0; ex < 8; ex++) {
            unsigned long long m = __ballot(e == ex);
            if (e == ex) {
                int leader = __ffsll((long long)m) - 1;
                int pos = (int)__popcll(m & lt);
                int bp = 0;
                if (lane == leader) bp = atomicAdd(&cursor[ex], (int)__popcll(m));
                bp = __shfl(bp, leader);
                p = base[ex] + bp + pos;
            }
        }
        row_token[p] = idx >> 1;
        row_w[p] = tok_w[idx];
        slot[idx] = p;
    }
}

__device__ void bk_body(int b, const float* __restrict__ v, float* __restrict__ feats) {
    int t = threadIdx.x;
    bool act = t < 256;
    __shared__ float sm[256][8];
    const mob I = {{1.f,0.f},{0.f,0.f},{0.f,0.f},{1.f,0.f}};
    cplx a[8];
    const float* vb = v + (size_t)b * NN;
    if (act) {
        #pragma unroll
        for (int j = 0; j < 8; j++) { a[j].x = -2.f + vb[t*8 + j]; a[j].y = -1.f; }
    }

    mob cur = I;
    if (act) {
        #pragma unroll
        for (int j = 0; j < 8; j++) cur = mstep(a[j], cur);
        mnorm(cur);
        mstore(sm[t], cur);
    }
    for (int s = 1; s < 256; s <<= 1) {
        __syncthreads();
        mob prev; bool has = act && (t >= s);
        if (has) prev = mload(sm[t - s]);
        __syncthreads();
        if (has) { cur = mmul(cur, prev); mnorm(cur); mstore(sm[t], cur); }
    }
    __syncthreads();
    cplx dreg[8];
    if (act) {
        mob P = (t > 0) ? mload(sm[t - 1]) : I;
        #pragma unroll
        for (int j = 0; j < 8; j++) {
            P = mstep(a[j], P); mnorm(P);
            dreg[j] = cdivc(P.m00, P.m10);
        }
    }
    __syncthreads();

    cur = I;
    if (act) {
        #pragma unroll
        for (int j = 7; j >= 0; j--) cur = mstep(a[j], cur);
        mnorm(cur);
        mstore(sm[t], cur);
    }
    for (int s = 1; s < 256; s <<= 1) {
        __syncthreads();
        mob nxt; bool has = act && (t + s < 256);
        if (has) nxt = mload(sm[t + s]);
        __syncthreads();
        if (has) { cur = mmul(cur, nxt); mnorm(cur); mstore(sm[t], cur); }
    }
    __syncthreads();
    if (act) {
        mob P = (t < 255) ? mload(sm[t + 1]) : I;
        #pragma unroll
        for (int j = 7; j >= 0; j--) {
            P = mstep(a[j], P); mnorm(P);
            cplx e = cdivc(P.m00, P.m10);
            cplx den = {dreg[j].x + e.x - a[j].x, dreg[j].y + e.y - a[j].y};
            cplx one = {1.f, 0.f};
            cplx G = cdivc(one, den);
            int i = b * NN + t*8 + j;
            feats[2*i]   = G.x;
            feats[2*i+1] = G.y;
        }
    }
}

__global__ __launch_bounds__(1024) void setup_bk_kernel(
    const int* __restrict__ tok_e, const float* __restrict__ tok_w,
    int* __restrict__ ctrl, int* __restrict__ row_token, float* __restrict__ row_w,
    int* __restrict__ slot, const float* __restrict__ v, float* __restrict__ feats)
{
    if (blockIdx.x == 0) setup_body(tok_e, tok_w, ctrl, row_token, row_w, slot);
    else                 bk_body(blockIdx.x - 1, v, feats);
}

#define MFMAS() do { \
        _Pragma("unroll") \
        for (int i = 0; i < 4; i++) \
            _Pragma("unroll") \
            for (int j = 0; j < 4; j++) \
                acc[i][j] = __builtin_amdgcn_mfma_f32_16x16x32_bf16(afr[i], bfr[j], acc[i][j], 0, 0, 0); \
    } while (0)

// ---------- K5-fused: gemm1 (blocks < G1N) + w2^T convert (rest) ----------
// gemm1: 256x128 tile, 8 waves, BK=32, counted-vmcnt 2-deep pipeline (round 6).
// H epilogue: paired-bf16 u32 stores in permuted f-layout (pos lm*2+b within
// 32-groups) -> half the store instrs, 4B width. w2^T writer applies the SAME
// permutation, so gemm2 (unchanged) consumes both in consistent stored order.
// w2cvt blocks stream ~115MB over HBM pipes gemm1 leaves idle (1.45 of 6.3 TB/s).
#define G1N   (24 * 36)                 // 864 gemm1 blocks (f-fast)
#define NW2T  (48 * 12 * EE / 2)        // 2304 blocks x 2 tiles (512 thr)

__global__ __launch_bounds__(512, 4) void gemm1_fused_kernel(
    const ushort* __restrict__ x_bf, const ushort* __restrict__ w1t, const float* __restrict__ b1,
    const int* __restrict__ ctrl, const int* __restrict__ row_token, ushort* __restrict__ H,
    const float* __restrict__ w2, ushort* __restrict__ w2t)
{
    __shared__ __align__(16) ushort SH[4][256 * 32];   // 64KB: As0,As1,Bs0,Bs1 / cvt tiles
    __shared__ int toks[256];
    int bid = blockIdx.x;
    int tid = threadIdx.x;

    if (bid >= G1N) {
        // ---- w2 [e][3072][768] -> w2t [e][768][3072] with f-perm; 2 tiles/block ----
        int tt = (bid - G1N) * 2 + (tid >> 8);
        int e = tt / (48 * 12);
        int rem = tt - e * 48 * 12;
        int cy = rem / 48;              // c-tile (d) 0..11
        int rx = rem - cy * 48;         // r-tile (f) 0..47, fast
        ushort* tT = &SH[0][0] + (tid >> 8) * 4608;   // 64*72 ushorts per half
        tcvt64_body<true>(w2 + (size_t)e * FF * DD, w2t + (size_t)e * DD * FF,
                          FF, DD, rx * 64, cy * 64, tT, tid & 255);
        return;
    }

    int fx = bid % 24;                  // f-block fast (L2 locality, round-1 proven)
    int tile = bid / 24;                // 256-row tile 0..35
    int e0 = ctrl[24 + 2*tile];
    if (e0 < 0) return;
    int e1 = ctrl[24 + 2*tile + 1];
    if (e1 < 0) e1 = e0;
    int p0 = tile * 256;
    int f0 = fx * 128;

    ushort* As0 = &SH[0][0];
    ushort* As1 = &SH[1][0];
    ushort* Bs0 = &SH[2][0];
    ushort* Bs1 = &SH[3][0];

    if (tid < 256) { int tk = row_token[p0 + tid]; toks[tid] = tk < 0 ? 0 : tk; }
    __syncthreads();

    int wave = tid >> 6, lane = tid & 63;
    int rsub = lane >> 2;
    int kq = (((lane & 3) ^ ((rsub >> 1) & 3))) * 8;
    int tokA0 = toks[wave*32 + rsub];
    int tokA1 = toks[wave*32 + 16 + rsub];
    const ushort* aglob0 = x_bf + (size_t)tokA0 * DD + kq;
    const ushort* aglob1 = x_bf + (size_t)tokA1 * DD + kq;
    int eh = (wave >> 2) ? e1 : e0;
    const ushort* w1e = w1t + (size_t)eh * (FF * DD);
    const ushort* bglob0 = w1e + (size_t)(f0 + (wave & 3)*32 + rsub) * DD + kq;
    const ushort* bglob1 = bglob0 + (size_t)16 * DD;
    ushort* AsW0 = As0 + wave * 32 * 32;
    ushort* BsW0 = Bs0 + wave * 32 * 32;
    ushort* AsW1 = As1 + wave * 32 * 32;
    ushort* BsW1 = Bs1 + wave * 32 * 32;

    floatx4 zero4 = {0.f, 0.f, 0.f, 0.f};
    floatx4 acc[4][4];
    #pragma unroll
    for (int i = 0; i < 4; i++)
        #pragma unroll
        for (int j = 0; j < 4; j++) acc[i][j] = zero4;

    int wm = (wave >> 1) * 64, wn = (wave & 1) * 64;
    int bbase = (wave >> 2) * 128;
    int lm = lane & 15, q = lane >> 4;
    int qx = (q ^ ((lm >> 1) & 3)) * 8;

    #define G1_STAGE(AW, BW, k0) do { \
        gload16(aglob0 + (k0), (AW)); \
        gload16(aglob1 + (k0), (AW) + 16*32); \
        gload16(bglob0 + (k0), (BW)); \
        gload16(bglob1 + (k0), (BW) + 16*32); } while (0)

    G1_STAGE(AsW0, BsW0, 0);
    G1_STAGE(AsW1, BsW1, 32);
    const int NK = DD / 32;
    for (int ks = 0; ks < NK; ks++) {
        int cur = ks & 1;
        const ushort* Ab = cur ? As1 : As0;
        const ushort* Bb = cur ? Bs1 : Bs0;
        ushort* AsN = cur ? AsW1 : AsW0;
        ushort* BsN = cur ? BsW1 : BsW0;
        if (ks < NK - 1) { asm volatile("s_waitcnt vmcnt(4)" ::: "memory"); }
        else             { asm volatile("s_waitcnt vmcnt(0)" ::: "memory"); }
        __builtin_amdgcn_s_barrier();
        bf16x8 afr[4], bfr[4];
        #pragma unroll
        for (int i = 0; i < 4; i++)
            afr[i] = *(const bf16x8*)(const void*)(Ab + (wm + i*16 + lm) * 32 + qx);
        #pragma unroll
        for (int j = 0; j < 4; j++)
            bfr[j] = *(const bf16x8*)(const void*)(Bb + (bbase + wn + j*16 + lm) * 32 + qx);
        asm volatile("s_waitcnt lgkmcnt(0)" ::: "memory");
        __builtin_amdgcn_sched_barrier(0);
        __builtin_amdgcn_s_barrier();
        if (ks + 2 < NK) G1_STAGE(AsN, BsN, ks*32 + 64);
        __builtin_amdgcn_s_setprio(1);
        MFMAS();
        __builtin_amdgcn_s_setprio(0);
    }
    #undef G1_STAGE

    // epilogue: paired u32 stores at permuted positions f0+wn+jp*32+lm*2
    #pragma unroll
    for (int i = 0; i < 4; i++) {
        #pragma unroll
        for (int jp = 0; jp < 2; jp++) {
            float bias0 = b1[eh * FF + f0 + wn + (2*jp)*16 + lm];
            float bias1 = b1[eh * FF + f0 + wn + (2*jp+1)*16 + lm];
            #pragma unroll
            for (int r = 0; r < 4; r++) {
                int m = wm + i*16 + q*4 + r;
                float h0 = gelu_f(acc[i][2*jp][r] + bias0);
                float h1 = gelu_f(acc[i][2*jp+1][r] + bias1);
                *(unsigned int*)(H + (size_t)(p0 + m) * FF + f0 + wn + jp*32 + lm*2) = pk2(h0, h1);
            }
        }
    }
}

// ---------- K6: GEMM2 (unchanged; consumes permuted H & w2t consistently) ----------
#define STAGE64(AW, BW, k0) do { \
        _Pragma("unroll") \
        for (int g = 0; g < 4; g++) { \
            gload16(ag[g] + (k0), (AW) + g*8*64); \
            gload16(bg[g] + (k0), (BW) + g*8*64); \
        } } while (0)

#define LOADFR64(APTR, BPTR, QX) do { \
        _Pragma("unroll") \
        for (int i = 0; i < 4; i++) \
            afr[i] = *(const bf16x8*)(const void*)((APTR) + (wm + i*16 + lm) * 64 + (QX)); \
        _Pragma("unroll") \
        for (int j = 0; j < 4; j++) \
            bfr[j] = *(const bf16x8*)(const void*)((BPTR) + (wn + j*16 + lm) * 64 + (QX)); \
    } while (0)

#define PIPE64(NK) do { \
    STAGE64(AsW0, BsW0, 0); \
    STAGE64(AsW1, BsW1, 64); \
    for (int ks = 0; ks < (NK); ks++) { \
        int cur = ks & 1; \
        const ushort* Ab = cur ? As[1] : As[0]; \
        const ushort* Bb = cur ? Bs[1] : Bs[0]; \
        ushort* AsN = cur ? AsW1 : AsW0; \
        ushort* BsN = cur ? BsW1 : BsW0; \
        if (ks < (NK) - 1) { asm volatile("s_waitcnt vmcnt(8)" ::: "memory"); } \
        else               { asm volatile("s_waitcnt vmcnt(0)" ::: "memory"); } \
        __builtin_amdgcn_s_barrier(); \
        { \
            bf16x8 afr[4], bfr[4]; \
            LOADFR64(Ab, Bb, qx0); \
            __builtin_amdgcn_s_setprio(1); \
            MFMAS(); \
            __builtin_amdgcn_s_setprio(0); \
        } \
        { \
            bf16x8 afr[4], bfr[4]; \
            LOADFR64(Ab, Bb, qx0 ^ 32); \
            asm volatile("s_waitcnt lgkmcnt(0)" ::: "memory"); \
            __builtin_amdgcn_sched_barrier(0); \
            __builtin_amdgcn_s_barrier(); \
            if (ks + 2 < (NK)) STAGE64(AsN, BsN, ks*64 + 128); \
            __builtin_amdgcn_s_setprio(1); \
            MFMAS(); \
            __builtin_amdgcn_s_setprio(0); \
        } \
    } } while (0)

__global__ __launch_bounds__(256) void gemm2_kernel(
    const ushort* __restrict__ H, const ushort* __restrict__ w2t, const float* __restrict__ b2,
    const int* __restrict__ ctrl, const float* __restrict__ row_w, float* __restrict__ Y)
{
    int tile = blockIdx.x;
    int e = ctrl[24 + tile];
    if (e < 0) return;
    int p0 = tile * 128;
    int d0 = blockIdx.y * 128;

    __shared__ ushort As[2][128 * 64];
    __shared__ ushort Bs[2][128 * 64];

    int tid = threadIdx.x;
    int wave = tid >> 6, lane = tid & 63;
    int srow = lane >> 3;
    int kq = (((lane & 7) ^ (srow & 7))) * 8;
    const ushort* ag[4];
    #pragma unroll
    for (int g = 0; g < 4; g++)
        ag[g] = H + (size_t)(p0 + wave*32 + g*8 + srow) * FF + kq;
    const ushort* w2e = w2t + (size_t)e * (DD * FF);
    const ushort* bg[4];
    #pragma unroll
    for (int g = 0; g < 4; g++)
        bg[g] = w2e + (size_t)(d0 + wave*32 + g*8 + srow) * FF + kq;
    ushort* AsW0 = &As[0][wave * 32 * 64];
    ushort* BsW0 = &Bs[0][wave * 32 * 64];
    ushort* AsW1 = &As[1][wave * 32 * 64];
    ushort* BsW1 = &Bs[1][wave * 32 * 64];

    floatx4 zero4 = {0.f, 0.f, 0.f, 0.f};
    floatx4 acc[4][4];
    #pragma unroll
    for (int i = 0; i < 4; i++)
        #pragma unroll
        for (int j = 0; j < 4; j++) acc[i][j] = zero4;

    int wm = (wave & 1) * 64, wn = (wave >> 1) * 64;
    int lm = lane & 15, q = lane >> 4;
    int qx0 = (q ^ (lm & 7)) * 8;

    PIPE64(FF/64);

    #pragma unroll
    for (int i = 0; i < 4; i++) {
        #pragma unroll
        for (int j = 0; j < 4; j++) {
            int n = wn + j*16 + lm;
            float bias = b2[e * DD + d0 + n];
            #pragma unroll
            for (int r = 0; r < 4; r++) {
                int m = wm + i*16 + q*4 + r;
                float wgt = row_w[p0 + m];
                Y[(size_t)(p0 + m) * DD + d0 + n] = wgt * (acc[i][j][r] + bias);
            }
        }
    }
}

// ---------- K7: final combine ----------
__global__ __launch_bounds__(256) void final_kernel(
    const float* __restrict__ Y, const int* __restrict__ slot, const float* __restrict__ feats,
    const float* __restrict__ out_w, const float* __restrict__ out_b,
    const float* __restrict__ bk_scale, float* __restrict__ out)
{
    int idx = blockIdx.x * 256 + threadIdx.x;
    int base = idx * 4;
    int t = base / DD;
    int d = base - t * DD;
    int p0 = slot[2*t], p1 = slot[2*t + 1];
    const float4 ya = *(const float4*)(Y + (size_t)p0 * DD + d);
    const float4 yb = *(const float4*)(Y + (size_t)p1 * DD + d);
    float f0 = feats[2*t], f1 = feats[2*t + 1];
    f0 = fminf(fmaxf(f0, -10.f), 10.f);
    f1 = fminf(fmaxf(f1, -10.f), 10.f);
    float ff[4] = {ya.x + yb.x, ya.y + yb.y, ya.z + yb.z, ya.w + yb.w};
    float4 o;
    float* op = (float*)&o;
    #pragma unroll
    for (int u = 0; u < 4; u++) {
        float spec = f0 * out_w[d + u] + f1 * out_w[DD + d + u] + out_b[d + u];
        op[u] = ff[u] + bk_scale[d + u] * spec;
    }
    *(float4*)(out + base) = o;
}

extern "C" void kernel_launch(void* const* d_in, const int* in_sizes, int n_in,
                              void* d_out, int out_size, void* d_ws, size_t ws_size,
                              hipStream_t stream)
{
    const float* x      = (const float*)d_in[0];
    const float* v_w    = (const float*)d_in[1];
    const float* v_b    = (const float*)d_in[2];
    const float* gate_w = (const float*)d_in[3];
    const float* gate_b = (const float*)d_in[4];
    const float* w1     = (const float*)d_in[5];
    const float* b1     = (const float*)d_in[6];
    const float* w2     = (const float*)d_in[7];
    const float* b2     = (const float*)d_in[8];
    const float* out_w  = (const float*)d_in[9];
    const float* out_b  = (const float*)d_in[10];
    const float* bk_s   = (const float*)d_in[11];

    char* ws = (char*)d_ws;
    int*    ctrl    = (int*)(ws + OFF_CTRL);
    float*  v       = (float*)(ws + OFF_V);
    int*    tok_e   = (int*)(ws + OFF_TOKE);
    float*  tok_w   = (float*)(ws + OFF_TOKW);
    int*    row_tok = (int*)(ws + OFF_ROWTOK);
    float*  row_w   = (float*)(ws + OFF_ROWW);
    int*    slot    = (int*)(ws + OFF_SLOT);
    float*  feats   = (float*)(ws + OFF_FEATS);
    ushort* w2t     = (ushort*)(ws + OFF_W2T);
    ushort* x_bf    = (ushort*)(ws + OFF_XBF);
    ushort* w1t     = (ushort*)(ws + OFF_W1T);
    ushort* H       = (ushort*)(ws + OFF_H);
    float*  Y       = (float*)(ws + OFF_Y);
    float*  out     = (float*)d_out;

    prep1_kernel<<<NB_CVT + NB_ROUTE + NB_W1T, 256, 0, stream>>>(
        x, x_bf, v_w, v_b, gate_w, gate_b, v, tok_e, tok_w, w1, w1t);
    setup_bk_kernel<<<1 + BB, 1024, 0, stream>>>(tok_e, tok_w, ctrl, row_tok, row_w, slot, v, feats);
    gemm1_fused_kernel<<<G1N + NW2T, 512, 0, stream>>>(x_bf, w1t, b1, ctrl, row_tok, H, w2, w2t);
    gemm2_kernel<<<dim3(TILES, DD / 128), 256, 0, stream>>>(H, w2t, b2, ctrl, row_w, Y);
    final_kernel<<<(TOK * DD) / 1024, 256, 0, stream>>>(Y, slot, feats, out_w, out_b, bk_s, out);
}